// Round 5
// baseline (335.631 us; speedup 1.0000x reference)
//
#include <hip/hip_runtime.h>

namespace {

constexpr int NB_  = 2;
constexpr int TC_  = 1024;
constexpr int TP_  = 512;
constexpr int TT_  = 1536;   // TC + TP
constexpr int D_   = 128;
constexpr int H_   = 8;
constexpr int DK_  = 16;
constexpr int DFF_ = 512;
constexpr int L_   = 2;
constexpr int HOR_ = 96;
constexpr int NQ_  = 3;

constexpr int SCP_ = TT_ + 8;   // ushort stride per head row (even → dword-tiled)

typedef _Float16 h2 __attribute__((ext_vector_type(2)));

// ---- output float offsets (return order: out, v_cond, v_pred, logs) ----
constexpr int OFF_OUT  = 0;
constexpr int OFF_VC   = NB_ * NQ_ * HOR_;            // 576
constexpr int OFF_VP   = OFF_VC + NB_ * TC_ * 8;      // 16960
constexpr int OFF_LOGS = OFF_VP + NB_ * TP_ * 4;      // 21056

// ---- workspace float offsets ----
constexpr int WS_XA  = 0;
constexpr int WS_XB  = WS_XA  + NB_ * TT_ * D_;       // 393216
constexpr int WS_Q16 = WS_XB  + NB_ * TT_ * D_;       // f16, half-sized
constexpr int WS_K16 = WS_Q16 + NB_ * TT_ * D_ / 2;
constexpr int WS_VC  = WS_K16 + NB_ * TT_ * D_ / 2;
constexpr int WS_WVC = WS_VC  + NB_ * TT_ * DK_;      // 2 layers x 2048
constexpr int WS_BVC = WS_WVC + L_ * D_ * DK_;        // 2 layers x 16
// R20: packed-f16 weight pairs (reduction-dim pairs), one dword per entry
constexpr int FH1_L  = (D_ / 2) * DFF_;               // 32768 per layer
constexpr int FH2_L  = (DFF_ / 2) * D_;               // 32768 per layer
constexpr int WHQ_L  = (D_ / 2) * D_;                 // 8192 per layer
constexpr int WS_FH1 = WS_BVC + L_ * DK_;             // 1232928
constexpr int WS_FH2 = WS_FH1 + L_ * FH1_L;
constexpr int WS_WHQ = WS_FH2 + L_ * FH2_L;
constexpr int WS_WHK = WS_WHQ + L_ * WHQ_L;           // end ~1396768 floats

__device__ inline float dot2f(h2 a, h2 b, float c) {
#if __has_builtin(__builtin_amdgcn_fdot2)
    return __builtin_amdgcn_fdot2(a, b, c, false);
#else
    return c + (float)a[0] * (float)b[0] + (float)a[1] * (float)b[1];
#endif
}

__device__ inline unsigned pack2h(float a, float b) {   // 1 inst: v_cvt_pkrtz
#if __has_builtin(__builtin_amdgcn_cvt_pkrtz)
    return __builtin_bit_cast(unsigned, __builtin_amdgcn_cvt_pkrtz(a, b));
#else
    h2 p; p[0] = (_Float16)a; p[1] = (_Float16)b;
    return __builtin_bit_cast(unsigned, p);
#endif
}

__device__ inline float fast_rcp(float x) {             // v_rcp_f32, 1 inst
#if __has_builtin(__builtin_amdgcn_rcpf)
    return __builtin_amdgcn_rcpf(x);
#else
    return 1.0f / x;
#endif
}

// =======================================================================
// DPP wave reductions — VALU pipe (R16: attn 79->64 µs).
// =======================================================================
template <int CTRL>
__device__ inline float dpp_add(float x) {
    const int y = __builtin_amdgcn_update_dpp(
        0, __builtin_bit_cast(int, x), CTRL, 0xF, 0xF, true);
    return x + __builtin_bit_cast(float, y);
}
template <int CTRL>
__device__ inline float dpp_maxf(float x) {
    const int y = __builtin_amdgcn_update_dpp(
        __builtin_bit_cast(int, x), __builtin_bit_cast(int, x),
        CTRL, 0xF, 0xF, false);
    return fmaxf(x, __builtin_bit_cast(float, y));
}
__device__ inline float bcast63(float x) {
    return __builtin_bit_cast(float,
        __builtin_amdgcn_readlane(__builtin_bit_cast(int, x), 63));
}
__device__ inline float wave_sum_l63(float x) {
    x = dpp_add<0x111>(x); x = dpp_add<0x112>(x); x = dpp_add<0x114>(x);
    x = dpp_add<0x118>(x); x = dpp_add<0x142>(x); x = dpp_add<0x143>(x);
    return x;
}
__device__ inline float wave_sum(float x) { return bcast63(wave_sum_l63(x)); }
__device__ inline float wave_max(float x) {
    x = dpp_maxf<0x111>(x); x = dpp_maxf<0x112>(x); x = dpp_maxf<0x114>(x);
    x = dpp_maxf<0x118>(x); x = dpp_maxf<0x142>(x); x = dpp_maxf<0x143>(x);
    return bcast63(x);
}

// =======================================================================
// Prep: Wv head-mean + all packed-f16 weight conversions (R20).
// fh1[l][i2*DFF+c]  = (fw1[2i2][c], fw1[2i2+1][c])   — pairs along i
// fh2[l][j2*D+d]    = (fw2[2j2][d], fw2[2j2+1][d])   — pairs along j
// whq/whk[l][i2*D+c]= (W[2i2][c],  W[2i2+1][c])      — pairs along i
// =======================================================================
__global__ __launch_bounds__(256) void prep_kernel(
    const float* __restrict__ Wv, const float* __restrict__ bv,
    float* __restrict__ wvc, float* __restrict__ bvc,
    const float* __restrict__ fw1, const float* __restrict__ fw2,
    const float* __restrict__ Wq, const float* __restrict__ Wk,
    unsigned* __restrict__ fh1, unsigned* __restrict__ fh2,
    unsigned* __restrict__ whq, unsigned* __restrict__ whk)
{
    const int gid = blockIdx.x * 256 + threadIdx.x;
    const int stride = gridDim.x * 256;

    for (int e = gid; e < L_ * D_ * DK_; e += stride) {
        const int l = e / (D_ * DK_), rem = e - l * D_ * DK_;
        const int i = rem >> 4, dk = rem & 15;
        const float* W = Wv + (long)l * D_ * D_;
        float s = 0.f;
        #pragma unroll
        for (int hh = 0; hh < H_; ++hh) s += W[i * D_ + hh * DK_ + dk];
        wvc[e] = s * 0.125f;
    }
    for (int e = gid; e < L_ * DK_; e += stride) {
        const int l = e / DK_, dk = e - l * DK_;
        const float* bb = bv + l * D_;
        float s = 0.f;
        #pragma unroll
        for (int hh = 0; hh < H_; ++hh) s += bb[hh * DK_ + dk];
        bvc[e] = s * 0.125f;
    }
    for (int e = gid; e < L_ * FH1_L; e += stride) {
        const int l = e / FH1_L, rem = e - l * FH1_L;
        const int i2 = rem / DFF_, c = rem - i2 * DFF_;
        const float* W = fw1 + (long)l * D_ * DFF_;
        fh1[e] = pack2h(W[(2 * i2) * DFF_ + c], W[(2 * i2 + 1) * DFF_ + c]);
    }
    for (int e = gid; e < L_ * FH2_L; e += stride) {
        const int l = e / FH2_L, rem = e - l * FH2_L;
        const int j2 = rem >> 7, d = rem & 127;
        const float* W = fw2 + (long)l * DFF_ * D_;
        fh2[e] = pack2h(W[(2 * j2) * D_ + d], W[(2 * j2 + 1) * D_ + d]);
    }
    for (int e = gid; e < L_ * WHQ_L; e += stride) {
        const int l = e / WHQ_L, rem = e - l * WHQ_L;
        const int i2 = rem >> 7, c = rem & 127;
        const float* Q = Wq + (long)l * D_ * D_;
        const float* K = Wk + (long)l * D_ * D_;
        whq[e] = pack2h(Q[(2 * i2) * D_ + c], Q[(2 * i2 + 1) * D_ + c]);
        whk[e] = pack2h(K[(2 * i2) * D_ + c], K[(2 * i2 + 1) * D_ + c]);
    }
}

// =======================================================================
// Selector + fused layer-0 QKV — R19: 4 tokens/block (768 blocks), one
// wave per token for the selector; R20: QKV via packed-f16 dot2 pairs
// (halved loads + VALU in the 64-iter loop).
// =======================================================================
template <int NV>
__device__ inline void selector_qkv_body(
    const float* __restrict__ x, const float* __restrict__ cw,
    const float* __restrict__ cb, const float* __restrict__ sw,
    const float* __restrict__ sb, float* __restrict__ vout,
    float* __restrict__ xout, int Tsel, int row_off, int blk,
    const unsigned* __restrict__ whq0, const float* __restrict__ bq,
    const unsigned* __restrict__ whk0, const float* __restrict__ bk,
    const float* __restrict__ wvc, const float* __restrict__ bvc,
    _Float16* __restrict__ q16, _Float16* __restrict__ k16,
    float* __restrict__ vc)
{
    const int tpb = Tsel / 4;            // token-groups per batch
    const int b   = blk / tpb;
    const int t0  = (blk - b * tpb) * 4;
    const int tid = threadIdx.x;
    const int lane = tid & 63, wave = tid >> 6;
    const int t = t0 + wave;             // this wave's token

    __shared__ float xrT[D_][4];         // staged selector outputs [d][r]
    __shared__ unsigned xh2[D_ / 2][4];  // packed pairs along d  [i2][r]

    // ---- selector: lane covers dims d0 = lane, d1 = lane + 64 ----
    const int d0 = lane, d1 = lane + 64;
    float xw[3 * NV];
    #pragma unroll
    for (int kk = 0; kk < 3; ++kk) {
        const int ts = t + kk - 2;
        #pragma unroll
        for (int v = 0; v < NV; ++v)
            xw[kk * NV + v] = (ts >= 0) ? x[((long)b * Tsel + ts) * NV + v] : 0.0f;
    }
    float ls0[NV], ls1[NV];
    #pragma unroll
    for (int v = 0; v < NV; ++v) {
        const float* c0 = cw + ((long)(v * D_ + d0)) * 3;
        const float* c1 = cw + ((long)(v * D_ + d1)) * 3;
        float a0 = cb[v * D_ + d0], a1 = cb[v * D_ + d1];
        a0 = fmaf(xw[0*NV+v], c0[0], a0); a1 = fmaf(xw[0*NV+v], c1[0], a1);
        a0 = fmaf(xw[1*NV+v], c0[1], a0); a1 = fmaf(xw[1*NV+v], c1[1], a1);
        a0 = fmaf(xw[2*NV+v], c0[2], a0); a1 = fmaf(xw[2*NV+v], c1[2], a1);
        ls0[v] = a0; ls1[v] = a1;
    }
    float u[NV];
    {
        const float s0 = sw[d0], s1 = sw[d1];
        #pragma unroll
        for (int v = 0; v < NV; ++v)
            u[v] = wave_sum(fmaf(ls1[v], s1, ls0[v] * s0));
    }
    // tiny entmax Newton, run redundantly by all 64 lanes (no divergence)
    float wls[NV];
    {
        float m = -1e30f;
        #pragma unroll
        for (int v = 0; v < NV; ++v) {
            float s = u[v] + sb[0];
            s = fminf(fmaxf(s, -10.0f), 10.0f);
            u[v] = 0.5f * s;
            m = fmaxf(m, u[v]);
        }
        float tau = m - 1.0f;
        for (int it = 0; it < 12; ++it) {
            float S1 = 0.f, S2 = 0.f;
            #pragma unroll
            for (int v = 0; v < NV; ++v) {
                float dd = fmaxf(u[v] - tau, 0.f);
                S1 += dd; S2 = fmaf(dd, dd, S2);
            }
            tau += (S2 - 1.0f) * 0.5f * fast_rcp(S1);   // self-correcting
        }
        float S1 = 0.f, S2 = 0.f, K = 0.f;
        #pragma unroll
        for (int v = 0; v < NV; ++v) {
            if (u[v] > tau) { S1 += u[v]; S2 = fmaf(u[v], u[v], S2); K += 1.f; }
        }
        const float mean = S1 / K;
        const float arg  = fmaxf(fmaf(mean, mean, -(S2 - 1.0f) / K), 0.f);
        tau = mean - sqrtf(arg);
        #pragma unroll
        for (int v = 0; v < NV; ++v) {
            const float dd = fmaxf(u[v] - tau, 0.f);
            wls[v] = dd * dd;
        }
    }
    float acc0 = 0.f, acc1 = 0.f;
    #pragma unroll
    for (int v = 0; v < NV; ++v) {
        acc0 = fmaf(ls0[v], wls[v], acc0);
        acc1 = fmaf(ls1[v], wls[v], acc1);
    }
    const long rowb = (long)b * TT_ + row_off + t0;   // block's first row
    const long row  = rowb + wave;
    xout[row * D_ + d0] = acc0;
    xout[row * D_ + d1] = acc1;
    xrT[d0][wave] = acc0;
    xrT[d1][wave] = acc1;
    if (lane == 0) {
        #pragma unroll
        for (int v = 0; v < NV; ++v)
            vout[((long)b * Tsel + t) * NV + v] = wls[v];
    }
    __syncthreads();

    // pack activation pairs for dot2 QKV
    {
        const int i2 = tid >> 2, r = tid & 3;
        xh2[i2][r] = pack2h(xrT[2 * i2][r], xrT[2 * i2 + 1][r]);
    }
    __syncthreads();

    // ---- fused layer-0 QKV over 4 staged rows, packed-f16 dot2 ----
    {
        const int c = tid & 127;
        const int which = tid >> 7;             // 0: q, 1: k (wave-uniform)
        const unsigned* __restrict__ Wp = which ? whk0 : whq0;
        const float bb = which ? bk[c] : bq[c];
        float a0 = bb, a1 = bb, a2 = bb, a3 = bb;
        for (int i2 = 0; i2 < D_ / 2; ++i2) {
            const h2 w = __builtin_bit_cast(h2, Wp[i2 * D_ + c]);
            const uint4 xp = *(const uint4*)&xh2[i2][0];
            a0 = dot2f(w, __builtin_bit_cast(h2, xp.x), a0);
            a1 = dot2f(w, __builtin_bit_cast(h2, xp.y), a1);
            a2 = dot2f(w, __builtin_bit_cast(h2, xp.z), a2);
            a3 = dot2f(w, __builtin_bit_cast(h2, xp.w), a3);
        }
        _Float16* __restrict__ dst = which ? k16 : q16;
        dst[(rowb + 0) * D_ + c] = (_Float16)a0;
        dst[(rowb + 1) * D_ + c] = (_Float16)a1;
        dst[(rowb + 2) * D_ + c] = (_Float16)a2;
        dst[(rowb + 3) * D_ + c] = (_Float16)a3;
    }
    if (tid < 64) {
        const int r = tid >> 4, c16 = tid & 15;
        float av = bvc[c16];
        for (int i = 0; i < D_; ++i)
            av = fmaf(xrT[i][r], wvc[i * DK_ + c16], av);
        vc[(rowb + r) * DK_ + c16] = av;
    }
}

__global__ __launch_bounds__(256) void pre_kernel(
    const float* __restrict__ x_cond, const float* __restrict__ cw_c,
    const float* __restrict__ cb_c, const float* __restrict__ sw_c,
    const float* __restrict__ sb_c,
    const float* __restrict__ x_pred, const float* __restrict__ cw_p,
    const float* __restrict__ cb_p, const float* __restrict__ sw_p,
    const float* __restrict__ sb_p,
    float* __restrict__ vc_out, float* __restrict__ vp_out,
    float* __restrict__ xout,
    const unsigned* __restrict__ whq0, const float* __restrict__ bq,
    const unsigned* __restrict__ whk0, const float* __restrict__ bk,
    const float* __restrict__ wvc, const float* __restrict__ bvc,
    _Float16* __restrict__ q16, _Float16* __restrict__ k16,
    float* __restrict__ vc)
{
    const int blk = blockIdx.x;
    if (blk < NB_ * TC_ / 4) {
        selector_qkv_body<8>(x_cond, cw_c, cb_c, sw_c, sb_c, vc_out, xout,
                             TC_, 0, blk, whq0, bq, whk0, bk, wvc, bvc,
                             q16, k16, vc);
    } else {
        selector_qkv_body<4>(x_pred, cw_p, cb_p, sw_p, sb_p, vp_out, xout,
                             TP_, TC_, blk - NB_ * TC_ / 4,
                             whq0, bq, whk0, bk, wvc, bvc, q16, k16, vc);
    }
}

// =======================================================================
// entmax15 Newton, TWO head rows per wave INTERLEAVED (R18, 62.4 µs).
// R17 packed-f16 Newton regressed — scalar f32 retained.
// =======================================================================
template <int NJ>
__device__ inline void entmax_head2(unsigned short* __restrict__ sa,
                                    unsigned short* __restrict__ sb,
                                    int lane, int t)
{
    const unsigned* __restrict__ rpa = (const unsigned*)sa;
    const unsigned* __restrict__ rpb = (const unsigned*)sb;
    float va[2 * NJ], vb[2 * NJ];
    #pragma unroll
    for (int j = 0; j < NJ; ++j) {
        const unsigned dwa = rpa[64 * j + lane];
        const unsigned dwb = rpb[64 * j + lane];
        const h2 ha = __builtin_bit_cast(h2, dwa);
        const h2 hb = __builtin_bit_cast(h2, dwb);
        const int s0 = 128 * j + 2 * lane;
        const bool in0 = (s0 <= t), in1 = (s0 + 1 <= t);
        va[2*j]   = in0 ? (float)ha[0] : -1e30f;
        va[2*j+1] = in1 ? (float)ha[1] : -1e30f;
        vb[2*j]   = in0 ? (float)hb[0] : -1e30f;
        vb[2*j+1] = in1 ? (float)hb[1] : -1e30f;
    }

    float ma0 = va[0], ma1 = va[1], mb0 = vb[0], mb1 = vb[1];
    #pragma unroll
    for (int j = 2; j < 2 * NJ; j += 2) {
        ma0 = fmaxf(ma0, va[j]); ma1 = fmaxf(ma1, va[j+1]);
        mb0 = fmaxf(mb0, vb[j]); mb1 = fmaxf(mb1, vb[j+1]);
    }
    const float ma = wave_max(fmaxf(ma0, ma1));
    const float mb = wave_max(fmaxf(mb0, mb1));

    float ta = ma - 1.0f, tb = mb - 1.0f;   // f(tau0) >= 0
    #pragma unroll
    for (int it = 0; it < 7; ++it) {
        float a10 = 0.f, a11 = 0.f, a20 = 0.f, a21 = 0.f;
        float b10 = 0.f, b11 = 0.f, b20 = 0.f, b21 = 0.f;
        #pragma unroll
        for (int j = 0; j < 2 * NJ; j += 2) {
            const float da0 = fmaxf(va[j]   - ta, 0.f);
            const float da1 = fmaxf(va[j+1] - ta, 0.f);
            const float db0 = fmaxf(vb[j]   - tb, 0.f);
            const float db1 = fmaxf(vb[j+1] - tb, 0.f);
            a10 += da0; a11 += da1;
            a20 = fmaf(da0, da0, a20); a21 = fmaf(da1, da1, a21);
            b10 += db0; b11 += db1;
            b20 = fmaf(db0, db0, b20); b21 = fmaf(db1, db1, b21);
        }
        const float S1a = wave_sum(a10 + a11);
        const float S2a = wave_sum(a20 + a21);
        const float S1b = wave_sum(b10 + b11);
        const float S2b = wave_sum(b20 + b21);
        ta += (S2a - 1.0f) * 0.5f * fast_rcp(S1a);
        tb += (S2b - 1.0f) * 0.5f * fast_rcp(S1b);
    }
    {
        float a1 = 0.f, a2 = 0.f, ka = 0.f;
        float b1 = 0.f, b2 = 0.f, kb = 0.f;
        #pragma unroll
        for (int j = 0; j < 2 * NJ; ++j) {
            if (va[j] > ta) { a1 += va[j]; a2 = fmaf(va[j], va[j], a2); ka += 1.f; }
            if (vb[j] > tb) { b1 += vb[j]; b2 = fmaf(vb[j], vb[j], b2); kb += 1.f; }
        }
        a1 = wave_sum(a1); a2 = wave_sum(a2); ka = wave_sum(ka);
        b1 = wave_sum(b1); b2 = wave_sum(b2); kb = wave_sum(kb);
        const float meana = a1 / ka;
        const float arga  = fmaxf(fmaf(meana, meana, -(a2 - 1.0f) / ka), 0.f);
        ta = meana - sqrtf(arga);
        const float meanb = b1 / kb;
        const float argb  = fmaxf(fmaf(meanb, meanb, -(b2 - 1.0f) / kb), 0.f);
        tb = meanb - sqrtf(argb);
    }
    unsigned* __restrict__ wpa = (unsigned*)sa;
    unsigned* __restrict__ wpb = (unsigned*)sb;
    #pragma unroll
    for (int j = 0; j < NJ; ++j) {
        const float da0 = fmaxf(va[2*j]   - ta, 0.f);
        const float da1 = fmaxf(va[2*j+1] - ta, 0.f);
        const float db0 = fmaxf(vb[2*j]   - tb, 0.f);
        const float db1 = fmaxf(vb[2*j+1] - tb, 0.f);
        wpa[64 * j + lane] = pack2h(da0 * da0, da1 * da1);
        wpb[64 * j + lane] = pack2h(db0 * db0, db1 * db1);
    }
}

template <int NJ>
__device__ inline void entmax_pair(unsigned short* __restrict__ scb,
                                   int wave, int lane, int t)
{
    entmax_head2<NJ>(scb + (wave * 2 + 0) * SCP_,
                     scb + (wave * 2 + 1) * SCP_, lane, t);
}

// =======================================================================
// Attention: one block (256 threads, 4 waves) per (b, t).  [R14 config]
// UNCHANGED in R20 (62.4 µs, VALUBusy ~64%). See R15/R16/R17/R18 notes.
// =======================================================================
__global__ __launch_bounds__(256) void attn_kernel(
    const _Float16* __restrict__ q16, const _Float16* __restrict__ k16,
    const float* __restrict__ vcomb, const float* __restrict__ xin,
    float* __restrict__ xout,
    const float* __restrict__ Wo, const float* __restrict__ bo,
    const float* __restrict__ lng, const float* __restrict__ lnb,
    float* __restrict__ logs)
{
    __shared__ unsigned short scb[H_ * SCP_];   // 24.7 KB f16 scores/weights
    __shared__ _Float16 qrow16[D_];
    __shared__ float red[64];
    __shared__ float o16[DK_];
    __shared__ float yrow[D_];
    __shared__ float stat[2];

    const int blk = blockIdx.x;
    const int t = TT_ - 1 - (blk >> 1);   // descending-work dispatch order
    const int b = blk & 1;
    const int tid = threadIdx.x;
    const int lane = tid & 63, wave = tid >> 6;
    const long rowq  = (long)b * TT_ + t;
    const long bbase = (long)b * TT_;

    if (tid < 64)
        ((unsigned*)qrow16)[tid] = ((const unsigned*)(q16 + rowq * D_))[tid];
    __syncthreads();

    // ---- scores: u = (q.k / 4) / 2 = dot * 0.125, f16 dot2, stored f16 ----
    {
        const int h  = tid & 7;
        const int sl = tid >> 3;   // 0..31
        unsigned short* __restrict__ srow = scb + h * SCP_;
        h2 qv[8];
        __builtin_memcpy(qv, (const _Float16*)qrow16 + h * DK_, 32);
        for (int s = sl; s <= t; s += 32) {
            float4 kk0, kk1;
            {
                const float4* kp4 = (const float4*)(k16 + (bbase + s) * D_ + h * DK_);
                kk0 = kp4[0]; kk1 = kp4[1];
            }
            h2 kh[8];
            __builtin_memcpy(kh,     &kk0, 16);
            __builtin_memcpy(kh + 4, &kk1, 16);
            float dot = 0.f;
            #pragma unroll
            for (int i2 = 0; i2 < 8; ++i2) dot = dot2f(qv[i2], kh[i2], dot);
            const _Float16 sh = (_Float16)(dot * 0.125f);
            srow[s] = __builtin_bit_cast(unsigned short, sh);
        }
    }
    __syncthreads();

    // ---- entmax15: wave w = heads 2w, 2w+1 interleaved; even-NJ templates ----
    {
        const int njn = (t >> 7) + 1;          // needed dwords: 1..12
        switch ((njn + 1) & ~1) {              // round up to even
        case 2:  entmax_pair<2 >(scb, wave, lane, t); break;
        case 4:  entmax_pair<4 >(scb, wave, lane, t); break;
        case 6:  entmax_pair<6 >(scb, wave, lane, t); break;
        case 8:  entmax_pair<8 >(scb, wave, lane, t); break;
        case 10: entmax_pair<10>(scb, wave, lane, t); break;
        default: entmax_pair<12>(scb, wave, lane, t); break;
        }
    }
    __syncthreads();

    // ---- w_avg via v_pk_add_f16 -> logs; acc16 += w_avg * v_comb ----
    float4 A0 = make_float4(0,0,0,0), A1 = A0, A2 = A0, A3 = A0;
    float* lrow = logs + rowq * TT_;
    const unsigned* __restrict__ rp0 = (const unsigned*)scb;
    #pragma unroll
    for (int it = 0; it < 3; ++it) {
        const int dwi = tid + 256 * it;       // 0..767
        const int s0 = 2 * dwi;
        if (s0 <= t) {
            h2 hs = __builtin_bit_cast(h2, rp0[dwi]);
            #pragma unroll
            for (int h = 1; h < H_; ++h)
                hs = hs + __builtin_bit_cast(h2, rp0[h * (SCP_ / 2) + dwi]);
            const float wa0 = (float)hs[0] * 0.125f;
            const float wa1 = (float)hs[1] * 0.125f;  // 0 beyond t
            {
                const float4* vp = (const float4*)(vcomb + (bbase + s0) * DK_);
                const float4 v0 = vp[0], v1 = vp[1], v2 = vp[2], v3 = vp[3];
                A0.x = fmaf(wa0, v0.x, A0.x); A0.y = fmaf(wa0, v0.y, A0.y);
                A0.z = fmaf(wa0, v0.z, A0.z); A0.w = fmaf(wa0, v0.w, A0.w);
                A1.x = fmaf(wa0, v1.x, A1.x); A1.y = fmaf(wa0, v1.y, A1.y);
                A1.z = fmaf(wa0, v1.z, A1.z); A1.w = fmaf(wa0, v1.w, A1.w);
                A2.x = fmaf(wa0, v2.x, A2.x); A2.y = fmaf(wa0, v2.y, A2.y);
                A2.z = fmaf(wa0, v2.z, A2.z); A2.w = fmaf(wa0, v2.w, A2.w);
                A3.x = fmaf(wa0, v3.x, A3.x); A3.y = fmaf(wa0, v3.y, A3.y);
                A3.z = fmaf(wa0, v3.z, A3.z); A3.w = fmaf(wa0, v3.w, A3.w);
            }
            if (s0 + 1 <= t) {
                const float4* vp = (const float4*)(vcomb + (bbase + s0 + 1) * DK_);
                const float4 v0 = vp[0], v1 = vp[1], v2 = vp[2], v3 = vp[3];
                A0.x = fmaf(wa1, v0.x, A0.x); A0.y = fmaf(wa1, v0.y, A0.y);
                A0.z = fmaf(wa1, v0.z, A0.z); A0.w = fmaf(wa1, v0.w, A0.w);
                A1.x = fmaf(wa1, v1.x, A1.x); A1.y = fmaf(wa1, v1.y, A1.y);
                A1.z = fmaf(wa1, v1.z, A1.z); A1.w = fmaf(wa1, v1.w, A1.w);
                A2.x = fmaf(wa1, v2.x, A2.x); A2.y = fmaf(wa1, v2.y, A2.y);
                A2.z = fmaf(wa1, v2.z, A2.z); A2.w = fmaf(wa1, v2.w, A2.w);
                A3.x = fmaf(wa1, v3.x, A3.x); A3.y = fmaf(wa1, v3.y, A3.y);
                A3.z = fmaf(wa1, v3.z, A3.z); A3.w = fmaf(wa1, v3.w, A3.w);
            }
            *(float2*)(lrow + s0) = make_float2(wa0, wa1);
        } else {
            *(float2*)(lrow + s0) = make_float2(0.f, 0.f);
        }
    }
    A0.x = wave_sum_l63(A0.x); A0.y = wave_sum_l63(A0.y);
    A0.z = wave_sum_l63(A0.z); A0.w = wave_sum_l63(A0.w);
    A1.x = wave_sum_l63(A1.x); A1.y = wave_sum_l63(A1.y);
    A1.z = wave_sum_l63(A1.z); A1.w = wave_sum_l63(A1.w);
    A2.x = wave_sum_l63(A2.x); A2.y = wave_sum_l63(A2.y);
    A2.z = wave_sum_l63(A2.z); A2.w = wave_sum_l63(A2.w);
    A3.x = wave_sum_l63(A3.x); A3.y = wave_sum_l63(A3.y);
    A3.z = wave_sum_l63(A3.z); A3.w = wave_sum_l63(A3.w);
    if (lane == 63) {
        float* r = red + wave * 16;
        r[0]=A0.x; r[1]=A0.y; r[2]=A0.z; r[3]=A0.w;
        r[4]=A1.x; r[5]=A1.y; r[6]=A1.z; r[7]=A1.w;
        r[8]=A2.x; r[9]=A2.y; r[10]=A2.z; r[11]=A2.w;
        r[12]=A3.x; r[13]=A3.y; r[14]=A3.z; r[15]=A3.w;
    }
    __syncthreads();
    if (tid < DK_) o16[tid] = red[tid] + red[16 + tid] + red[32 + tid] + red[48 + tid];
    __syncthreads();

    // ---- @Wo + bo, residual, LN1 (single-pass mean/var) ----
    float y = 0.f;
    if (tid < D_) {
        float a = bo[tid];
        #pragma unroll
        for (int j = 0; j < DK_; ++j) a = fmaf(o16[j], Wo[j * D_ + tid], a);
        y = xin[rowq * D_ + tid] + a;
        yrow[tid] = y;
    }
    __syncthreads();
    if (tid < 64) {
        const float y0 = yrow[tid], y1 = yrow[tid + 64];
        float sm = wave_sum_l63(y0 + y1);
        float sq = wave_sum_l63(fmaf(y0, y0, y1 * y1));
        if (tid == 63) {
            const float mean = sm * (1.0f / D_);
            stat[0] = mean;
            stat[1] = fmaxf(sq * (1.0f / D_) - mean * mean, 0.f);
        }
    }
    __syncthreads();
    if (tid < D_) {
        const float r = rsqrtf(stat[1] + 1e-5f);
        xout[rowq * D_ + tid] = (y - stat[0]) * r * lng[tid] + lnb[tid];
    }
}

// =======================================================================
// FFN + LN2 (+ fused next-layer QKV, or final projection).
// R20: GEMM1/GEMM2/QKV via packed-f16 dot2 (reduction-dim pairs).
// GEMM1 thread owns cols (2t, 2t+1) -> produces the h-pair directly;
// h stored packed in hb2[r][j2] (writes conflict-free, reads broadcast).
// Instruction count in the three inner loops ~halves vs f32.
// =======================================================================
__global__ __launch_bounds__(256) void ffn_kernel(
    const float* __restrict__ xin, float* __restrict__ xout,
    const unsigned* __restrict__ fh1l, const float* __restrict__ fb1,
    const unsigned* __restrict__ fh2l, const float* __restrict__ fb2,
    const float* __restrict__ g, const float* __restrict__ bta,
    int do_qkv,
    const unsigned* __restrict__ whq_nl, const float* __restrict__ bq,
    const unsigned* __restrict__ whk_nl, const float* __restrict__ bk,
    const float* __restrict__ wvc, const float* __restrict__ bvc,
    _Float16* __restrict__ q16, _Float16* __restrict__ k16,
    float* __restrict__ vc,
    int do_proj, const float* __restrict__ pw,
    const float* __restrict__ pb, float* __restrict__ outp)
{
    __shared__ float xrT[D_][4];         // [i][r]  2 KB (f32, for residual)
    __shared__ unsigned xh2[D_ / 2][4];  // packed x pairs  1 KB
    __shared__ unsigned hb2[4 * (DFF_ / 2)];  // packed h [r*256+j2]  4 KB
    __shared__ float pred[2][4][D_];     //         4 KB (GEMM2 partials)
    __shared__ float yb[4][D_];          //         2 KB
    __shared__ float xn[D_];             // last-row normalized (proj) 0.5 KB

    const long row0 = (long)blockIdx.x * 4;
    const int tid = threadIdx.x;

    for (int idx = tid; idx < 4 * D_; idx += 256) {
        const int r = idx >> 7, i = idx & 127;
        xrT[i][r] = xin[row0 * D_ + idx];
    }
    __syncthreads();
    {
        const int i2 = tid >> 2, r = tid & 3;
        xh2[i2][r] = pack2h(xrT[2 * i2][r], xrT[2 * i2 + 1][r]);
    }
    __syncthreads();

    // GEMM1 + relu: thread owns cols 2t, 2t+1 (packed dot2)
    {
        const int c2 = tid;                      // pair index 0..255
        const uint2* __restrict__ wp2 = (const uint2*)fh1l;
        float4 aE = make_float4(0,0,0,0), aO = aE;
        for (int i2 = 0; i2 < D_ / 2; ++i2) {
            const uint2 w = wp2[i2 * 256 + c2];
            const h2 wE = __builtin_bit_cast(h2, w.x);
            const h2 wO = __builtin_bit_cast(h2, w.y);
            const uint4 xp = *(const uint4*)&xh2[i2][0];
            const h2 x0 = __builtin_bit_cast(h2, xp.x);
            const h2 x1 = __builtin_bit_cast(h2, xp.y);
            const h2 x2 = __builtin_bit_cast(h2, xp.z);
            const h2 x3 = __builtin_bit_cast(h2, xp.w);
            aE.x = dot2f(wE, x0, aE.x); aE.y = dot2f(wE, x1, aE.y);
            aE.z = dot2f(wE, x2, aE.z); aE.w = dot2f(wE, x3, aE.w);
            aO.x = dot2f(wO, x0, aO.x); aO.y = dot2f(wO, x1, aO.y);
            aO.z = dot2f(wO, x2, aO.z); aO.w = dot2f(wO, x3, aO.w);
        }
        const float bE = fb1[2 * c2], bO = fb1[2 * c2 + 1];
        hb2[0 * 256 + c2] = pack2h(fmaxf(aE.x + bE, 0.f), fmaxf(aO.x + bO, 0.f));
        hb2[1 * 256 + c2] = pack2h(fmaxf(aE.y + bE, 0.f), fmaxf(aO.y + bO, 0.f));
        hb2[2 * 256 + c2] = pack2h(fmaxf(aE.z + bE, 0.f), fmaxf(aO.z + bO, 0.f));
        hb2[3 * 256 + c2] = pack2h(fmaxf(aE.w + bE, 0.f), fmaxf(aO.w + bO, 0.f));
    }
    __syncthreads();

    // GEMM2 partials: thread (d, half), 128 j-pairs each (packed dot2)
    {
        const int d = tid & 127;
        const int half = tid >> 7;
        float a0 = 0.f, a1 = 0.f, a2 = 0.f, a3 = 0.f;
        for (int j2 = half * 128; j2 < half * 128 + 128; ++j2) {
            const h2 w = __builtin_bit_cast(h2, fh2l[j2 * D_ + d]);
            a0 = dot2f(w, __builtin_bit_cast(h2, hb2[0 * 256 + j2]), a0);
            a1 = dot2f(w, __builtin_bit_cast(h2, hb2[1 * 256 + j2]), a1);
            a2 = dot2f(w, __builtin_bit_cast(h2, hb2[2 * 256 + j2]), a2);
            a3 = dot2f(w, __builtin_bit_cast(h2, hb2[3 * 256 + j2]), a3);
        }
        pred[half][0][d] = a0; pred[half][1][d] = a1;
        pred[half][2][d] = a2; pred[half][3][d] = a3;
    }
    __syncthreads();

    // combine + bias + residual: thread owns (d, 2 rows)
    {
        const int d = tid & 127;
        const int r0 = (tid >> 7) * 2;
        const float bb = fb2[d];
        yb[r0 + 0][d] = pred[0][r0 + 0][d] + pred[1][r0 + 0][d] + bb + xrT[d][r0 + 0];
        yb[r0 + 1][d] = pred[0][r0 + 1][d] + pred[1][r0 + 1][d] + bb + xrT[d][r0 + 1];
    }
    __syncthreads();

    // LN per row (single-pass): wave w handles row w; normalized -> xrT
    const int w = tid >> 6, lane = tid & 63;
    const bool pblk = do_proj && (((row0 + 4) % TT_) == 0);
    {
        const float y0 = yb[w][lane], y1 = yb[w][lane + 64];
        const float sm = wave_sum(y0 + y1);
        const float sq = wave_sum(fmaf(y0, y0, y1 * y1));
        const float mean = sm * (1.0f / D_);
        const float var  = fmaxf(sq * (1.0f / D_) - mean * mean, 0.f);
        const float rcp = rsqrtf(var + 1e-5f);
        const float o0 = (y0 - mean) * rcp * g[lane]      + bta[lane];
        const float o1 = (y1 - mean) * rcp * g[lane + 64] + bta[lane + 64];
        xout[(row0 + w) * D_ + lane]      = o0;
        xout[(row0 + w) * D_ + lane + 64] = o1;
        xrT[lane][w]      = o0;           // re-stash for fused qkv
        xrT[lane + 64][w] = o1;
        if (pblk && w == 3) { xn[lane] = o0; xn[lane + 64] = o1; }
    }

    if (do_qkv) {
        __syncthreads();   // xrT now holds the 4 normalized rows
        {
            const int i2 = tid >> 2, r = tid & 3;
            xh2[i2][r] = pack2h(xrT[2 * i2][r], xrT[2 * i2 + 1][r]);
        }
        __syncthreads();
        const int c = tid & 127;
        const int which = tid >> 7;             // 0: q, 1: k (wave-uniform)
        const unsigned* __restrict__ Wp = which ? whk_nl : whq_nl;
        const float bb = which ? bk[c] : bq[c];
        float a0 = bb, a1 = bb, a2 = bb, a3 = bb;
        for (int i2 = 0; i2 < D_ / 2; ++i2) {
            const h2 wv = __builtin_bit_cast(h2, Wp[i2 * D_ + c]);
            const uint4 xp = *(const uint4*)&xh2[i2][0];
            a0 = dot2f(wv, __builtin_bit_cast(h2, xp.x), a0);
            a1 = dot2f(wv, __builtin_bit_cast(h2, xp.y), a1);
            a2 = dot2f(wv, __builtin_bit_cast(h2, xp.z), a2);
            a3 = dot2f(wv, __builtin_bit_cast(h2, xp.w), a3);
        }
        _Float16* __restrict__ dst = which ? k16 : q16;
        dst[(row0 + 0) * D_ + c] = (_Float16)a0;
        dst[(row0 + 1) * D_ + c] = (_Float16)a1;
        dst[(row0 + 2) * D_ + c] = (_Float16)a2;
        dst[(row0 + 3) * D_ + c] = (_Float16)a3;

        if (tid < 64) {
            const int r = tid >> 4, c16 = tid & 15;
            float av = bvc[c16];
            for (int i = 0; i < D_; ++i)
                av = fmaf(xrT[i][r], wvc[i * DK_ + c16], av);
            vc[(row0 + r) * DK_ + c16] = av;
        }
    }

    if (pblk) {
        __syncthreads();   // block-uniform condition — safe
        const int b = (int)((row0 + 3) / TT_);
        for (int idx = tid; idx < NQ_ * HOR_; idx += 256) {
            const int qq = idx / HOR_, hh = idx - qq * HOR_;
            float s = pb[idx];
            for (int d = 0; d < D_; ++d)
                s = fmaf(xn[d], pw[((long)qq * D_ + d) * HOR_ + hh], s);
            outp[b * NQ_ * HOR_ + idx] = s;
        }
    }
}

} // namespace

extern "C" void kernel_launch(void* const* d_in, const int* in_sizes, int n_in,
                              void* d_out, int out_size, void* d_ws, size_t ws_size,
                              hipStream_t stream) {
    (void)in_sizes; (void)n_in; (void)out_size; (void)ws_size;

    const float* x_cond = (const float*)d_in[0];
    const float* x_pred = (const float*)d_in[1];
    const float* cw_c   = (const float*)d_in[2];
    const float* cb_c   = (const float*)d_in[3];
    const float* sw_c   = (const float*)d_in[4];
    const float* sb_c   = (const float*)d_in[5];
    const float* cw_p   = (const float*)d_in[6];
    const float* cb_p   = (const float*)d_in[7];
    const float* sw_p   = (const float*)d_in[8];
    const float* sb_p   = (const float*)d_in[9];
    const float* Wq     = (const float*)d_in[10];
    const float* bq     = (const float*)d_in[11];
    const float* Wk     = (const float*)d_in[12];
    const float* bk     = (const float*)d_in[13];
    const float* Wv     = (const float*)d_in[14];
    const float* bv     = (const float*)d_in[15];
    const float* Wo     = (const float*)d_in[16];
    const float* bo     = (const float*)d_in[17];
    const float* ln1g   = (const float*)d_in[18];
    const float* ln1b   = (const float*)d_in[19];
    const float* fw1    = (const float*)d_in[20];
    const float* fb1    = (const float*)d_in[21];
    const float* fw2    = (const float*)d_in[22];
    const float* fb2    = (const float*)d_in[23];
    const float* ln2g   = (const float*)d_in[24];
    const float* ln2b   = (const float*)d_in[25];
    const float* pw     = (const float*)d_in[26];
    const float* pb     = (const float*)d_in[27];

    float* outp = (float*)d_out;
    float* ws   = (float*)d_ws;
    float*     xA   = ws + WS_XA;
    float*     xB   = ws + WS_XB;
    _Float16*  q16  = (_Float16*)(ws + WS_Q16);
    _Float16*  k16  = (_Float16*)(ws + WS_K16);
    float*     vcb  = ws + WS_VC;
    float*     wvc  = ws + WS_WVC;
    float*     bvc  = ws + WS_BVC;
    unsigned*  fh1  = (unsigned*)(ws + WS_FH1);
    unsigned*  fh2  = (unsigned*)(ws + WS_FH2);
    unsigned*  whq  = (unsigned*)(ws + WS_WHQ);
    unsigned*  whk  = (unsigned*)(ws + WS_WHK);

    // Wv head-mean + packed-f16 weight conversions (must precede pre/ffn)
    prep_kernel<<<128, 256, 0, stream>>>(Wv, bv, wvc, bvc,
                                         fw1, fw2, Wq, Wk,
                                         fh1, fh2, whq, whk);

    // selectors + layer-0 QKV, one launch (R19: 4 tokens per block)
    pre_kernel<<<(NB_ * TC_ + NB_ * TP_) / 4, 256, 0, stream>>>(
        x_cond, cw_c, cb_c, sw_c, sb_c,
        x_pred, cw_p, cb_p, sw_p, sb_p,
        outp + OFF_VC, outp + OFF_VP, xA,
        whq, bq, whk, bk, wvc, bvc, q16, k16, vcb);

    for (int l = 0; l < L_; ++l) {
        attn_kernel<<<NB_ * TT_, 256, 0, stream>>>(
            q16, k16, vcb, xA, xB,
            Wo + (long)l * DK_ * D_, bo + l * D_,
            ln1g + l * D_, ln1b + l * D_,
            outp + OFF_LOGS + (long)l * NB_ * TT_ * TT_);
        const int nl = l + 1;
        const int more = (l < L_ - 1);
        ffn_kernel<<<NB_ * TT_ / 4, 256, 0, stream>>>(
            xB, xA, fh1 + (long)l * FH1_L, fb1 + l * DFF_,
            fh2 + (long)l * FH2_L, fb2 + l * D_,
            ln2g + l * D_, ln2b + l * D_,
            more,
            whq + (long)nl * WHQ_L * more, bq + nl * D_ * more,
            whk + (long)nl * WHQ_L * more, bk + nl * D_ * more,
            wvc + nl * D_ * DK_ * more, bvc + nl * DK_ * more,
            q16, k16, vcb,
            (l == L_ - 1) ? 1 : 0, pw, pb, outp);
    }
}

// Round 6
// 310.787 us; speedup vs baseline: 1.0799x; 1.0799x over previous
//
#include <hip/hip_runtime.h>

namespace {

constexpr int NB_  = 2;
constexpr int TC_  = 1024;
constexpr int TP_  = 512;
constexpr int TT_  = 1536;   // TC + TP
constexpr int D_   = 128;
constexpr int H_   = 8;
constexpr int DK_  = 16;
constexpr int DFF_ = 512;
constexpr int L_   = 2;
constexpr int HOR_ = 96;
constexpr int NQ_  = 3;

constexpr int SCP_ = TT_ + 8;   // ushort stride per head row (even → dword-tiled)

typedef _Float16 h2 __attribute__((ext_vector_type(2)));

// ---- output float offsets (return order: out, v_cond, v_pred, logs) ----
constexpr int OFF_OUT  = 0;
constexpr int OFF_VC   = NB_ * NQ_ * HOR_;            // 576
constexpr int OFF_VP   = OFF_VC + NB_ * TC_ * 8;      // 16960
constexpr int OFF_LOGS = OFF_VP + NB_ * TP_ * 4;      // 21056

// ---- workspace float offsets ----
constexpr int WS_XA  = 0;
constexpr int WS_XB  = WS_XA  + NB_ * TT_ * D_;       // 393216
constexpr int WS_Q16 = WS_XB  + NB_ * TT_ * D_;       // f16, half-sized
constexpr int WS_K16 = WS_Q16 + NB_ * TT_ * D_ / 2;
constexpr int WS_VC  = WS_K16 + NB_ * TT_ * D_ / 2;
constexpr int WS_WVC = WS_VC  + NB_ * TT_ * DK_;      // 2 layers x 2048
constexpr int WS_BVC = WS_WVC + L_ * D_ * DK_;        // 2 layers x 16

__device__ inline float dot2f(h2 a, h2 b, float c) {
#if __has_builtin(__builtin_amdgcn_fdot2)
    return __builtin_amdgcn_fdot2(a, b, c, false);
#else
    return c + (float)a[0] * (float)b[0] + (float)a[1] * (float)b[1];
#endif
}

__device__ inline unsigned pack2h(float a, float b) {   // 1 inst: v_cvt_pkrtz
#if __has_builtin(__builtin_amdgcn_cvt_pkrtz)
    return __builtin_bit_cast(unsigned, __builtin_amdgcn_cvt_pkrtz(a, b));
#else
    h2 p; p[0] = (_Float16)a; p[1] = (_Float16)b;
    return __builtin_bit_cast(unsigned, p);
#endif
}

__device__ inline float fast_rcp(float x) {             // v_rcp_f32, 1 inst
#if __has_builtin(__builtin_amdgcn_rcpf)
    return __builtin_amdgcn_rcpf(x);
#else
    return 1.0f / x;
#endif
}

// =======================================================================
// DPP wave reductions — VALU pipe (R16: attn 79->64 µs).
// NOTE (R17/R20 lesson): packed-f16 fdot2 rewrites of f32 VALU loops
// REGRESSED twice on this chip (attn Newton 64->82; ffn/pre +35 µs).
// Do not reintroduce dot2 math outside the attn score phase.
// =======================================================================
template <int CTRL>
__device__ inline float dpp_add(float x) {
    const int y = __builtin_amdgcn_update_dpp(
        0, __builtin_bit_cast(int, x), CTRL, 0xF, 0xF, true);
    return x + __builtin_bit_cast(float, y);
}
template <int CTRL>
__device__ inline float dpp_maxf(float x) {
    const int y = __builtin_amdgcn_update_dpp(
        __builtin_bit_cast(int, x), __builtin_bit_cast(int, x),
        CTRL, 0xF, 0xF, false);
    return fmaxf(x, __builtin_bit_cast(float, y));
}
__device__ inline float bcast63(float x) {
    return __builtin_bit_cast(float,
        __builtin_amdgcn_readlane(__builtin_bit_cast(int, x), 63));
}
__device__ inline float wave_sum_l63(float x) {
    x = dpp_add<0x111>(x); x = dpp_add<0x112>(x); x = dpp_add<0x114>(x);
    x = dpp_add<0x118>(x); x = dpp_add<0x142>(x); x = dpp_add<0x143>(x);
    return x;
}
__device__ inline float wave_sum(float x) { return bcast63(wave_sum_l63(x)); }
__device__ inline float wave_max(float x) {
    x = dpp_maxf<0x111>(x); x = dpp_maxf<0x112>(x); x = dpp_maxf<0x114>(x);
    x = dpp_maxf<0x118>(x); x = dpp_maxf<0x142>(x); x = dpp_maxf<0x143>(x);
    return bcast63(x);
}

// =======================================================================
// Wv head-mean prep (tiny separate launch so wvc/bvc are ready before
// pre_kernel's fused QKV — no intra-kernel block-ordering assumption).
// =======================================================================
__global__ __launch_bounds__(128) void prep_wvc_kernel(
    const float* __restrict__ Wv, const float* __restrict__ bv,
    float* __restrict__ wvc, float* __restrict__ bvc)
{
    const int l = blockIdx.x;
    const float* W  = Wv + (long)l * D_ * D_;
    const float* bb = bv + l * D_;
    float* wv = wvc + l * D_ * DK_;
    float* bo = bvc + l * DK_;
    const int tid = threadIdx.x;
    for (int idx = tid; idx < D_ * DK_; idx += 128) {
        const int i = idx >> 4, dk = idx & 15;
        float s = 0.f;
        #pragma unroll
        for (int hh = 0; hh < H_; ++hh) s += W[i * D_ + hh * DK_ + dk];
        wv[idx] = s * 0.125f;
    }
    if (tid < DK_) {
        float s = 0.f;
        #pragma unroll
        for (int hh = 0; hh < H_; ++hh) s += bb[hh * DK_ + tid];
        bo[tid] = s * 0.125f;
    }
}

// =======================================================================
// Selector + fused layer-0 QKV — R19: 4 tokens/block (768 blocks), one
// wave per token for the selector (lane covers dims d and d+64; Newton
// run redundantly by all 64 lanes), then ffn's do_qkv pattern over the
// 4 staged rows (1 load : 4 FMA).  [R19: total 309 -> 300]
// =======================================================================
template <int NV>
__device__ inline void selector_qkv_body(
    const float* __restrict__ x, const float* __restrict__ cw,
    const float* __restrict__ cb, const float* __restrict__ sw,
    const float* __restrict__ sb, float* __restrict__ vout,
    float* __restrict__ xout, int Tsel, int row_off, int blk,
    const float* __restrict__ Wq, const float* __restrict__ bq,
    const float* __restrict__ Wk, const float* __restrict__ bk,
    const float* __restrict__ wvc, const float* __restrict__ bvc,
    _Float16* __restrict__ q16, _Float16* __restrict__ k16,
    float* __restrict__ vc)
{
    const int tpb = Tsel / 4;            // token-groups per batch
    const int b   = blk / tpb;
    const int t0  = (blk - b * tpb) * 4;
    const int tid = threadIdx.x;
    const int lane = tid & 63, wave = tid >> 6;
    const int t = t0 + wave;             // this wave's token

    __shared__ float xrT[D_][4];         // staged selector outputs [d][r]

    // ---- selector: lane covers dims d0 = lane, d1 = lane + 64 ----
    const int d0 = lane, d1 = lane + 64;
    float xw[3 * NV];
    #pragma unroll
    for (int kk = 0; kk < 3; ++kk) {
        const int ts = t + kk - 2;
        #pragma unroll
        for (int v = 0; v < NV; ++v)
            xw[kk * NV + v] = (ts >= 0) ? x[((long)b * Tsel + ts) * NV + v] : 0.0f;
    }
    float ls0[NV], ls1[NV];
    #pragma unroll
    for (int v = 0; v < NV; ++v) {
        const float* c0 = cw + ((long)(v * D_ + d0)) * 3;
        const float* c1 = cw + ((long)(v * D_ + d1)) * 3;
        float a0 = cb[v * D_ + d0], a1 = cb[v * D_ + d1];
        a0 = fmaf(xw[0*NV+v], c0[0], a0); a1 = fmaf(xw[0*NV+v], c1[0], a1);
        a0 = fmaf(xw[1*NV+v], c0[1], a0); a1 = fmaf(xw[1*NV+v], c1[1], a1);
        a0 = fmaf(xw[2*NV+v], c0[2], a0); a1 = fmaf(xw[2*NV+v], c1[2], a1);
        ls0[v] = a0; ls1[v] = a1;
    }
    float u[NV];
    {
        const float s0 = sw[d0], s1 = sw[d1];
        #pragma unroll
        for (int v = 0; v < NV; ++v)
            u[v] = wave_sum(fmaf(ls1[v], s1, ls0[v] * s0));
    }
    // tiny entmax Newton, run redundantly by all 64 lanes (no divergence)
    float wls[NV];
    {
        float m = -1e30f;
        #pragma unroll
        for (int v = 0; v < NV; ++v) {
            float s = u[v] + sb[0];
            s = fminf(fmaxf(s, -10.0f), 10.0f);
            u[v] = 0.5f * s;
            m = fmaxf(m, u[v]);
        }
        float tau = m - 1.0f;
        for (int it = 0; it < 12; ++it) {
            float S1 = 0.f, S2 = 0.f;
            #pragma unroll
            for (int v = 0; v < NV; ++v) {
                float dd = fmaxf(u[v] - tau, 0.f);
                S1 += dd; S2 = fmaf(dd, dd, S2);
            }
            tau += (S2 - 1.0f) * 0.5f * fast_rcp(S1);   // self-correcting
        }
        float S1 = 0.f, S2 = 0.f, K = 0.f;
        #pragma unroll
        for (int v = 0; v < NV; ++v) {
            if (u[v] > tau) { S1 += u[v]; S2 = fmaf(u[v], u[v], S2); K += 1.f; }
        }
        const float mean = S1 / K;
        const float arg  = fmaxf(fmaf(mean, mean, -(S2 - 1.0f) / K), 0.f);
        tau = mean - sqrtf(arg);
        #pragma unroll
        for (int v = 0; v < NV; ++v) {
            const float dd = fmaxf(u[v] - tau, 0.f);
            wls[v] = dd * dd;
        }
    }
    float acc0 = 0.f, acc1 = 0.f;
    #pragma unroll
    for (int v = 0; v < NV; ++v) {
        acc0 = fmaf(ls0[v], wls[v], acc0);
        acc1 = fmaf(ls1[v], wls[v], acc1);
    }
    const long rowb = (long)b * TT_ + row_off + t0;   // block's first row
    const long row  = rowb + wave;
    xout[row * D_ + d0] = acc0;
    xout[row * D_ + d1] = acc1;
    xrT[d0][wave] = acc0;
    xrT[d1][wave] = acc1;
    if (lane == 0) {
        #pragma unroll
        for (int v = 0; v < NV; ++v)
            vout[((long)b * Tsel + t) * NV + v] = wls[v];
    }
    __syncthreads();

    // ---- fused layer-0 QKV over 4 staged rows (ffn do_qkv pattern) ----
    {
        const int c = tid & 127;
        const int which = tid >> 7;             // 0: q, 1: k (wave-uniform)
        const float* __restrict__ W = which ? Wk : Wq;
        const float bb = which ? bk[c] : bq[c];
        float a0 = bb, a1 = bb, a2 = bb, a3 = bb;
        for (int i = 0; i < D_; ++i) {
            const float wv = W[i * D_ + c];
            const float4 xv = *(const float4*)&xrT[i][0];
            a0 = fmaf(xv.x, wv, a0);
            a1 = fmaf(xv.y, wv, a1);
            a2 = fmaf(xv.z, wv, a2);
            a3 = fmaf(xv.w, wv, a3);
        }
        _Float16* __restrict__ dst = which ? k16 : q16;
        dst[(rowb + 0) * D_ + c] = (_Float16)a0;
        dst[(rowb + 1) * D_ + c] = (_Float16)a1;
        dst[(rowb + 2) * D_ + c] = (_Float16)a2;
        dst[(rowb + 3) * D_ + c] = (_Float16)a3;
    }
    if (tid < 64) {
        const int r = tid >> 4, c16 = tid & 15;
        float av = bvc[c16];
        for (int i = 0; i < D_; ++i)
            av = fmaf(xrT[i][r], wvc[i * DK_ + c16], av);
        vc[(rowb + r) * DK_ + c16] = av;
    }
}

__global__ __launch_bounds__(256) void pre_kernel(
    const float* __restrict__ x_cond, const float* __restrict__ cw_c,
    const float* __restrict__ cb_c, const float* __restrict__ sw_c,
    const float* __restrict__ sb_c,
    const float* __restrict__ x_pred, const float* __restrict__ cw_p,
    const float* __restrict__ cb_p, const float* __restrict__ sw_p,
    const float* __restrict__ sb_p,
    float* __restrict__ vc_out, float* __restrict__ vp_out,
    float* __restrict__ xout,
    const float* __restrict__ Wq, const float* __restrict__ bq,
    const float* __restrict__ Wk, const float* __restrict__ bk,
    const float* __restrict__ wvc, const float* __restrict__ bvc,
    _Float16* __restrict__ q16, _Float16* __restrict__ k16,
    float* __restrict__ vc)
{
    const int blk = blockIdx.x;
    if (blk < NB_ * TC_ / 4) {
        selector_qkv_body<8>(x_cond, cw_c, cb_c, sw_c, sb_c, vc_out, xout,
                             TC_, 0, blk, Wq, bq, Wk, bk, wvc, bvc,
                             q16, k16, vc);
    } else {
        selector_qkv_body<4>(x_pred, cw_p, cb_p, sw_p, sb_p, vp_out, xout,
                             TP_, TC_, blk - NB_ * TC_ / 4,
                             Wq, bq, Wk, bk, wvc, bvc, q16, k16, vc);
    }
}

// =======================================================================
// entmax15 Newton, TWO head rows per wave INTERLEAVED (R18, 62.4 µs).
// R17 packed-f16 Newton regressed — scalar f32 retained.
// =======================================================================
template <int NJ>
__device__ inline void entmax_head2(unsigned short* __restrict__ sa,
                                    unsigned short* __restrict__ sb,
                                    int lane, int t)
{
    const unsigned* __restrict__ rpa = (const unsigned*)sa;
    const unsigned* __restrict__ rpb = (const unsigned*)sb;
    float va[2 * NJ], vb[2 * NJ];
    #pragma unroll
    for (int j = 0; j < NJ; ++j) {
        const unsigned dwa = rpa[64 * j + lane];
        const unsigned dwb = rpb[64 * j + lane];
        const h2 ha = __builtin_bit_cast(h2, dwa);
        const h2 hb = __builtin_bit_cast(h2, dwb);
        const int s0 = 128 * j + 2 * lane;
        const bool in0 = (s0 <= t), in1 = (s0 + 1 <= t);
        va[2*j]   = in0 ? (float)ha[0] : -1e30f;
        va[2*j+1] = in1 ? (float)ha[1] : -1e30f;
        vb[2*j]   = in0 ? (float)hb[0] : -1e30f;
        vb[2*j+1] = in1 ? (float)hb[1] : -1e30f;
    }

    float ma0 = va[0], ma1 = va[1], mb0 = vb[0], mb1 = vb[1];
    #pragma unroll
    for (int j = 2; j < 2 * NJ; j += 2) {
        ma0 = fmaxf(ma0, va[j]); ma1 = fmaxf(ma1, va[j+1]);
        mb0 = fmaxf(mb0, vb[j]); mb1 = fmaxf(mb1, vb[j+1]);
    }
    const float ma = wave_max(fmaxf(ma0, ma1));
    const float mb = wave_max(fmaxf(mb0, mb1));

    float ta = ma - 1.0f, tb = mb - 1.0f;   // f(tau0) >= 0
    #pragma unroll
    for (int it = 0; it < 7; ++it) {
        float a10 = 0.f, a11 = 0.f, a20 = 0.f, a21 = 0.f;
        float b10 = 0.f, b11 = 0.f, b20 = 0.f, b21 = 0.f;
        #pragma unroll
        for (int j = 0; j < 2 * NJ; j += 2) {
            const float da0 = fmaxf(va[j]   - ta, 0.f);
            const float da1 = fmaxf(va[j+1] - ta, 0.f);
            const float db0 = fmaxf(vb[j]   - tb, 0.f);
            const float db1 = fmaxf(vb[j+1] - tb, 0.f);
            a10 += da0; a11 += da1;
            a20 = fmaf(da0, da0, a20); a21 = fmaf(da1, da1, a21);
            b10 += db0; b11 += db1;
            b20 = fmaf(db0, db0, b20); b21 = fmaf(db1, db1, b21);
        }
        const float S1a = wave_sum(a10 + a11);
        const float S2a = wave_sum(a20 + a21);
        const float S1b = wave_sum(b10 + b11);
        const float S2b = wave_sum(b20 + b21);
        ta += (S2a - 1.0f) * 0.5f * fast_rcp(S1a);
        tb += (S2b - 1.0f) * 0.5f * fast_rcp(S1b);
    }
    {
        float a1 = 0.f, a2 = 0.f, ka = 0.f;
        float b1 = 0.f, b2 = 0.f, kb = 0.f;
        #pragma unroll
        for (int j = 0; j < 2 * NJ; ++j) {
            if (va[j] > ta) { a1 += va[j]; a2 = fmaf(va[j], va[j], a2); ka += 1.f; }
            if (vb[j] > tb) { b1 += vb[j]; b2 = fmaf(vb[j], vb[j], b2); kb += 1.f; }
        }
        a1 = wave_sum(a1); a2 = wave_sum(a2); ka = wave_sum(ka);
        b1 = wave_sum(b1); b2 = wave_sum(b2); kb = wave_sum(kb);
        const float meana = a1 / ka;
        const float arga  = fmaxf(fmaf(meana, meana, -(a2 - 1.0f) / ka), 0.f);
        ta = meana - sqrtf(arga);
        const float meanb = b1 / kb;
        const float argb  = fmaxf(fmaf(meanb, meanb, -(b2 - 1.0f) / kb), 0.f);
        tb = meanb - sqrtf(argb);
    }
    unsigned* __restrict__ wpa = (unsigned*)sa;
    unsigned* __restrict__ wpb = (unsigned*)sb;
    #pragma unroll
    for (int j = 0; j < NJ; ++j) {
        const float da0 = fmaxf(va[2*j]   - ta, 0.f);
        const float da1 = fmaxf(va[2*j+1] - ta, 0.f);
        const float db0 = fmaxf(vb[2*j]   - tb, 0.f);
        const float db1 = fmaxf(vb[2*j+1] - tb, 0.f);
        wpa[64 * j + lane] = pack2h(da0 * da0, da1 * da1);
        wpb[64 * j + lane] = pack2h(db0 * db0, db1 * db1);
    }
}

template <int NJ>
__device__ inline void entmax_pair(unsigned short* __restrict__ scb,
                                   int wave, int lane, int t)
{
    entmax_head2<NJ>(scb + (wave * 2 + 0) * SCP_,
                     scb + (wave * 2 + 1) * SCP_, lane, t);
}

// =======================================================================
// Attention: one block (256 threads, 4 waves) per (b, t).  [R14 config]
// UNCHANGED since R18 (62.4 µs, VALUBusy ~64%). See R15-R18 notes.
// =======================================================================
__global__ __launch_bounds__(256) void attn_kernel(
    const _Float16* __restrict__ q16, const _Float16* __restrict__ k16,
    const float* __restrict__ vcomb, const float* __restrict__ xin,
    float* __restrict__ xout,
    const float* __restrict__ Wo, const float* __restrict__ bo,
    const float* __restrict__ lng, const float* __restrict__ lnb,
    float* __restrict__ logs)
{
    __shared__ unsigned short scb[H_ * SCP_];   // 24.7 KB f16 scores/weights
    __shared__ _Float16 qrow16[D_];
    __shared__ float red[64];
    __shared__ float o16[DK_];
    __shared__ float yrow[D_];
    __shared__ float stat[2];

    const int blk = blockIdx.x;
    const int t = TT_ - 1 - (blk >> 1);   // descending-work dispatch order
    const int b = blk & 1;
    const int tid = threadIdx.x;
    const int lane = tid & 63, wave = tid >> 6;
    const long rowq  = (long)b * TT_ + t;
    const long bbase = (long)b * TT_;

    if (tid < 64)
        ((unsigned*)qrow16)[tid] = ((const unsigned*)(q16 + rowq * D_))[tid];
    __syncthreads();

    // ---- scores: u = (q.k / 4) / 2 = dot * 0.125, f16 dot2, stored f16 ----
    {
        const int h  = tid & 7;
        const int sl = tid >> 3;   // 0..31
        unsigned short* __restrict__ srow = scb + h * SCP_;
        h2 qv[8];
        __builtin_memcpy(qv, (const _Float16*)qrow16 + h * DK_, 32);
        for (int s = sl; s <= t; s += 32) {
            float4 kk0, kk1;
            {
                const float4* kp4 = (const float4*)(k16 + (bbase + s) * D_ + h * DK_);
                kk0 = kp4[0]; kk1 = kp4[1];
            }
            h2 kh[8];
            __builtin_memcpy(kh,     &kk0, 16);
            __builtin_memcpy(kh + 4, &kk1, 16);
            float dot = 0.f;
            #pragma unroll
            for (int i2 = 0; i2 < 8; ++i2) dot = dot2f(qv[i2], kh[i2], dot);
            const _Float16 sh = (_Float16)(dot * 0.125f);
            srow[s] = __builtin_bit_cast(unsigned short, sh);
        }
    }
    __syncthreads();

    // ---- entmax15: wave w = heads 2w, 2w+1 interleaved; even-NJ templates ----
    {
        const int njn = (t >> 7) + 1;          // needed dwords: 1..12
        switch ((njn + 1) & ~1) {              // round up to even
        case 2:  entmax_pair<2 >(scb, wave, lane, t); break;
        case 4:  entmax_pair<4 >(scb, wave, lane, t); break;
        case 6:  entmax_pair<6 >(scb, wave, lane, t); break;
        case 8:  entmax_pair<8 >(scb, wave, lane, t); break;
        case 10: entmax_pair<10>(scb, wave, lane, t); break;
        default: entmax_pair<12>(scb, wave, lane, t); break;
        }
    }
    __syncthreads();

    // ---- w_avg via v_pk_add_f16 -> logs; acc16 += w_avg * v_comb ----
    float4 A0 = make_float4(0,0,0,0), A1 = A0, A2 = A0, A3 = A0;
    float* lrow = logs + rowq * TT_;
    const unsigned* __restrict__ rp0 = (const unsigned*)scb;
    #pragma unroll
    for (int it = 0; it < 3; ++it) {
        const int dwi = tid + 256 * it;       // 0..767
        const int s0 = 2 * dwi;
        if (s0 <= t) {
            h2 hs = __builtin_bit_cast(h2, rp0[dwi]);
            #pragma unroll
            for (int h = 1; h < H_; ++h)
                hs = hs + __builtin_bit_cast(h2, rp0[h * (SCP_ / 2) + dwi]);
            const float wa0 = (float)hs[0] * 0.125f;
            const float wa1 = (float)hs[1] * 0.125f;  // 0 beyond t
            {
                const float4* vp = (const float4*)(vcomb + (bbase + s0) * DK_);
                const float4 v0 = vp[0], v1 = vp[1], v2 = vp[2], v3 = vp[3];
                A0.x = fmaf(wa0, v0.x, A0.x); A0.y = fmaf(wa0, v0.y, A0.y);
                A0.z = fmaf(wa0, v0.z, A0.z); A0.w = fmaf(wa0, v0.w, A0.w);
                A1.x = fmaf(wa0, v1.x, A1.x); A1.y = fmaf(wa0, v1.y, A1.y);
                A1.z = fmaf(wa0, v1.z, A1.z); A1.w = fmaf(wa0, v1.w, A1.w);
                A2.x = fmaf(wa0, v2.x, A2.x); A2.y = fmaf(wa0, v2.y, A2.y);
                A2.z = fmaf(wa0, v2.z, A2.z); A2.w = fmaf(wa0, v2.w, A2.w);
                A3.x = fmaf(wa0, v3.x, A3.x); A3.y = fmaf(wa0, v3.y, A3.y);
                A3.z = fmaf(wa0, v3.z, A3.z); A3.w = fmaf(wa0, v3.w, A3.w);
            }
            if (s0 + 1 <= t) {
                const float4* vp = (const float4*)(vcomb + (bbase + s0 + 1) * DK_);
                const float4 v0 = vp[0], v1 = vp[1], v2 = vp[2], v3 = vp[3];
                A0.x = fmaf(wa1, v0.x, A0.x); A0.y = fmaf(wa1, v0.y, A0.y);
                A0.z = fmaf(wa1, v0.z, A0.z); A0.w = fmaf(wa1, v0.w, A0.w);
                A1.x = fmaf(wa1, v1.x, A1.x); A1.y = fmaf(wa1, v1.y, A1.y);
                A1.z = fmaf(wa1, v1.z, A1.z); A1.w = fmaf(wa1, v1.w, A1.w);
                A2.x = fmaf(wa1, v2.x, A2.x); A2.y = fmaf(wa1, v2.y, A2.y);
                A2.z = fmaf(wa1, v2.z, A2.z); A2.w = fmaf(wa1, v2.w, A2.w);
                A3.x = fmaf(wa1, v3.x, A3.x); A3.y = fmaf(wa1, v3.y, A3.y);
                A3.z = fmaf(wa1, v3.z, A3.z); A3.w = fmaf(wa1, v3.w, A3.w);
            }
            *(float2*)(lrow + s0) = make_float2(wa0, wa1);
        } else {
            *(float2*)(lrow + s0) = make_float2(0.f, 0.f);
        }
    }
    A0.x = wave_sum_l63(A0.x); A0.y = wave_sum_l63(A0.y);
    A0.z = wave_sum_l63(A0.z); A0.w = wave_sum_l63(A0.w);
    A1.x = wave_sum_l63(A1.x); A1.y = wave_sum_l63(A1.y);
    A1.z = wave_sum_l63(A1.z); A1.w = wave_sum_l63(A1.w);
    A2.x = wave_sum_l63(A2.x); A2.y = wave_sum_l63(A2.y);
    A2.z = wave_sum_l63(A2.z); A2.w = wave_sum_l63(A2.w);
    A3.x = wave_sum_l63(A3.x); A3.y = wave_sum_l63(A3.y);
    A3.z = wave_sum_l63(A3.z); A3.w = wave_sum_l63(A3.w);
    if (lane == 63) {
        float* r = red + wave * 16;
        r[0]=A0.x; r[1]=A0.y; r[2]=A0.z; r[3]=A0.w;
        r[4]=A1.x; r[5]=A1.y; r[6]=A1.z; r[7]=A1.w;
        r[8]=A2.x; r[9]=A2.y; r[10]=A2.z; r[11]=A2.w;
        r[12]=A3.x; r[13]=A3.y; r[14]=A3.z; r[15]=A3.w;
    }
    __syncthreads();
    if (tid < DK_) o16[tid] = red[tid] + red[16 + tid] + red[32 + tid] + red[48 + tid];
    __syncthreads();

    // ---- @Wo + bo, residual, LN1 (single-pass mean/var) ----
    float y = 0.f;
    if (tid < D_) {
        float a = bo[tid];
        #pragma unroll
        for (int j = 0; j < DK_; ++j) a = fmaf(o16[j], Wo[j * D_ + tid], a);
        y = xin[rowq * D_ + tid] + a;
        yrow[tid] = y;
    }
    __syncthreads();
    if (tid < 64) {
        const float y0 = yrow[tid], y1 = yrow[tid + 64];
        float sm = wave_sum_l63(y0 + y1);
        float sq = wave_sum_l63(fmaf(y0, y0, y1 * y1));
        if (tid == 63) {
            const float mean = sm * (1.0f / D_);
            stat[0] = mean;
            stat[1] = fmaxf(sq * (1.0f / D_) - mean * mean, 0.f);
        }
    }
    __syncthreads();
    if (tid < D_) {
        const float r = rsqrtf(stat[1] + 1e-5f);
        xout[rowq * D_ + tid] = (y - stat[0]) * r * lng[tid] + lnb[tid];
    }
}

// =======================================================================
// FFN + LN2 (+ fused next-layer QKV, or final projection).
// 4 rows per block (256 threads, 768 blocks = 3/CU). GEMM2 j-split +
// LDS partial reduce; single-pass LN. R21: GEMM1 thread owns ADJACENT
// cols 2c, 2c+1 -> ONE float2 weight load per iter (was two dword loads
// 1KB apart) — same bytes, half the VMEM instructions in the hottest
// loop. LDS writes stride-32B = 2-way bank alias (free, measured).
// =======================================================================
__global__ __launch_bounds__(256) void ffn_kernel(
    const float* __restrict__ xin, float* __restrict__ xout,
    const float* __restrict__ fw1, const float* __restrict__ fb1,
    const float* __restrict__ fw2, const float* __restrict__ fb2,
    const float* __restrict__ g, const float* __restrict__ bta,
    int do_qkv,
    const float* __restrict__ Wq, const float* __restrict__ bq,
    const float* __restrict__ Wk, const float* __restrict__ bk,
    const float* __restrict__ wvc, const float* __restrict__ bvc,
    _Float16* __restrict__ q16, _Float16* __restrict__ k16,
    float* __restrict__ vc,
    int do_proj, const float* __restrict__ pw,
    const float* __restrict__ pb, float* __restrict__ outp)
{
    __shared__ float xrT[D_][4];     // [i][r]  2 KB (reused for normalized)
    __shared__ float hbT[DFF_][4];   // [j][r]  8 KB
    __shared__ float pred[2][4][D_]; //         4 KB (GEMM2 partials)
    __shared__ float yb[4][D_];      //         2 KB
    __shared__ float xn[D_];         // last-row normalized (proj) 0.5 KB

    const long row0 = (long)blockIdx.x * 4;
    const int tid = threadIdx.x;

    for (int idx = tid; idx < 4 * D_; idx += 256) {
        const int r = idx >> 7, i = idx & 127;
        xrT[i][r] = xin[row0 * D_ + idx];
    }
    __syncthreads();

    // GEMM1 + relu: thread owns adjacent cols 2c, 2c+1 (one 8B load/iter)
    {
        const int c2 = tid;                   // pair index 0..255
        float4 a0 = make_float4(0,0,0,0), a1 = a0;
        for (int i = 0; i < D_; ++i) {
            const float2 w = *(const float2*)&fw1[i * DFF_ + 2 * c2];
            const float4 xv = *(const float4*)&xrT[i][0];
            a0.x = fmaf(xv.x, w.x, a0.x); a0.y = fmaf(xv.y, w.x, a0.y);
            a0.z = fmaf(xv.z, w.x, a0.z); a0.w = fmaf(xv.w, w.x, a0.w);
            a1.x = fmaf(xv.x, w.y, a1.x); a1.y = fmaf(xv.y, w.y, a1.y);
            a1.z = fmaf(xv.z, w.y, a1.z); a1.w = fmaf(xv.w, w.y, a1.w);
        }
        const float b0 = fb1[2 * c2], b1 = fb1[2 * c2 + 1];
        float4 h0, h1;
        h0.x = fmaxf(a0.x + b0, 0.f); h0.y = fmaxf(a0.y + b0, 0.f);
        h0.z = fmaxf(a0.z + b0, 0.f); h0.w = fmaxf(a0.w + b0, 0.f);
        h1.x = fmaxf(a1.x + b1, 0.f); h1.y = fmaxf(a1.y + b1, 0.f);
        h1.z = fmaxf(a1.z + b1, 0.f); h1.w = fmaxf(a1.w + b1, 0.f);
        *(float4*)&hbT[2 * c2][0]     = h0;
        *(float4*)&hbT[2 * c2 + 1][0] = h1;
    }
    __syncthreads();

    // GEMM2 partials: thread (d, half) does 4 rows over half the j range
    {
        const int d = tid & 127;
        const int half = tid >> 7;
        const int j0 = half * 256;
        float a0 = 0.f, a1 = 0.f, a2 = 0.f, a3 = 0.f;
        for (int j = j0; j < j0 + 256; ++j) {
            const float wv = fw2[j * D_ + d];
            const float4 hv = *(const float4*)&hbT[j][0];
            a0 = fmaf(hv.x, wv, a0);
            a1 = fmaf(hv.y, wv, a1);
            a2 = fmaf(hv.z, wv, a2);
            a3 = fmaf(hv.w, wv, a3);
        }
        pred[half][0][d] = a0; pred[half][1][d] = a1;
        pred[half][2][d] = a2; pred[half][3][d] = a3;
    }
    __syncthreads();

    // combine + bias + residual: thread owns (d, 2 rows)
    {
        const int d = tid & 127;
        const int r0 = (tid >> 7) * 2;
        const float bb = fb2[d];
        yb[r0 + 0][d] = pred[0][r0 + 0][d] + pred[1][r0 + 0][d] + bb + xrT[d][r0 + 0];
        yb[r0 + 1][d] = pred[0][r0 + 1][d] + pred[1][r0 + 1][d] + bb + xrT[d][r0 + 1];
    }
    __syncthreads();

    // LN per row (single-pass): wave w handles row w; normalized -> xrT
    const int w = tid >> 6, lane = tid & 63;
    const bool pblk = do_proj && (((row0 + 4) % TT_) == 0);
    {
        const float y0 = yb[w][lane], y1 = yb[w][lane + 64];
        const float sm = wave_sum(y0 + y1);
        const float sq = wave_sum(fmaf(y0, y0, y1 * y1));
        const float mean = sm * (1.0f / D_);
        const float var  = fmaxf(sq * (1.0f / D_) - mean * mean, 0.f);
        const float rcp = rsqrtf(var + 1e-5f);
        const float o0 = (y0 - mean) * rcp * g[lane]      + bta[lane];
        const float o1 = (y1 - mean) * rcp * g[lane + 64] + bta[lane + 64];
        xout[(row0 + w) * D_ + lane]      = o0;
        xout[(row0 + w) * D_ + lane + 64] = o1;
        xrT[lane][w]      = o0;           // re-stash for fused qkv
        xrT[lane + 64][w] = o1;
        if (pblk && w == 3) { xn[lane] = o0; xn[lane + 64] = o1; }
    }

    if (do_qkv) {
        __syncthreads();   // xrT now holds the 4 normalized rows
        const int c = tid & 127;
        const int which = tid >> 7;             // 0: q, 1: k (wave-uniform)
        const float* __restrict__ W = which ? Wk : Wq;
        const float bb = which ? bk[c] : bq[c];
        float a0 = bb, a1 = bb, a2 = bb, a3 = bb;
        for (int i = 0; i < D_; ++i) {
            const float wv = W[i * D_ + c];
            const float4 xv = *(const float4*)&xrT[i][0];
            a0 = fmaf(xv.x, wv, a0);
            a1 = fmaf(xv.y, wv, a1);
            a2 = fmaf(xv.z, wv, a2);
            a3 = fmaf(xv.w, wv, a3);
        }
        _Float16* __restrict__ dst = which ? k16 : q16;
        dst[(row0 + 0) * D_ + c] = (_Float16)a0;
        dst[(row0 + 1) * D_ + c] = (_Float16)a1;
        dst[(row0 + 2) * D_ + c] = (_Float16)a2;
        dst[(row0 + 3) * D_ + c] = (_Float16)a3;

        if (tid < 64) {
            const int r = tid >> 4, c16 = tid & 15;
            float av = bvc[c16];
            for (int i = 0; i < D_; ++i)
                av = fmaf(xrT[i][r], wvc[i * DK_ + c16], av);
            vc[(row0 + r) * DK_ + c16] = av;
        }
    }

    if (pblk) {
        __syncthreads();   // block-uniform condition — safe
        const int b = (int)((row0 + 3) / TT_);
        for (int idx = tid; idx < NQ_ * HOR_; idx += 256) {
            const int qq = idx / HOR_, hh = idx - qq * HOR_;
            float s = pb[idx];
            for (int d = 0; d < D_; ++d)
                s = fmaf(xn[d], pw[((long)qq * D_ + d) * HOR_ + hh], s);
            outp[b * NQ_ * HOR_ + idx] = s;
        }
    }
}

} // namespace

extern "C" void kernel_launch(void* const* d_in, const int* in_sizes, int n_in,
                              void* d_out, int out_size, void* d_ws, size_t ws_size,
                              hipStream_t stream) {
    (void)in_sizes; (void)n_in; (void)out_size; (void)ws_size;

    const float* x_cond = (const float*)d_in[0];
    const float* x_pred = (const float*)d_in[1];
    const float* cw_c   = (const float*)d_in[2];
    const float* cb_c   = (const float*)d_in[3];
    const float* sw_c   = (const float*)d_in[4];
    const float* sb_c   = (const float*)d_in[5];
    const float* cw_p   = (const float*)d_in[6];
    const float* cb_p   = (const float*)d_in[7];
    const float* sw_p   = (const float*)d_in[8];
    const float* sb_p   = (const float*)d_in[9];
    const float* Wq     = (const float*)d_in[10];
    const float* bq     = (const float*)d_in[11];
    const float* Wk     = (const float*)d_in[12];
    const float* bk     = (const float*)d_in[13];
    const float* Wv     = (const float*)d_in[14];
    const float* bv     = (const float*)d_in[15];
    const float* Wo     = (const float*)d_in[16];
    const float* bo     = (const float*)d_in[17];
    const float* ln1g   = (const float*)d_in[18];
    const float* ln1b   = (const float*)d_in[19];
    const float* fw1    = (const float*)d_in[20];
    const float* fb1    = (const float*)d_in[21];
    const float* fw2    = (const float*)d_in[22];
    const float* fb2    = (const float*)d_in[23];
    const float* ln2g   = (const float*)d_in[24];
    const float* ln2b   = (const float*)d_in[25];
    const float* pw     = (const float*)d_in[26];
    const float* pb     = (const float*)d_in[27];

    float* outp = (float*)d_out;
    float* ws   = (float*)d_ws;
    float*     xA   = ws + WS_XA;
    float*     xB   = ws + WS_XB;
    _Float16*  q16  = (_Float16*)(ws + WS_Q16);
    _Float16*  k16  = (_Float16*)(ws + WS_K16);
    float*     vcb  = ws + WS_VC;
    float*     wvc  = ws + WS_WVC;
    float*     bvc  = ws + WS_BVC;

    // Wv head-mean for both layers (tiny; must precede pre's fused QKV)
    prep_wvc_kernel<<<L_, 128, 0, stream>>>(Wv, bv, wvc, bvc);

    // selectors + layer-0 QKV, one launch (R19: 4 tokens per block)
    pre_kernel<<<(NB_ * TC_ + NB_ * TP_) / 4, 256, 0, stream>>>(
        x_cond, cw_c, cb_c, sw_c, sb_c,
        x_pred, cw_p, cb_p, sw_p, sb_p,
        outp + OFF_VC, outp + OFF_VP, xA,
        Wq, bq, Wk, bk, wvc, bvc, q16, k16, vcb);

    for (int l = 0; l < L_; ++l) {
        attn_kernel<<<NB_ * TT_, 256, 0, stream>>>(
            q16, k16, vcb, xA, xB,
            Wo + (long)l * DK_ * D_, bo + l * D_,
            ln1g + l * D_, ln1b + l * D_,
            outp + OFF_LOGS + (long)l * NB_ * TT_ * TT_);
        const int nl = l + 1;
        ffn_kernel<<<NB_ * TT_ / 4, 256, 0, stream>>>(
            xB, xA, fw1 + (long)l * D_ * DFF_, fb1 + l * DFF_,
            fw2 + (long)l * DFF_ * D_, fb2 + l * D_,
            ln2g + l * D_, ln2b + l * D_,
            (l < L_ - 1) ? 1 : 0,
            Wq + (long)nl * D_ * D_ * (l < L_ - 1),
            bq + nl * D_ * (l < L_ - 1),
            Wk + (long)nl * D_ * D_ * (l < L_ - 1),
            bk + nl * D_ * (l < L_ - 1),
            wvc + nl * D_ * DK_ * (l < L_ - 1),
            bvc + nl * DK_ * (l < L_ - 1),
            q16, k16, vcb,
            (l == L_ - 1) ? 1 : 0, pw, pb, outp);
    }
}

// Round 7
// 302.873 us; speedup vs baseline: 1.1082x; 1.0261x over previous
//
#include <hip/hip_runtime.h>

namespace {

constexpr int NB_  = 2;
constexpr int TC_  = 1024;
constexpr int TP_  = 512;
constexpr int TT_  = 1536;   // TC + TP
constexpr int D_   = 128;
constexpr int H_   = 8;
constexpr int DK_  = 16;
constexpr int DFF_ = 512;
constexpr int L_   = 2;
constexpr int HOR_ = 96;
constexpr int NQ_  = 3;

constexpr int SCP_ = TT_ + 8;   // ushort stride per head row (even → dword-tiled)

typedef _Float16 h2 __attribute__((ext_vector_type(2)));

// ---- output float offsets (return order: out, v_cond, v_pred, logs) ----
constexpr int OFF_OUT  = 0;
constexpr int OFF_VC   = NB_ * NQ_ * HOR_;            // 576
constexpr int OFF_VP   = OFF_VC + NB_ * TC_ * 8;      // 16960
constexpr int OFF_LOGS = OFF_VP + NB_ * TP_ * 4;      // 21056

// ---- workspace float offsets ----
constexpr int WS_XA  = 0;
constexpr int WS_XB  = WS_XA  + NB_ * TT_ * D_;       // 393216
constexpr int WS_Q16 = WS_XB  + NB_ * TT_ * D_;       // f16, half-sized
constexpr int WS_K16 = WS_Q16 + NB_ * TT_ * D_ / 2;
constexpr int WS_VC  = WS_K16 + NB_ * TT_ * D_ / 2;
constexpr int WS_WVC = WS_VC  + NB_ * TT_ * DK_;      // 2 layers x 2048
constexpr int WS_BVC = WS_WVC + L_ * D_ * DK_;        // 2 layers x 16

__device__ inline float dot2f(h2 a, h2 b, float c) {
#if __has_builtin(__builtin_amdgcn_fdot2)
    return __builtin_amdgcn_fdot2(a, b, c, false);
#else
    return c + (float)a[0] * (float)b[0] + (float)a[1] * (float)b[1];
#endif
}

__device__ inline unsigned pack2h(float a, float b) {   // 1 inst: v_cvt_pkrtz
#if __has_builtin(__builtin_amdgcn_cvt_pkrtz)
    return __builtin_bit_cast(unsigned, __builtin_amdgcn_cvt_pkrtz(a, b));
#else
    h2 p; p[0] = (_Float16)a; p[1] = (_Float16)b;
    return __builtin_bit_cast(unsigned, p);
#endif
}

__device__ inline float fast_rcp(float x) {             // v_rcp_f32, 1 inst
#if __has_builtin(__builtin_amdgcn_rcpf)
    return __builtin_amdgcn_rcpf(x);
#else
    return 1.0f / x;
#endif
}

// =======================================================================
// DPP wave reductions — VALU pipe (R16: attn 79->64 µs).
// MEASURED-DEAD-END ledger (do not retry):
//  - R17/R20: packed-f16 fdot2 rewrites of f32 VALU loops (attn Newton
//    64->82 µs; ffn/pre +35 µs).
//  - R21/R6: ffn GEMM1 float2 weight loads (300.2 -> 310.8 µs). The
//    c / c+256 dual-dword form is measured-optimal.
// =======================================================================
template <int CTRL>
__device__ inline float dpp_add(float x) {
    const int y = __builtin_amdgcn_update_dpp(
        0, __builtin_bit_cast(int, x), CTRL, 0xF, 0xF, true);
    return x + __builtin_bit_cast(float, y);
}
template <int CTRL>
__device__ inline float dpp_maxf(float x) {
    const int y = __builtin_amdgcn_update_dpp(
        __builtin_bit_cast(int, x), __builtin_bit_cast(int, x),
        CTRL, 0xF, 0xF, false);
    return fmaxf(x, __builtin_bit_cast(float, y));
}
__device__ inline float bcast63(float x) {
    return __builtin_bit_cast(float,
        __builtin_amdgcn_readlane(__builtin_bit_cast(int, x), 63));
}
__device__ inline float wave_sum_l63(float x) {
    x = dpp_add<0x111>(x); x = dpp_add<0x112>(x); x = dpp_add<0x114>(x);
    x = dpp_add<0x118>(x); x = dpp_add<0x142>(x); x = dpp_add<0x143>(x);
    return x;
}
__device__ inline float wave_sum(float x) { return bcast63(wave_sum_l63(x)); }
__device__ inline float wave_max(float x) {
    x = dpp_maxf<0x111>(x); x = dpp_maxf<0x112>(x); x = dpp_maxf<0x114>(x);
    x = dpp_maxf<0x118>(x); x = dpp_maxf<0x142>(x); x = dpp_maxf<0x143>(x);
    return bcast63(x);
}

// =======================================================================
// Wv head-mean prep (tiny separate launch so wvc/bvc are ready before
// pre_kernel's fused QKV — no intra-kernel block-ordering assumption).
// =======================================================================
__global__ __launch_bounds__(128) void prep_wvc_kernel(
    const float* __restrict__ Wv, const float* __restrict__ bv,
    float* __restrict__ wvc, float* __restrict__ bvc)
{
    const int l = blockIdx.x;
    const float* W  = Wv + (long)l * D_ * D_;
    const float* bb = bv + l * D_;
    float* wv = wvc + l * D_ * DK_;
    float* bo = bvc + l * DK_;
    const int tid = threadIdx.x;
    for (int idx = tid; idx < D_ * DK_; idx += 128) {
        const int i = idx >> 4, dk = idx & 15;
        float s = 0.f;
        #pragma unroll
        for (int hh = 0; hh < H_; ++hh) s += W[i * D_ + hh * DK_ + dk];
        wv[idx] = s * 0.125f;
    }
    if (tid < DK_) {
        float s = 0.f;
        #pragma unroll
        for (int hh = 0; hh < H_; ++hh) s += bb[hh * DK_ + tid];
        bo[tid] = s * 0.125f;
    }
}

// =======================================================================
// Selector + fused layer-0 QKV — R19: 4 tokens/block (768 blocks), one
// wave per token for the selector (lane covers dims d and d+64; Newton
// run redundantly by all 64 lanes), then ffn's do_qkv pattern over the
// 4 staged rows (1 load : 4 FMA).  [R19: total 309 -> 300]
// =======================================================================
template <int NV>
__device__ inline void selector_qkv_body(
    const float* __restrict__ x, const float* __restrict__ cw,
    const float* __restrict__ cb, const float* __restrict__ sw,
    const float* __restrict__ sb, float* __restrict__ vout,
    float* __restrict__ xout, int Tsel, int row_off, int blk,
    const float* __restrict__ Wq, const float* __restrict__ bq,
    const float* __restrict__ Wk, const float* __restrict__ bk,
    const float* __restrict__ wvc, const float* __restrict__ bvc,
    _Float16* __restrict__ q16, _Float16* __restrict__ k16,
    float* __restrict__ vc)
{
    const int tpb = Tsel / 4;            // token-groups per batch
    const int b   = blk / tpb;
    const int t0  = (blk - b * tpb) * 4;
    const int tid = threadIdx.x;
    const int lane = tid & 63, wave = tid >> 6;
    const int t = t0 + wave;             // this wave's token

    __shared__ float xrT[D_][4];         // staged selector outputs [d][r]

    // ---- selector: lane covers dims d0 = lane, d1 = lane + 64 ----
    const int d0 = lane, d1 = lane + 64;
    float xw[3 * NV];
    #pragma unroll
    for (int kk = 0; kk < 3; ++kk) {
        const int ts = t + kk - 2;
        #pragma unroll
        for (int v = 0; v < NV; ++v)
            xw[kk * NV + v] = (ts >= 0) ? x[((long)b * Tsel + ts) * NV + v] : 0.0f;
    }
    float ls0[NV], ls1[NV];
    #pragma unroll
    for (int v = 0; v < NV; ++v) {
        const float* c0 = cw + ((long)(v * D_ + d0)) * 3;
        const float* c1 = cw + ((long)(v * D_ + d1)) * 3;
        float a0 = cb[v * D_ + d0], a1 = cb[v * D_ + d1];
        a0 = fmaf(xw[0*NV+v], c0[0], a0); a1 = fmaf(xw[0*NV+v], c1[0], a1);
        a0 = fmaf(xw[1*NV+v], c0[1], a0); a1 = fmaf(xw[1*NV+v], c1[1], a1);
        a0 = fmaf(xw[2*NV+v], c0[2], a0); a1 = fmaf(xw[2*NV+v], c1[2], a1);
        ls0[v] = a0; ls1[v] = a1;
    }
    float u[NV];
    {
        const float s0 = sw[d0], s1 = sw[d1];
        #pragma unroll
        for (int v = 0; v < NV; ++v)
            u[v] = wave_sum(fmaf(ls1[v], s1, ls0[v] * s0));
    }
    // tiny entmax Newton, run redundantly by all 64 lanes (no divergence)
    float wls[NV];
    {
        float m = -1e30f;
        #pragma unroll
        for (int v = 0; v < NV; ++v) {
            float s = u[v] + sb[0];
            s = fminf(fmaxf(s, -10.0f), 10.0f);
            u[v] = 0.5f * s;
            m = fmaxf(m, u[v]);
        }
        float tau = m - 1.0f;
        for (int it = 0; it < 12; ++it) {
            float S1 = 0.f, S2 = 0.f;
            #pragma unroll
            for (int v = 0; v < NV; ++v) {
                float dd = fmaxf(u[v] - tau, 0.f);
                S1 += dd; S2 = fmaf(dd, dd, S2);
            }
            tau += (S2 - 1.0f) * 0.5f * fast_rcp(S1);   // self-correcting
        }
        float S1 = 0.f, S2 = 0.f, K = 0.f;
        #pragma unroll
        for (int v = 0; v < NV; ++v) {
            if (u[v] > tau) { S1 += u[v]; S2 = fmaf(u[v], u[v], S2); K += 1.f; }
        }
        const float mean = S1 / K;
        const float arg  = fmaxf(fmaf(mean, mean, -(S2 - 1.0f) / K), 0.f);
        tau = mean - sqrtf(arg);
        #pragma unroll
        for (int v = 0; v < NV; ++v) {
            const float dd = fmaxf(u[v] - tau, 0.f);
            wls[v] = dd * dd;
        }
    }
    float acc0 = 0.f, acc1 = 0.f;
    #pragma unroll
    for (int v = 0; v < NV; ++v) {
        acc0 = fmaf(ls0[v], wls[v], acc0);
        acc1 = fmaf(ls1[v], wls[v], acc1);
    }
    const long rowb = (long)b * TT_ + row_off + t0;   // block's first row
    const long row  = rowb + wave;
    xout[row * D_ + d0] = acc0;
    xout[row * D_ + d1] = acc1;
    xrT[d0][wave] = acc0;
    xrT[d1][wave] = acc1;
    if (lane == 0) {
        #pragma unroll
        for (int v = 0; v < NV; ++v)
            vout[((long)b * Tsel + t) * NV + v] = wls[v];
    }
    __syncthreads();

    // ---- fused layer-0 QKV over 4 staged rows (ffn do_qkv pattern) ----
    {
        const int c = tid & 127;
        const int which = tid >> 7;             // 0: q, 1: k (wave-uniform)
        const float* __restrict__ W = which ? Wk : Wq;
        const float bb = which ? bk[c] : bq[c];
        float a0 = bb, a1 = bb, a2 = bb, a3 = bb;
        for (int i = 0; i < D_; ++i) {
            const float wv = W[i * D_ + c];
            const float4 xv = *(const float4*)&xrT[i][0];
            a0 = fmaf(xv.x, wv, a0);
            a1 = fmaf(xv.y, wv, a1);
            a2 = fmaf(xv.z, wv, a2);
            a3 = fmaf(xv.w, wv, a3);
        }
        _Float16* __restrict__ dst = which ? k16 : q16;
        dst[(rowb + 0) * D_ + c] = (_Float16)a0;
        dst[(rowb + 1) * D_ + c] = (_Float16)a1;
        dst[(rowb + 2) * D_ + c] = (_Float16)a2;
        dst[(rowb + 3) * D_ + c] = (_Float16)a3;
    }
    if (tid < 64) {
        const int r = tid >> 4, c16 = tid & 15;
        float av = bvc[c16];
        for (int i = 0; i < D_; ++i)
            av = fmaf(xrT[i][r], wvc[i * DK_ + c16], av);
        vc[(rowb + r) * DK_ + c16] = av;
    }
}

__global__ __launch_bounds__(256) void pre_kernel(
    const float* __restrict__ x_cond, const float* __restrict__ cw_c,
    const float* __restrict__ cb_c, const float* __restrict__ sw_c,
    const float* __restrict__ sb_c,
    const float* __restrict__ x_pred, const float* __restrict__ cw_p,
    const float* __restrict__ cb_p, const float* __restrict__ sw_p,
    const float* __restrict__ sb_p,
    float* __restrict__ vc_out, float* __restrict__ vp_out,
    float* __restrict__ xout,
    const float* __restrict__ Wq, const float* __restrict__ bq,
    const float* __restrict__ Wk, const float* __restrict__ bk,
    const float* __restrict__ wvc, const float* __restrict__ bvc,
    _Float16* __restrict__ q16, _Float16* __restrict__ k16,
    float* __restrict__ vc)
{
    const int blk = blockIdx.x;
    if (blk < NB_ * TC_ / 4) {
        selector_qkv_body<8>(x_cond, cw_c, cb_c, sw_c, sb_c, vc_out, xout,
                             TC_, 0, blk, Wq, bq, Wk, bk, wvc, bvc,
                             q16, k16, vc);
    } else {
        selector_qkv_body<4>(x_pred, cw_p, cb_p, sw_p, sb_p, vp_out, xout,
                             TP_, TC_, blk - NB_ * TC_ / 4,
                             Wq, bq, Wk, bk, wvc, bvc, q16, k16, vc);
    }
}

// =======================================================================
// entmax15 Newton, TWO head rows per wave INTERLEAVED (R18, 62.4 µs).
// R17 packed-f16 Newton regressed — scalar f32 retained.
// =======================================================================
template <int NJ>
__device__ inline void entmax_head2(unsigned short* __restrict__ sa,
                                    unsigned short* __restrict__ sb,
                                    int lane, int t)
{
    const unsigned* __restrict__ rpa = (const unsigned*)sa;
    const unsigned* __restrict__ rpb = (const unsigned*)sb;
    float va[2 * NJ], vb[2 * NJ];
    #pragma unroll
    for (int j = 0; j < NJ; ++j) {
        const unsigned dwa = rpa[64 * j + lane];
        const unsigned dwb = rpb[64 * j + lane];
        const h2 ha = __builtin_bit_cast(h2, dwa);
        const h2 hb = __builtin_bit_cast(h2, dwb);
        const int s0 = 128 * j + 2 * lane;
        const bool in0 = (s0 <= t), in1 = (s0 + 1 <= t);
        va[2*j]   = in0 ? (float)ha[0] : -1e30f;
        va[2*j+1] = in1 ? (float)ha[1] : -1e30f;
        vb[2*j]   = in0 ? (float)hb[0] : -1e30f;
        vb[2*j+1] = in1 ? (float)hb[1] : -1e30f;
    }

    float ma0 = va[0], ma1 = va[1], mb0 = vb[0], mb1 = vb[1];
    #pragma unroll
    for (int j = 2; j < 2 * NJ; j += 2) {
        ma0 = fmaxf(ma0, va[j]); ma1 = fmaxf(ma1, va[j+1]);
        mb0 = fmaxf(mb0, vb[j]); mb1 = fmaxf(mb1, vb[j+1]);
    }
    const float ma = wave_max(fmaxf(ma0, ma1));
    const float mb = wave_max(fmaxf(mb0, mb1));

    float ta = ma - 1.0f, tb = mb - 1.0f;   // f(tau0) >= 0
    #pragma unroll
    for (int it = 0; it < 7; ++it) {
        float a10 = 0.f, a11 = 0.f, a20 = 0.f, a21 = 0.f;
        float b10 = 0.f, b11 = 0.f, b20 = 0.f, b21 = 0.f;
        #pragma unroll
        for (int j = 0; j < 2 * NJ; j += 2) {
            const float da0 = fmaxf(va[j]   - ta, 0.f);
            const float da1 = fmaxf(va[j+1] - ta, 0.f);
            const float db0 = fmaxf(vb[j]   - tb, 0.f);
            const float db1 = fmaxf(vb[j+1] - tb, 0.f);
            a10 += da0; a11 += da1;
            a20 = fmaf(da0, da0, a20); a21 = fmaf(da1, da1, a21);
            b10 += db0; b11 += db1;
            b20 = fmaf(db0, db0, b20); b21 = fmaf(db1, db1, b21);
        }
        const float S1a = wave_sum(a10 + a11);
        const float S2a = wave_sum(a20 + a21);
        const float S1b = wave_sum(b10 + b11);
        const float S2b = wave_sum(b20 + b21);
        ta += (S2a - 1.0f) * 0.5f * fast_rcp(S1a);
        tb += (S2b - 1.0f) * 0.5f * fast_rcp(S1b);
    }
    {
        float a1 = 0.f, a2 = 0.f, ka = 0.f;
        float b1 = 0.f, b2 = 0.f, kb = 0.f;
        #pragma unroll
        for (int j = 0; j < 2 * NJ; ++j) {
            if (va[j] > ta) { a1 += va[j]; a2 = fmaf(va[j], va[j], a2); ka += 1.f; }
            if (vb[j] > tb) { b1 += vb[j]; b2 = fmaf(vb[j], vb[j], b2); kb += 1.f; }
        }
        a1 = wave_sum(a1); a2 = wave_sum(a2); ka = wave_sum(ka);
        b1 = wave_sum(b1); b2 = wave_sum(b2); kb = wave_sum(kb);
        const float meana = a1 / ka;
        const float arga  = fmaxf(fmaf(meana, meana, -(a2 - 1.0f) / ka), 0.f);
        ta = meana - sqrtf(arga);
        const float meanb = b1 / kb;
        const float argb  = fmaxf(fmaf(meanb, meanb, -(b2 - 1.0f) / kb), 0.f);
        tb = meanb - sqrtf(argb);
    }
    unsigned* __restrict__ wpa = (unsigned*)sa;
    unsigned* __restrict__ wpb = (unsigned*)sb;
    #pragma unroll
    for (int j = 0; j < NJ; ++j) {
        const float da0 = fmaxf(va[2*j]   - ta, 0.f);
        const float da1 = fmaxf(va[2*j+1] - ta, 0.f);
        const float db0 = fmaxf(vb[2*j]   - tb, 0.f);
        const float db1 = fmaxf(vb[2*j+1] - tb, 0.f);
        wpa[64 * j + lane] = pack2h(da0 * da0, da1 * da1);
        wpb[64 * j + lane] = pack2h(db0 * db0, db1 * db1);
    }
}

template <int NJ>
__device__ inline void entmax_pair(unsigned short* __restrict__ scb,
                                   int wave, int lane, int t)
{
    entmax_head2<NJ>(scb + (wave * 2 + 0) * SCP_,
                     scb + (wave * 2 + 1) * SCP_, lane, t);
}

// =======================================================================
// Attention: one block (256 threads, 4 waves) per (b, t).  [R14 config]
// UNCHANGED since R18 (62.4 µs, VALUBusy ~64%). See R15-R18 notes.
// =======================================================================
__global__ __launch_bounds__(256) void attn_kernel(
    const _Float16* __restrict__ q16, const _Float16* __restrict__ k16,
    const float* __restrict__ vcomb, const float* __restrict__ xin,
    float* __restrict__ xout,
    const float* __restrict__ Wo, const float* __restrict__ bo,
    const float* __restrict__ lng, const float* __restrict__ lnb,
    float* __restrict__ logs)
{
    __shared__ unsigned short scb[H_ * SCP_];   // 24.7 KB f16 scores/weights
    __shared__ _Float16 qrow16[D_];
    __shared__ float red[64];
    __shared__ float o16[DK_];
    __shared__ float yrow[D_];
    __shared__ float stat[2];

    const int blk = blockIdx.x;
    const int t = TT_ - 1 - (blk >> 1);   // descending-work dispatch order
    const int b = blk & 1;
    const int tid = threadIdx.x;
    const int lane = tid & 63, wave = tid >> 6;
    const long rowq  = (long)b * TT_ + t;
    const long bbase = (long)b * TT_;

    if (tid < 64)
        ((unsigned*)qrow16)[tid] = ((const unsigned*)(q16 + rowq * D_))[tid];
    __syncthreads();

    // ---- scores: u = (q.k / 4) / 2 = dot * 0.125, f16 dot2, stored f16 ----
    {
        const int h  = tid & 7;
        const int sl = tid >> 3;   // 0..31
        unsigned short* __restrict__ srow = scb + h * SCP_;
        h2 qv[8];
        __builtin_memcpy(qv, (const _Float16*)qrow16 + h * DK_, 32);
        for (int s = sl; s <= t; s += 32) {
            float4 kk0, kk1;
            {
                const float4* kp4 = (const float4*)(k16 + (bbase + s) * D_ + h * DK_);
                kk0 = kp4[0]; kk1 = kp4[1];
            }
            h2 kh[8];
            __builtin_memcpy(kh,     &kk0, 16);
            __builtin_memcpy(kh + 4, &kk1, 16);
            float dot = 0.f;
            #pragma unroll
            for (int i2 = 0; i2 < 8; ++i2) dot = dot2f(qv[i2], kh[i2], dot);
            const _Float16 sh = (_Float16)(dot * 0.125f);
            srow[s] = __builtin_bit_cast(unsigned short, sh);
        }
    }
    __syncthreads();

    // ---- entmax15: wave w = heads 2w, 2w+1 interleaved; even-NJ templates ----
    {
        const int njn = (t >> 7) + 1;          // needed dwords: 1..12
        switch ((njn + 1) & ~1) {              // round up to even
        case 2:  entmax_pair<2 >(scb, wave, lane, t); break;
        case 4:  entmax_pair<4 >(scb, wave, lane, t); break;
        case 6:  entmax_pair<6 >(scb, wave, lane, t); break;
        case 8:  entmax_pair<8 >(scb, wave, lane, t); break;
        case 10: entmax_pair<10>(scb, wave, lane, t); break;
        default: entmax_pair<12>(scb, wave, lane, t); break;
        }
    }
    __syncthreads();

    // ---- w_avg via v_pk_add_f16 -> logs; acc16 += w_avg * v_comb ----
    float4 A0 = make_float4(0,0,0,0), A1 = A0, A2 = A0, A3 = A0;
    float* lrow = logs + rowq * TT_;
    const unsigned* __restrict__ rp0 = (const unsigned*)scb;
    #pragma unroll
    for (int it = 0; it < 3; ++it) {
        const int dwi = tid + 256 * it;       // 0..767
        const int s0 = 2 * dwi;
        if (s0 <= t) {
            h2 hs = __builtin_bit_cast(h2, rp0[dwi]);
            #pragma unroll
            for (int h = 1; h < H_; ++h)
                hs = hs + __builtin_bit_cast(h2, rp0[h * (SCP_ / 2) + dwi]);
            const float wa0 = (float)hs[0] * 0.125f;
            const float wa1 = (float)hs[1] * 0.125f;  // 0 beyond t
            {
                const float4* vp = (const float4*)(vcomb + (bbase + s0) * DK_);
                const float4 v0 = vp[0], v1 = vp[1], v2 = vp[2], v3 = vp[3];
                A0.x = fmaf(wa0, v0.x, A0.x); A0.y = fmaf(wa0, v0.y, A0.y);
                A0.z = fmaf(wa0, v0.z, A0.z); A0.w = fmaf(wa0, v0.w, A0.w);
                A1.x = fmaf(wa0, v1.x, A1.x); A1.y = fmaf(wa0, v1.y, A1.y);
                A1.z = fmaf(wa0, v1.z, A1.z); A1.w = fmaf(wa0, v1.w, A1.w);
                A2.x = fmaf(wa0, v2.x, A2.x); A2.y = fmaf(wa0, v2.y, A2.y);
                A2.z = fmaf(wa0, v2.z, A2.z); A2.w = fmaf(wa0, v2.w, A2.w);
                A3.x = fmaf(wa0, v3.x, A3.x); A3.y = fmaf(wa0, v3.y, A3.y);
                A3.z = fmaf(wa0, v3.z, A3.z); A3.w = fmaf(wa0, v3.w, A3.w);
            }
            if (s0 + 1 <= t) {
                const float4* vp = (const float4*)(vcomb + (bbase + s0 + 1) * DK_);
                const float4 v0 = vp[0], v1 = vp[1], v2 = vp[2], v3 = vp[3];
                A0.x = fmaf(wa1, v0.x, A0.x); A0.y = fmaf(wa1, v0.y, A0.y);
                A0.z = fmaf(wa1, v0.z, A0.z); A0.w = fmaf(wa1, v0.w, A0.w);
                A1.x = fmaf(wa1, v1.x, A1.x); A1.y = fmaf(wa1, v1.y, A1.y);
                A1.z = fmaf(wa1, v1.z, A1.z); A1.w = fmaf(wa1, v1.w, A1.w);
                A2.x = fmaf(wa1, v2.x, A2.x); A2.y = fmaf(wa1, v2.y, A2.y);
                A2.z = fmaf(wa1, v2.z, A2.z); A2.w = fmaf(wa1, v2.w, A2.w);
                A3.x = fmaf(wa1, v3.x, A3.x); A3.y = fmaf(wa1, v3.y, A3.y);
                A3.z = fmaf(wa1, v3.z, A3.z); A3.w = fmaf(wa1, v3.w, A3.w);
            }
            *(float2*)(lrow + s0) = make_float2(wa0, wa1);
        } else {
            *(float2*)(lrow + s0) = make_float2(0.f, 0.f);
        }
    }
    A0.x = wave_sum_l63(A0.x); A0.y = wave_sum_l63(A0.y);
    A0.z = wave_sum_l63(A0.z); A0.w = wave_sum_l63(A0.w);
    A1.x = wave_sum_l63(A1.x); A1.y = wave_sum_l63(A1.y);
    A1.z = wave_sum_l63(A1.z); A1.w = wave_sum_l63(A1.w);
    A2.x = wave_sum_l63(A2.x); A2.y = wave_sum_l63(A2.y);
    A2.z = wave_sum_l63(A2.z); A2.w = wave_sum_l63(A2.w);
    A3.x = wave_sum_l63(A3.x); A3.y = wave_sum_l63(A3.y);
    A3.z = wave_sum_l63(A3.z); A3.w = wave_sum_l63(A3.w);
    if (lane == 63) {
        float* r = red + wave * 16;
        r[0]=A0.x; r[1]=A0.y; r[2]=A0.z; r[3]=A0.w;
        r[4]=A1.x; r[5]=A1.y; r[6]=A1.z; r[7]=A1.w;
        r[8]=A2.x; r[9]=A2.y; r[10]=A2.z; r[11]=A2.w;
        r[12]=A3.x; r[13]=A3.y; r[14]=A3.z; r[15]=A3.w;
    }
    __syncthreads();
    if (tid < DK_) o16[tid] = red[tid] + red[16 + tid] + red[32 + tid] + red[48 + tid];
    __syncthreads();

    // ---- @Wo + bo, residual, LN1 (single-pass mean/var) ----
    float y = 0.f;
    if (tid < D_) {
        float a = bo[tid];
        #pragma unroll
        for (int j = 0; j < DK_; ++j) a = fmaf(o16[j], Wo[j * D_ + tid], a);
        y = xin[rowq * D_ + tid] + a;
        yrow[tid] = y;
    }
    __syncthreads();
    if (tid < 64) {
        const float y0 = yrow[tid], y1 = yrow[tid + 64];
        float sm = wave_sum_l63(y0 + y1);
        float sq = wave_sum_l63(fmaf(y0, y0, y1 * y1));
        if (tid == 63) {
            const float mean = sm * (1.0f / D_);
            stat[0] = mean;
            stat[1] = fmaxf(sq * (1.0f / D_) - mean * mean, 0.f);
        }
    }
    __syncthreads();
    if (tid < D_) {
        const float r = rsqrtf(stat[1] + 1e-5f);
        xout[rowq * D_ + tid] = (y - stat[0]) * r * lng[tid] + lnb[tid];
    }
}

// =======================================================================
// FFN + LN2 (+ fused next-layer QKV, or final projection).
// 4 rows per block (256 threads, 768 blocks = 3/CU). GEMM2 j-split +
// LDS partial reduce; single-pass LN. GEMM1 owns cols c / c+256 (R4
// form — measured-optimal; float2 variant regressed, R6). R22: the
// combine+bias+residual phase is FUSED into the LN (wave w computes
// pred0+pred1+fb2+xrT for its own row directly) — deletes one
// __syncthreads, the 2KB yb buffer, and an LDS round-trip.
// =======================================================================
__global__ __launch_bounds__(256) void ffn_kernel(
    const float* __restrict__ xin, float* __restrict__ xout,
    const float* __restrict__ fw1, const float* __restrict__ fb1,
    const float* __restrict__ fw2, const float* __restrict__ fb2,
    const float* __restrict__ g, const float* __restrict__ bta,
    int do_qkv,
    const float* __restrict__ Wq, const float* __restrict__ bq,
    const float* __restrict__ Wk, const float* __restrict__ bk,
    const float* __restrict__ wvc, const float* __restrict__ bvc,
    _Float16* __restrict__ q16, _Float16* __restrict__ k16,
    float* __restrict__ vc,
    int do_proj, const float* __restrict__ pw,
    const float* __restrict__ pb, float* __restrict__ outp)
{
    __shared__ float xrT[D_][4];     // [i][r]  2 KB (reused for normalized)
    __shared__ float hbT[DFF_][4];   // [j][r]  8 KB
    __shared__ float pred[2][4][D_]; //         4 KB (GEMM2 partials)
    __shared__ float xn[D_];         // last-row normalized (proj) 0.5 KB

    const long row0 = (long)blockIdx.x * 4;
    const int tid = threadIdx.x;

    for (int idx = tid; idx < 4 * D_; idx += 256) {
        const int r = idx >> 7, i = idx & 127;
        xrT[i][r] = xin[row0 * D_ + idx];
    }
    __syncthreads();

    // GEMM1 + relu: thread owns cols c and c+256
    {
        const int c = tid;
        float4 a0 = make_float4(0,0,0,0), a1 = a0;
        for (int i = 0; i < D_; ++i) {
            const float w0 = fw1[i * DFF_ + c];
            const float w1 = fw1[i * DFF_ + c + 256];
            const float4 xv = *(const float4*)&xrT[i][0];
            a0.x = fmaf(xv.x, w0, a0.x); a0.y = fmaf(xv.y, w0, a0.y);
            a0.z = fmaf(xv.z, w0, a0.z); a0.w = fmaf(xv.w, w0, a0.w);
            a1.x = fmaf(xv.x, w1, a1.x); a1.y = fmaf(xv.y, w1, a1.y);
            a1.z = fmaf(xv.z, w1, a1.z); a1.w = fmaf(xv.w, w1, a1.w);
        }
        const float b0 = fb1[c], b1 = fb1[c + 256];
        float4 h0, h1;
        h0.x = fmaxf(a0.x + b0, 0.f); h0.y = fmaxf(a0.y + b0, 0.f);
        h0.z = fmaxf(a0.z + b0, 0.f); h0.w = fmaxf(a0.w + b0, 0.f);
        h1.x = fmaxf(a1.x + b1, 0.f); h1.y = fmaxf(a1.y + b1, 0.f);
        h1.z = fmaxf(a1.z + b1, 0.f); h1.w = fmaxf(a1.w + b1, 0.f);
        *(float4*)&hbT[c][0]       = h0;
        *(float4*)&hbT[c + 256][0] = h1;
    }
    __syncthreads();

    // GEMM2 partials: thread (d, half) does 4 rows over half the j range
    {
        const int d = tid & 127;
        const int half = tid >> 7;
        const int j0 = half * 256;
        float a0 = 0.f, a1 = 0.f, a2 = 0.f, a3 = 0.f;
        for (int j = j0; j < j0 + 256; ++j) {
            const float wv = fw2[j * D_ + d];
            const float4 hv = *(const float4*)&hbT[j][0];
            a0 = fmaf(hv.x, wv, a0);
            a1 = fmaf(hv.y, wv, a1);
            a2 = fmaf(hv.z, wv, a2);
            a3 = fmaf(hv.w, wv, a3);
        }
        pred[half][0][d] = a0; pred[half][1][d] = a1;
        pred[half][2][d] = a2; pred[half][3][d] = a3;
    }
    __syncthreads();

    // LN per row, FUSED combine+bias+residual (R22): wave w handles row w;
    // lane l computes y = pred0+pred1+fb2+residual for dims l and l+64
    // directly from LDS (all cells touched by exactly this lane).
    const int w = tid >> 6, lane = tid & 63;
    const bool pblk = do_proj && (((row0 + 4) % TT_) == 0);
    {
        const float y0 = pred[0][w][lane]      + pred[1][w][lane]
                       + fb2[lane]             + xrT[lane][w];
        const float y1 = pred[0][w][lane + 64] + pred[1][w][lane + 64]
                       + fb2[lane + 64]        + xrT[lane + 64][w];
        const float sm = wave_sum(y0 + y1);
        const float sq = wave_sum(fmaf(y0, y0, y1 * y1));
        const float mean = sm * (1.0f / D_);
        const float var  = fmaxf(sq * (1.0f / D_) - mean * mean, 0.f);
        const float rcp = rsqrtf(var + 1e-5f);
        const float o0 = (y0 - mean) * rcp * g[lane]      + bta[lane];
        const float o1 = (y1 - mean) * rcp * g[lane + 64] + bta[lane + 64];
        xout[(row0 + w) * D_ + lane]      = o0;
        xout[(row0 + w) * D_ + lane + 64] = o1;
        xrT[lane][w]      = o0;           // re-stash for fused qkv
        xrT[lane + 64][w] = o1;
        if (pblk && w == 3) { xn[lane] = o0; xn[lane + 64] = o1; }
    }

    if (do_qkv) {
        __syncthreads();   // xrT now holds the 4 normalized rows
        const int c = tid & 127;
        const int which = tid >> 7;             // 0: q, 1: k (wave-uniform)
        const float* __restrict__ W = which ? Wk : Wq;
        const float bb = which ? bk[c] : bq[c];
        float a0 = bb, a1 = bb, a2 = bb, a3 = bb;
        for (int i = 0; i < D_; ++i) {
            const float wv = W[i * D_ + c];
            const float4 xv = *(const float4*)&xrT[i][0];
            a0 = fmaf(xv.x, wv, a0);
            a1 = fmaf(xv.y, wv, a1);
            a2 = fmaf(xv.z, wv, a2);
            a3 = fmaf(xv.w, wv, a3);
        }
        _Float16* __restrict__ dst = which ? k16 : q16;
        dst[(row0 + 0) * D_ + c] = (_Float16)a0;
        dst[(row0 + 1) * D_ + c] = (_Float16)a1;
        dst[(row0 + 2) * D_ + c] = (_Float16)a2;
        dst[(row0 + 3) * D_ + c] = (_Float16)a3;

        if (tid < 64) {
            const int r = tid >> 4, c16 = tid & 15;
            float av = bvc[c16];
            for (int i = 0; i < D_; ++i)
                av = fmaf(xrT[i][r], wvc[i * DK_ + c16], av);
            vc[(row0 + r) * DK_ + c16] = av;
        }
    }

    if (pblk) {
        __syncthreads();   // block-uniform condition — safe
        const int b = (int)((row0 + 3) / TT_);
        for (int idx = tid; idx < NQ_ * HOR_; idx += 256) {
            const int qq = idx / HOR_, hh = idx - qq * HOR_;
            float s = pb[idx];
            for (int d = 0; d < D_; ++d)
                s = fmaf(xn[d], pw[((long)qq * D_ + d) * HOR_ + hh], s);
            outp[b * NQ_ * HOR_ + idx] = s;
        }
    }
}

} // namespace

extern "C" void kernel_launch(void* const* d_in, const int* in_sizes, int n_in,
                              void* d_out, int out_size, void* d_ws, size_t ws_size,
                              hipStream_t stream) {
    (void)in_sizes; (void)n_in; (void)out_size; (void)ws_size;

    const float* x_cond = (const float*)d_in[0];
    const float* x_pred = (const float*)d_in[1];
    const float* cw_c   = (const float*)d_in[2];
    const float* cb_c   = (const float*)d_in[3];
    const float* sw_c   = (const float*)d_in[4];
    const float* sb_c   = (const float*)d_in[5];
    const float* cw_p   = (const float*)d_in[6];
    const float* cb_p   = (const float*)d_in[7];
    const float* sw_p   = (const float*)d_in[8];
    const float* sb_p   = (const float*)d_in[9];
    const float* Wq     = (const float*)d_in[10];
    const float* bq     = (const float*)d_in[11];
    const float* Wk     = (const float*)d_in[12];
    const float* bk     = (const float*)d_in[13];
    const float* Wv     = (const float*)d_in[14];
    const float* bv     = (const float*)d_in[15];
    const float* Wo     = (const float*)d_in[16];
    const float* bo     = (const float*)d_in[17];
    const float* ln1g   = (const float*)d_in[18];
    const float* ln1b   = (const float*)d_in[19];
    const float* fw1    = (const float*)d_in[20];
    const float* fb1    = (const float*)d_in[21];
    const float* fw2    = (const float*)d_in[22];
    const float* fb2    = (const float*)d_in[23];
    const float* ln2g   = (const float*)d_in[24];
    const float* ln2b   = (const float*)d_in[25];
    const float* pw     = (const float*)d_in[26];
    const float* pb     = (const float*)d_in[27];

    float* outp = (float*)d_out;
    float* ws   = (float*)d_ws;
    float*     xA   = ws + WS_XA;
    float*     xB   = ws + WS_XB;
    _Float16*  q16  = (_Float16*)(ws + WS_Q16);
    _Float16*  k16  = (_Float16*)(ws + WS_K16);
    float*     vcb  = ws + WS_VC;
    float*     wvc  = ws + WS_WVC;
    float*     bvc  = ws + WS_BVC;

    // Wv head-mean for both layers (tiny; must precede pre's fused QKV)
    prep_wvc_kernel<<<L_, 128, 0, stream>>>(Wv, bv, wvc, bvc);

    // selectors + layer-0 QKV, one launch (R19: 4 tokens per block)
    pre_kernel<<<(NB_ * TC_ + NB_ * TP_) / 4, 256, 0, stream>>>(
        x_cond, cw_c, cb_c, sw_c, sb_c,
        x_pred, cw_p, cb_p, sw_p, sb_p,
        outp + OFF_VC, outp + OFF_VP, xA,
        Wq, bq, Wk, bk, wvc, bvc, q16, k16, vcb);

    for (int l = 0; l < L_; ++l) {
        attn_kernel<<<NB_ * TT_, 256, 0, stream>>>(
            q16, k16, vcb, xA, xB,
            Wo + (long)l * DK_ * D_, bo + l * D_,
            ln1g + l * D_, ln1b + l * D_,
            outp + OFF_LOGS + (long)l * NB_ * TT_ * TT_);
        const int nl = l + 1;
        ffn_kernel<<<NB_ * TT_ / 4, 256, 0, stream>>>(
            xB, xA, fw1 + (long)l * D_ * DFF_, fb1 + l * DFF_,
            fw2 + (long)l * DFF_ * D_, fb2 + l * D_,
            ln2g + l * D_, ln2b + l * D_,
            (l < L_ - 1) ? 1 : 0,
            Wq + (long)nl * D_ * D_ * (l < L_ - 1),
            bq + nl * D_ * (l < L_ - 1),
            Wk + (long)nl * D_ * D_ * (l < L_ - 1),
            bk + nl * D_ * (l < L_ - 1),
            wvc + nl * D_ * DK_ * (l < L_ - 1),
            bvc + nl * DK_ * (l < L_ - 1),
            q16, k16, vcb,
            (l == L_ - 1) ? 1 : 0, pw, pb, outp);
    }
}

// Round 8
// 285.083 us; speedup vs baseline: 1.1773x; 1.0624x over previous
//
#include <hip/hip_runtime.h>

namespace {

constexpr int NB_  = 2;
constexpr int TC_  = 1024;
constexpr int TP_  = 512;
constexpr int TT_  = 1536;   // TC + TP
constexpr int D_   = 128;
constexpr int H_   = 8;
constexpr int DK_  = 16;
constexpr int DFF_ = 512;
constexpr int L_   = 2;
constexpr int HOR_ = 96;
constexpr int NQ_  = 3;

constexpr int SCP_ = TT_ + 8;   // ushort stride per head row (even → dword-tiled)

typedef _Float16 h2 __attribute__((ext_vector_type(2)));
typedef _Float16 h8 __attribute__((ext_vector_type(8)));
typedef float    f32x4 __attribute__((ext_vector_type(4)));

// ---- output float offsets (return order: out, v_cond, v_pred, logs) ----
constexpr int OFF_OUT  = 0;
constexpr int OFF_VC   = NB_ * NQ_ * HOR_;            // 576
constexpr int OFF_VP   = OFF_VC + NB_ * TC_ * 8;      // 16960
constexpr int OFF_LOGS = OFF_VP + NB_ * TP_ * 4;      // 21056

// ---- workspace float offsets ----
constexpr int WS_XA  = 0;
constexpr int WS_XB  = WS_XA  + NB_ * TT_ * D_;       // 393216
constexpr int WS_Q16 = WS_XB  + NB_ * TT_ * D_;       // f16, half-sized
constexpr int WS_K16 = WS_Q16 + NB_ * TT_ * D_ / 2;
constexpr int WS_VC  = WS_K16 + NB_ * TT_ * D_ / 2;
constexpr int WS_WVC = WS_VC  + NB_ * TT_ * DK_;      // 2 layers x 2048
constexpr int WS_BVC = WS_WVC + L_ * D_ * DK_;        // 2 layers x 16
// R23: MFMA B-fragments for ffn GEMM1/GEMM2 (f16 pairs, 1 dword each).
// fh1: fw1 [128][512] as 4x32 tiles; fh2: fw2 [512][128] as 16x8 tiles.
// Per tile: 64 lanes x 4 dwords (16B lane fragment), frag layout
// col = lane&15, k = 8*(lane>>4) + j  (j = 0..7 contiguous in k).
constexpr int FHL_   = 32768;                         // dwords per layer
constexpr int WS_FH1 = WS_BVC + L_ * DK_;
constexpr int WS_FH2 = WS_FH1 + L_ * FHL_;

__device__ inline float dot2f(h2 a, h2 b, float c) {
#if __has_builtin(__builtin_amdgcn_fdot2)
    return __builtin_amdgcn_fdot2(a, b, c, false);
#else
    return c + (float)a[0] * (float)b[0] + (float)a[1] * (float)b[1];
#endif
}

__device__ inline unsigned pack2h(float a, float b) {   // 1 inst: v_cvt_pkrtz
#if __has_builtin(__builtin_amdgcn_cvt_pkrtz)
    return __builtin_bit_cast(unsigned, __builtin_amdgcn_cvt_pkrtz(a, b));
#else
    h2 p; p[0] = (_Float16)a; p[1] = (_Float16)b;
    return __builtin_bit_cast(unsigned, p);
#endif
}

__device__ inline float fast_rcp(float x) {             // v_rcp_f32, 1 inst
#if __has_builtin(__builtin_amdgcn_rcpf)
    return __builtin_amdgcn_rcpf(x);
#else
    return 1.0f / x;
#endif
}

// =======================================================================
// DPP wave reductions — VALU pipe (R16: attn 79->64 µs).
// MEASURED-DEAD-END ledger (do not retry):
//  - R17/R20: packed-f16 fdot2 rewrites of f32 VALU loops (attn Newton
//    64->82 µs; ffn/pre +35 µs).
//  - R21/R6: ffn GEMM1 float2 weight loads (300.2 -> 310.8 µs). The
//    c / c+256 dual-dword form is measured-optimal.
//  - R22/R7: yb-fusion in ffn LN: neutral (noise band ±3-5 µs).
// =======================================================================
template <int CTRL>
__device__ inline float dpp_add(float x) {
    const int y = __builtin_amdgcn_update_dpp(
        0, __builtin_bit_cast(int, x), CTRL, 0xF, 0xF, true);
    return x + __builtin_bit_cast(float, y);
}
template <int CTRL>
__device__ inline float dpp_maxf(float x) {
    const int y = __builtin_amdgcn_update_dpp(
        __builtin_bit_cast(int, x), __builtin_bit_cast(int, x),
        CTRL, 0xF, 0xF, false);
    return fmaxf(x, __builtin_bit_cast(float, y));
}
__device__ inline float bcast63(float x) {
    return __builtin_bit_cast(float,
        __builtin_amdgcn_readlane(__builtin_bit_cast(int, x), 63));
}
__device__ inline float wave_sum_l63(float x) {
    x = dpp_add<0x111>(x); x = dpp_add<0x112>(x); x = dpp_add<0x114>(x);
    x = dpp_add<0x118>(x); x = dpp_add<0x142>(x); x = dpp_add<0x143>(x);
    return x;
}
__device__ inline float wave_sum(float x) { return bcast63(wave_sum_l63(x)); }
__device__ inline float wave_max(float x) {
    x = dpp_maxf<0x111>(x); x = dpp_maxf<0x112>(x); x = dpp_maxf<0x114>(x);
    x = dpp_maxf<0x118>(x); x = dpp_maxf<0x142>(x); x = dpp_maxf<0x143>(x);
    return bcast63(x);
}

// =======================================================================
// Prep: Wv head-mean + MFMA B-fragment packing for ffn (R23).
// =======================================================================
__global__ __launch_bounds__(256) void prep_kernel(
    const float* __restrict__ Wv, const float* __restrict__ bv,
    float* __restrict__ wvc, float* __restrict__ bvc,
    const float* __restrict__ fw1, const float* __restrict__ fw2,
    unsigned* __restrict__ fh1, unsigned* __restrict__ fh2)
{
    const int gid = blockIdx.x * 256 + threadIdx.x;
    const int stride = gridDim.x * 256;

    for (int e = gid; e < L_ * D_ * DK_; e += stride) {
        const int l = e / (D_ * DK_), rem = e - l * D_ * DK_;
        const int i = rem >> 4, dk = rem & 15;
        const float* W = Wv + (long)l * D_ * D_;
        float s = 0.f;
        #pragma unroll
        for (int hh = 0; hh < H_; ++hh) s += W[i * D_ + hh * DK_ + dk];
        wvc[e] = s * 0.125f;
    }
    for (int e = gid; e < L_ * DK_; e += stride) {
        const int l = e / DK_, dk = e - l * DK_;
        const float* bb = bv + l * D_;
        float s = 0.f;
        #pragma unroll
        for (int hh = 0; hh < H_; ++hh) s += bb[hh * DK_ + dk];
        bvc[e] = s * 0.125f;
    }
    // fh1: GEMM1 B = fw1 [k=128][n=512]; tiles kt 0..3, nt 0..31
    for (int e = gid; e < L_ * FHL_; e += stride) {
        const int l = e >> 15, rem = e & 32767;
        const int tile = rem >> 8, within = rem & 255;
        const int lane = within >> 2, p = within & 3;
        const int kt = tile >> 5, nt = tile & 31;
        const int k = kt * 32 + 8 * (lane >> 4) + 2 * p;
        const int n = nt * 16 + (lane & 15);
        const float* W = fw1 + (long)l * D_ * DFF_;
        fh1[e] = pack2h(W[k * DFF_ + n], W[(k + 1) * DFF_ + n]);
    }
    // fh2: GEMM2 B = fw2 [k=512][n=128]; tiles kt 0..15, nt 0..7
    for (int e = gid; e < L_ * FHL_; e += stride) {
        const int l = e >> 15, rem = e & 32767;
        const int tile = rem >> 8, within = rem & 255;
        const int lane = within >> 2, p = within & 3;
        const int kt = tile >> 3, nt = tile & 7;
        const int k = kt * 32 + 8 * (lane >> 4) + 2 * p;
        const int n = nt * 16 + (lane & 15);
        const float* W = fw2 + (long)l * DFF_ * D_;
        fh2[e] = pack2h(W[k * D_ + n], W[(k + 1) * D_ + n]);
    }
}

// =======================================================================
// Selector + fused layer-0 QKV — R19: 4 tokens/block (768 blocks), one
// wave per token for the selector (lane covers dims d and d+64; Newton
// run redundantly by all 64 lanes), then ffn's do_qkv pattern over the
// 4 staged rows (1 load : 4 FMA).  [R19: total 309 -> 300]
// =======================================================================
template <int NV>
__device__ inline void selector_qkv_body(
    const float* __restrict__ x, const float* __restrict__ cw,
    const float* __restrict__ cb, const float* __restrict__ sw,
    const float* __restrict__ sb, float* __restrict__ vout,
    float* __restrict__ xout, int Tsel, int row_off, int blk,
    const float* __restrict__ Wq, const float* __restrict__ bq,
    const float* __restrict__ Wk, const float* __restrict__ bk,
    const float* __restrict__ wvc, const float* __restrict__ bvc,
    _Float16* __restrict__ q16, _Float16* __restrict__ k16,
    float* __restrict__ vc)
{
    const int tpb = Tsel / 4;            // token-groups per batch
    const int b   = blk / tpb;
    const int t0  = (blk - b * tpb) * 4;
    const int tid = threadIdx.x;
    const int lane = tid & 63, wave = tid >> 6;
    const int t = t0 + wave;             // this wave's token

    __shared__ float xrT[D_][4];         // staged selector outputs [d][r]

    // ---- selector: lane covers dims d0 = lane, d1 = lane + 64 ----
    const int d0 = lane, d1 = lane + 64;
    float xw[3 * NV];
    #pragma unroll
    for (int kk = 0; kk < 3; ++kk) {
        const int ts = t + kk - 2;
        #pragma unroll
        for (int v = 0; v < NV; ++v)
            xw[kk * NV + v] = (ts >= 0) ? x[((long)b * Tsel + ts) * NV + v] : 0.0f;
    }
    float ls0[NV], ls1[NV];
    #pragma unroll
    for (int v = 0; v < NV; ++v) {
        const float* c0 = cw + ((long)(v * D_ + d0)) * 3;
        const float* c1 = cw + ((long)(v * D_ + d1)) * 3;
        float a0 = cb[v * D_ + d0], a1 = cb[v * D_ + d1];
        a0 = fmaf(xw[0*NV+v], c0[0], a0); a1 = fmaf(xw[0*NV+v], c1[0], a1);
        a0 = fmaf(xw[1*NV+v], c0[1], a0); a1 = fmaf(xw[1*NV+v], c1[1], a1);
        a0 = fmaf(xw[2*NV+v], c0[2], a0); a1 = fmaf(xw[2*NV+v], c1[2], a1);
        ls0[v] = a0; ls1[v] = a1;
    }
    float u[NV];
    {
        const float s0 = sw[d0], s1 = sw[d1];
        #pragma unroll
        for (int v = 0; v < NV; ++v)
            u[v] = wave_sum(fmaf(ls1[v], s1, ls0[v] * s0));
    }
    // tiny entmax Newton, run redundantly by all 64 lanes (no divergence)
    float wls[NV];
    {
        float m = -1e30f;
        #pragma unroll
        for (int v = 0; v < NV; ++v) {
            float s = u[v] + sb[0];
            s = fminf(fmaxf(s, -10.0f), 10.0f);
            u[v] = 0.5f * s;
            m = fmaxf(m, u[v]);
        }
        float tau = m - 1.0f;
        for (int it = 0; it < 12; ++it) {
            float S1 = 0.f, S2 = 0.f;
            #pragma unroll
            for (int v = 0; v < NV; ++v) {
                float dd = fmaxf(u[v] - tau, 0.f);
                S1 += dd; S2 = fmaf(dd, dd, S2);
            }
            tau += (S2 - 1.0f) * 0.5f * fast_rcp(S1);   // self-correcting
        }
        float S1 = 0.f, S2 = 0.f, K = 0.f;
        #pragma unroll
        for (int v = 0; v < NV; ++v) {
            if (u[v] > tau) { S1 += u[v]; S2 = fmaf(u[v], u[v], S2); K += 1.f; }
        }
        const float mean = S1 / K;
        const float arg  = fmaxf(fmaf(mean, mean, -(S2 - 1.0f) / K), 0.f);
        tau = mean - sqrtf(arg);
        #pragma unroll
        for (int v = 0; v < NV; ++v) {
            const float dd = fmaxf(u[v] - tau, 0.f);
            wls[v] = dd * dd;
        }
    }
    float acc0 = 0.f, acc1 = 0.f;
    #pragma unroll
    for (int v = 0; v < NV; ++v) {
        acc0 = fmaf(ls0[v], wls[v], acc0);
        acc1 = fmaf(ls1[v], wls[v], acc1);
    }
    const long rowb = (long)b * TT_ + row_off + t0;   // block's first row
    const long row  = rowb + wave;
    xout[row * D_ + d0] = acc0;
    xout[row * D_ + d1] = acc1;
    xrT[d0][wave] = acc0;
    xrT[d1][wave] = acc1;
    if (lane == 0) {
        #pragma unroll
        for (int v = 0; v < NV; ++v)
            vout[((long)b * Tsel + t) * NV + v] = wls[v];
    }
    __syncthreads();

    // ---- fused layer-0 QKV over 4 staged rows (ffn do_qkv pattern) ----
    {
        const int c = tid & 127;
        const int which = tid >> 7;             // 0: q, 1: k (wave-uniform)
        const float* __restrict__ W = which ? Wk : Wq;
        const float bb = which ? bk[c] : bq[c];
        float a0 = bb, a1 = bb, a2 = bb, a3 = bb;
        for (int i = 0; i < D_; ++i) {
            const float wv = W[i * D_ + c];
            const float4 xv = *(const float4*)&xrT[i][0];
            a0 = fmaf(xv.x, wv, a0);
            a1 = fmaf(xv.y, wv, a1);
            a2 = fmaf(xv.z, wv, a2);
            a3 = fmaf(xv.w, wv, a3);
        }
        _Float16* __restrict__ dst = which ? k16 : q16;
        dst[(rowb + 0) * D_ + c] = (_Float16)a0;
        dst[(rowb + 1) * D_ + c] = (_Float16)a1;
        dst[(rowb + 2) * D_ + c] = (_Float16)a2;
        dst[(rowb + 3) * D_ + c] = (_Float16)a3;
    }
    if (tid < 64) {
        const int r = tid >> 4, c16 = tid & 15;
        float av = bvc[c16];
        for (int i = 0; i < D_; ++i)
            av = fmaf(xrT[i][r], wvc[i * DK_ + c16], av);
        vc[(rowb + r) * DK_ + c16] = av;
    }
}

__global__ __launch_bounds__(256) void pre_kernel(
    const float* __restrict__ x_cond, const float* __restrict__ cw_c,
    const float* __restrict__ cb_c, const float* __restrict__ sw_c,
    const float* __restrict__ sb_c,
    const float* __restrict__ x_pred, const float* __restrict__ cw_p,
    const float* __restrict__ cb_p, const float* __restrict__ sw_p,
    const float* __restrict__ sb_p,
    float* __restrict__ vc_out, float* __restrict__ vp_out,
    float* __restrict__ xout,
    const float* __restrict__ Wq, const float* __restrict__ bq,
    const float* __restrict__ Wk, const float* __restrict__ bk,
    const float* __restrict__ wvc, const float* __restrict__ bvc,
    _Float16* __restrict__ q16, _Float16* __restrict__ k16,
    float* __restrict__ vc)
{
    const int blk = blockIdx.x;
    if (blk < NB_ * TC_ / 4) {
        selector_qkv_body<8>(x_cond, cw_c, cb_c, sw_c, sb_c, vc_out, xout,
                             TC_, 0, blk, Wq, bq, Wk, bk, wvc, bvc,
                             q16, k16, vc);
    } else {
        selector_qkv_body<4>(x_pred, cw_p, cb_p, sw_p, sb_p, vp_out, xout,
                             TP_, TC_, blk - NB_ * TC_ / 4,
                             Wq, bq, Wk, bk, wvc, bvc, q16, k16, vc);
    }
}

// =======================================================================
// entmax15 Newton, TWO head rows per wave INTERLEAVED (R18, 62.4 µs).
// R17 packed-f16 Newton regressed — scalar f32 retained.
// =======================================================================
template <int NJ>
__device__ inline void entmax_head2(unsigned short* __restrict__ sa,
                                    unsigned short* __restrict__ sb,
                                    int lane, int t)
{
    const unsigned* __restrict__ rpa = (const unsigned*)sa;
    const unsigned* __restrict__ rpb = (const unsigned*)sb;
    float va[2 * NJ], vb[2 * NJ];
    #pragma unroll
    for (int j = 0; j < NJ; ++j) {
        const unsigned dwa = rpa[64 * j + lane];
        const unsigned dwb = rpb[64 * j + lane];
        const h2 ha = __builtin_bit_cast(h2, dwa);
        const h2 hb = __builtin_bit_cast(h2, dwb);
        const int s0 = 128 * j + 2 * lane;
        const bool in0 = (s0 <= t), in1 = (s0 + 1 <= t);
        va[2*j]   = in0 ? (float)ha[0] : -1e30f;
        va[2*j+1] = in1 ? (float)ha[1] : -1e30f;
        vb[2*j]   = in0 ? (float)hb[0] : -1e30f;
        vb[2*j+1] = in1 ? (float)hb[1] : -1e30f;
    }

    float ma0 = va[0], ma1 = va[1], mb0 = vb[0], mb1 = vb[1];
    #pragma unroll
    for (int j = 2; j < 2 * NJ; j += 2) {
        ma0 = fmaxf(ma0, va[j]); ma1 = fmaxf(ma1, va[j+1]);
        mb0 = fmaxf(mb0, vb[j]); mb1 = fmaxf(mb1, vb[j+1]);
    }
    const float ma = wave_max(fmaxf(ma0, ma1));
    const float mb = wave_max(fmaxf(mb0, mb1));

    float ta = ma - 1.0f, tb = mb - 1.0f;   // f(tau0) >= 0
    #pragma unroll
    for (int it = 0; it < 7; ++it) {
        float a10 = 0.f, a11 = 0.f, a20 = 0.f, a21 = 0.f;
        float b10 = 0.f, b11 = 0.f, b20 = 0.f, b21 = 0.f;
        #pragma unroll
        for (int j = 0; j < 2 * NJ; j += 2) {
            const float da0 = fmaxf(va[j]   - ta, 0.f);
            const float da1 = fmaxf(va[j+1] - ta, 0.f);
            const float db0 = fmaxf(vb[j]   - tb, 0.f);
            const float db1 = fmaxf(vb[j+1] - tb, 0.f);
            a10 += da0; a11 += da1;
            a20 = fmaf(da0, da0, a20); a21 = fmaf(da1, da1, a21);
            b10 += db0; b11 += db1;
            b20 = fmaf(db0, db0, b20); b21 = fmaf(db1, db1, b21);
        }
        const float S1a = wave_sum(a10 + a11);
        const float S2a = wave_sum(a20 + a21);
        const float S1b = wave_sum(b10 + b11);
        const float S2b = wave_sum(b20 + b21);
        ta += (S2a - 1.0f) * 0.5f * fast_rcp(S1a);
        tb += (S2b - 1.0f) * 0.5f * fast_rcp(S1b);
    }
    {
        float a1 = 0.f, a2 = 0.f, ka = 0.f;
        float b1 = 0.f, b2 = 0.f, kb = 0.f;
        #pragma unroll
        for (int j = 0; j < 2 * NJ; ++j) {
            if (va[j] > ta) { a1 += va[j]; a2 = fmaf(va[j], va[j], a2); ka += 1.f; }
            if (vb[j] > tb) { b1 += vb[j]; b2 = fmaf(vb[j], vb[j], b2); kb += 1.f; }
        }
        a1 = wave_sum(a1); a2 = wave_sum(a2); ka = wave_sum(ka);
        b1 = wave_sum(b1); b2 = wave_sum(b2); kb = wave_sum(kb);
        const float meana = a1 / ka;
        const float arga  = fmaxf(fmaf(meana, meana, -(a2 - 1.0f) / ka), 0.f);
        ta = meana - sqrtf(arga);
        const float meanb = b1 / kb;
        const float argb  = fmaxf(fmaf(meanb, meanb, -(b2 - 1.0f) / kb), 0.f);
        tb = meanb - sqrtf(argb);
    }
    unsigned* __restrict__ wpa = (unsigned*)sa;
    unsigned* __restrict__ wpb = (unsigned*)sb;
    #pragma unroll
    for (int j = 0; j < NJ; ++j) {
        const float da0 = fmaxf(va[2*j]   - ta, 0.f);
        const float da1 = fmaxf(va[2*j+1] - ta, 0.f);
        const float db0 = fmaxf(vb[2*j]   - tb, 0.f);
        const float db1 = fmaxf(vb[2*j+1] - tb, 0.f);
        wpa[64 * j + lane] = pack2h(da0 * da0, da1 * da1);
        wpb[64 * j + lane] = pack2h(db0 * db0, db1 * db1);
    }
}

template <int NJ>
__device__ inline void entmax_pair(unsigned short* __restrict__ scb,
                                   int wave, int lane, int t)
{
    entmax_head2<NJ>(scb + (wave * 2 + 0) * SCP_,
                     scb + (wave * 2 + 1) * SCP_, lane, t);
}

// =======================================================================
// Attention: one block (256 threads, 4 waves) per (b, t).  [R14 config]
// UNCHANGED since R18 (62 µs, VALUBusy ~64%). See R15-R18 notes.
// =======================================================================
__global__ __launch_bounds__(256) void attn_kernel(
    const _Float16* __restrict__ q16, const _Float16* __restrict__ k16,
    const float* __restrict__ vcomb, const float* __restrict__ xin,
    float* __restrict__ xout,
    const float* __restrict__ Wo, const float* __restrict__ bo,
    const float* __restrict__ lng, const float* __restrict__ lnb,
    float* __restrict__ logs)
{
    __shared__ unsigned short scb[H_ * SCP_];   // 24.7 KB f16 scores/weights
    __shared__ _Float16 qrow16[D_];
    __shared__ float red[64];
    __shared__ float o16[DK_];
    __shared__ float yrow[D_];
    __shared__ float stat[2];

    const int blk = blockIdx.x;
    const int t = TT_ - 1 - (blk >> 1);   // descending-work dispatch order
    const int b = blk & 1;
    const int tid = threadIdx.x;
    const int lane = tid & 63, wave = tid >> 6;
    const long rowq  = (long)b * TT_ + t;
    const long bbase = (long)b * TT_;

    if (tid < 64)
        ((unsigned*)qrow16)[tid] = ((const unsigned*)(q16 + rowq * D_))[tid];
    __syncthreads();

    // ---- scores: u = (q.k / 4) / 2 = dot * 0.125, f16 dot2, stored f16 ----
    {
        const int h  = tid & 7;
        const int sl = tid >> 3;   // 0..31
        unsigned short* __restrict__ srow = scb + h * SCP_;
        h2 qv[8];
        __builtin_memcpy(qv, (const _Float16*)qrow16 + h * DK_, 32);
        for (int s = sl; s <= t; s += 32) {
            float4 kk0, kk1;
            {
                const float4* kp4 = (const float4*)(k16 + (bbase + s) * D_ + h * DK_);
                kk0 = kp4[0]; kk1 = kp4[1];
            }
            h2 kh[8];
            __builtin_memcpy(kh,     &kk0, 16);
            __builtin_memcpy(kh + 4, &kk1, 16);
            float dot = 0.f;
            #pragma unroll
            for (int i2 = 0; i2 < 8; ++i2) dot = dot2f(qv[i2], kh[i2], dot);
            const _Float16 sh = (_Float16)(dot * 0.125f);
            srow[s] = __builtin_bit_cast(unsigned short, sh);
        }
    }
    __syncthreads();

    // ---- entmax15: wave w = heads 2w, 2w+1 interleaved; even-NJ templates ----
    {
        const int njn = (t >> 7) + 1;          // needed dwords: 1..12
        switch ((njn + 1) & ~1) {              // round up to even
        case 2:  entmax_pair<2 >(scb, wave, lane, t); break;
        case 4:  entmax_pair<4 >(scb, wave, lane, t); break;
        case 6:  entmax_pair<6 >(scb, wave, lane, t); break;
        case 8:  entmax_pair<8 >(scb, wave, lane, t); break;
        case 10: entmax_pair<10>(scb, wave, lane, t); break;
        default: entmax_pair<12>(scb, wave, lane, t); break;
        }
    }
    __syncthreads();

    // ---- w_avg via v_pk_add_f16 -> logs; acc16 += w_avg * v_comb ----
    float4 A0 = make_float4(0,0,0,0), A1 = A0, A2 = A0, A3 = A0;
    float* lrow = logs + rowq * TT_;
    const unsigned* __restrict__ rp0 = (const unsigned*)scb;
    #pragma unroll
    for (int it = 0; it < 3; ++it) {
        const int dwi = tid + 256 * it;       // 0..767
        const int s0 = 2 * dwi;
        if (s0 <= t) {
            h2 hs = __builtin_bit_cast(h2, rp0[dwi]);
            #pragma unroll
            for (int h = 1; h < H_; ++h)
                hs = hs + __builtin_bit_cast(h2, rp0[h * (SCP_ / 2) + dwi]);
            const float wa0 = (float)hs[0] * 0.125f;
            const float wa1 = (float)hs[1] * 0.125f;  // 0 beyond t
            {
                const float4* vp = (const float4*)(vcomb + (bbase + s0) * DK_);
                const float4 v0 = vp[0], v1 = vp[1], v2 = vp[2], v3 = vp[3];
                A0.x = fmaf(wa0, v0.x, A0.x); A0.y = fmaf(wa0, v0.y, A0.y);
                A0.z = fmaf(wa0, v0.z, A0.z); A0.w = fmaf(wa0, v0.w, A0.w);
                A1.x = fmaf(wa0, v1.x, A1.x); A1.y = fmaf(wa0, v1.y, A1.y);
                A1.z = fmaf(wa0, v1.z, A1.z); A1.w = fmaf(wa0, v1.w, A1.w);
                A2.x = fmaf(wa0, v2.x, A2.x); A2.y = fmaf(wa0, v2.y, A2.y);
                A2.z = fmaf(wa0, v2.z, A2.z); A2.w = fmaf(wa0, v2.w, A2.w);
                A3.x = fmaf(wa0, v3.x, A3.x); A3.y = fmaf(wa0, v3.y, A3.y);
                A3.z = fmaf(wa0, v3.z, A3.z); A3.w = fmaf(wa0, v3.w, A3.w);
            }
            if (s0 + 1 <= t) {
                const float4* vp = (const float4*)(vcomb + (bbase + s0 + 1) * DK_);
                const float4 v0 = vp[0], v1 = vp[1], v2 = vp[2], v3 = vp[3];
                A0.x = fmaf(wa1, v0.x, A0.x); A0.y = fmaf(wa1, v0.y, A0.y);
                A0.z = fmaf(wa1, v0.z, A0.z); A0.w = fmaf(wa1, v0.w, A0.w);
                A1.x = fmaf(wa1, v1.x, A1.x); A1.y = fmaf(wa1, v1.y, A1.y);
                A1.z = fmaf(wa1, v1.z, A1.z); A1.w = fmaf(wa1, v1.w, A1.w);
                A2.x = fmaf(wa1, v2.x, A2.x); A2.y = fmaf(wa1, v2.y, A2.y);
                A2.z = fmaf(wa1, v2.z, A2.z); A2.w = fmaf(wa1, v2.w, A2.w);
                A3.x = fmaf(wa1, v3.x, A3.x); A3.y = fmaf(wa1, v3.y, A3.y);
                A3.z = fmaf(wa1, v3.z, A3.z); A3.w = fmaf(wa1, v3.w, A3.w);
            }
            *(float2*)(lrow + s0) = make_float2(wa0, wa1);
        } else {
            *(float2*)(lrow + s0) = make_float2(0.f, 0.f);
        }
    }
    A0.x = wave_sum_l63(A0.x); A0.y = wave_sum_l63(A0.y);
    A0.z = wave_sum_l63(A0.z); A0.w = wave_sum_l63(A0.w);
    A1.x = wave_sum_l63(A1.x); A1.y = wave_sum_l63(A1.y);
    A1.z = wave_sum_l63(A1.z); A1.w = wave_sum_l63(A1.w);
    A2.x = wave_sum_l63(A2.x); A2.y = wave_sum_l63(A2.y);
    A2.z = wave_sum_l63(A2.z); A2.w = wave_sum_l63(A2.w);
    A3.x = wave_sum_l63(A3.x); A3.y = wave_sum_l63(A3.y);
    A3.z = wave_sum_l63(A3.z); A3.w = wave_sum_l63(A3.w);
    if (lane == 63) {
        float* r = red + wave * 16;
        r[0]=A0.x; r[1]=A0.y; r[2]=A0.z; r[3]=A0.w;
        r[4]=A1.x; r[5]=A1.y; r[6]=A1.z; r[7]=A1.w;
        r[8]=A2.x; r[9]=A2.y; r[10]=A2.z; r[11]=A2.w;
        r[12]=A3.x; r[13]=A3.y; r[14]=A3.z; r[15]=A3.w;
    }
    __syncthreads();
    if (tid < DK_) o16[tid] = red[tid] + red[16 + tid] + red[32 + tid] + red[48 + tid];
    __syncthreads();

    // ---- @Wo + bo, residual, LN1 (single-pass mean/var) ----
    float y = 0.f;
    if (tid < D_) {
        float a = bo[tid];
        #pragma unroll
        for (int j = 0; j < DK_; ++j) a = fmaf(o16[j], Wo[j * D_ + tid], a);
        y = xin[rowq * D_ + tid] + a;
        yrow[tid] = y;
    }
    __syncthreads();
    if (tid < 64) {
        const float y0 = yrow[tid], y1 = yrow[tid + 64];
        float sm = wave_sum_l63(y0 + y1);
        float sq = wave_sum_l63(fmaf(y0, y0, y1 * y1));
        if (tid == 63) {
            const float mean = sm * (1.0f / D_);
            stat[0] = mean;
            stat[1] = fmaxf(sq * (1.0f / D_) - mean * mean, 0.f);
        }
    }
    __syncthreads();
    if (tid < D_) {
        const float r = rsqrtf(stat[1] + 1e-5f);
        xout[rowq * D_ + tid] = (y - stat[0]) * r * lng[tid] + lnb[tid];
    }
}

// =======================================================================
// FFN + LN2 (+ fused next-layer QKV, or final projection).  R23: the
// two GEMMs run on the MATRIX pipe (v_mfma_f32_16x16x32_f16), first
// nonzero MfmaUtil of the session. A = block's 4 rows zero-padded to
// M=16 (f16, LDS, +8-elem row pad -> 2-way bank alias only); B = f16
// fragments pre-packed by prep (per-tile 64x16B, coalesced dwordx4).
// C/D layout (HW-verified m89): col=lane&15, row=(lane>>4)*4+reg ->
// real rows 0-3 live in lanes 0-15. f32 accumulate; LN/QKV/proj remain
// f32 and unchanged.
// =======================================================================
__global__ __launch_bounds__(256) void ffn_kernel(
    const float* __restrict__ xin, float* __restrict__ xout,
    const unsigned* __restrict__ fh1l, const float* __restrict__ fb1,
    const unsigned* __restrict__ fh2l, const float* __restrict__ fb2,
    const float* __restrict__ g, const float* __restrict__ bta,
    int do_qkv,
    const float* __restrict__ Wq, const float* __restrict__ bq,
    const float* __restrict__ Wk, const float* __restrict__ bk,
    const float* __restrict__ wvc, const float* __restrict__ bvc,
    _Float16* __restrict__ q16, _Float16* __restrict__ k16,
    float* __restrict__ vc,
    int do_proj, const float* __restrict__ pw,
    const float* __restrict__ pb, float* __restrict__ outp)
{
    __shared__ float    xrT[D_][4];        // [i][r] f32, residual + QKV  2 KB
    __shared__ _Float16 xh16[16][136];     // A of GEMM1 (rows 4-15 zero) 4.25 KB
    __shared__ _Float16 h16[16][520];      // A of GEMM2 (rows 4-15 zero) 16.25 KB
    __shared__ float    predf[4][D_];      // GEMM2 output rows           2 KB
    __shared__ float    xn[D_];            // last-row normalized (proj)  0.5 KB

    const long row0 = (long)blockIdx.x * 4;
    const int tid = threadIdx.x;
    const int w = tid >> 6, l = tid & 63;

    // stage x: f32 (residual/QKV) + f16 rows 0-3; zero pad rows 4-15
    for (int idx = tid; idx < 4 * D_; idx += 256) {
        const int r = idx >> 7, i = idx & 127;
        const float v = xin[row0 * D_ + idx];
        xrT[i][r] = v;
        xh16[r][i] = (_Float16)v;
    }
    for (int idx = tid; idx < 12 * 64; idx += 256)
        *(unsigned*)&xh16[4 + (idx >> 6)][2 * (idx & 63)] = 0u;
    for (int idx = tid; idx < 12 * 256; idx += 256)
        *(unsigned*)&h16[4 + (idx >> 8)][2 * (idx & 255)] = 0u;
    __syncthreads();

    // ---- GEMM1 (MFMA): [16x128] @ [128x512]; wave w owns nt = 8w..8w+7 ----
    {
        const int arow = l & 15, ak = 8 * (l >> 4);
        h8 af[4];
        #pragma unroll
        for (int kt = 0; kt < 4; ++kt)
            af[kt] = *(const h8*)&xh16[arow][kt * 32 + ak];
        #pragma unroll
        for (int nt8 = 0; nt8 < 8; ++nt8) {
            const int nt = w * 8 + nt8;
            f32x4 acc = {0.f, 0.f, 0.f, 0.f};
            #pragma unroll
            for (int kt = 0; kt < 4; ++kt) {
                const h8 bf = *(const h8*)(fh1l + (((kt * 32 + nt) * 64 + l) << 2));
                acc = __builtin_amdgcn_mfma_f32_16x16x32_f16(af[kt], bf, acc, 0, 0, 0);
            }
            if (l < 16) {
                const int col = nt * 16 + l;
                const float bias = fb1[col];
                #pragma unroll
                for (int j = 0; j < 4; ++j)
                    h16[j][col] = (_Float16)fmaxf(acc[j] + bias, 0.f);
            }
        }
    }
    __syncthreads();

    // ---- GEMM2 (MFMA): [16x512] @ [512x128]; wave w owns nt = 2w, 2w+1 ----
    {
        const int arow = l & 15, ak = 8 * (l >> 4);
        f32x4 acc0 = {0.f, 0.f, 0.f, 0.f}, acc1 = acc0;
        for (int kt = 0; kt < 16; ++kt) {
            const h8 af = *(const h8*)&h16[arow][kt * 32 + ak];
            const h8 b0 = *(const h8*)(fh2l + (((kt * 8 + 2 * w + 0) * 64 + l) << 2));
            const h8 b1 = *(const h8*)(fh2l + (((kt * 8 + 2 * w + 1) * 64 + l) << 2));
            acc0 = __builtin_amdgcn_mfma_f32_16x16x32_f16(af, b0, acc0, 0, 0, 0);
            acc1 = __builtin_amdgcn_mfma_f32_16x16x32_f16(af, b1, acc1, 0, 0, 0);
        }
        if (l < 16) {
            #pragma unroll
            for (int j = 0; j < 4; ++j) {
                predf[j][(2 * w + 0) * 16 + l] = acc0[j];
                predf[j][(2 * w + 1) * 16 + l] = acc1[j];
            }
        }
    }
    __syncthreads();

    // LN per row, fused bias+residual (R22): wave w handles row w
    const int lane = l;
    const bool pblk = do_proj && (((row0 + 4) % TT_) == 0);
    {
        const float y0 = predf[w][lane]      + fb2[lane]      + xrT[lane][w];
        const float y1 = predf[w][lane + 64] + fb2[lane + 64] + xrT[lane + 64][w];
        const float sm = wave_sum(y0 + y1);
        const float sq = wave_sum(fmaf(y0, y0, y1 * y1));
        const float mean = sm * (1.0f / D_);
        const float var  = fmaxf(sq * (1.0f / D_) - mean * mean, 0.f);
        const float rcp = rsqrtf(var + 1e-5f);
        const float o0 = (y0 - mean) * rcp * g[lane]      + bta[lane];
        const float o1 = (y1 - mean) * rcp * g[lane + 64] + bta[lane + 64];
        xout[(row0 + w) * D_ + lane]      = o0;
        xout[(row0 + w) * D_ + lane + 64] = o1;
        xrT[lane][w]      = o0;           // re-stash for fused qkv
        xrT[lane + 64][w] = o1;
        if (pblk && w == 3) { xn[lane] = o0; xn[lane + 64] = o1; }
    }

    if (do_qkv) {
        __syncthreads();   // xrT now holds the 4 normalized rows
        const int c = tid & 127;
        const int which = tid >> 7;             // 0: q, 1: k (wave-uniform)
        const float* __restrict__ W = which ? Wk : Wq;
        const float bb = which ? bk[c] : bq[c];
        float a0 = bb, a1 = bb, a2 = bb, a3 = bb;
        for (int i = 0; i < D_; ++i) {
            const float wv = W[i * D_ + c];
            const float4 xv = *(const float4*)&xrT[i][0];
            a0 = fmaf(xv.x, wv, a0);
            a1 = fmaf(xv.y, wv, a1);
            a2 = fmaf(xv.z, wv, a2);
            a3 = fmaf(xv.w, wv, a3);
        }
        _Float16* __restrict__ dst = which ? k16 : q16;
        dst[(row0 + 0) * D_ + c] = (_Float16)a0;
        dst[(row0 + 1) * D_ + c] = (_Float16)a1;
        dst[(row0 + 2) * D_ + c] = (_Float16)a2;
        dst[(row0 + 3) * D_ + c] = (_Float16)a3;

        if (tid < 64) {
            const int r = tid >> 4, c16 = tid & 15;
            float av = bvc[c16];
            for (int i = 0; i < D_; ++i)
                av = fmaf(xrT[i][r], wvc[i * DK_ + c16], av);
            vc[(row0 + r) * DK_ + c16] = av;
        }
    }

    if (pblk) {
        __syncthreads();   // block-uniform condition — safe
        const int b = (int)((row0 + 3) / TT_);
        for (int idx = tid; idx < NQ_ * HOR_; idx += 256) {
            const int qq = idx / HOR_, hh = idx - qq * HOR_;
            float s = pb[idx];
            for (int d = 0; d < D_; ++d)
                s = fmaf(xn[d], pw[((long)qq * D_ + d) * HOR_ + hh], s);
            outp[b * NQ_ * HOR_ + idx] = s;
        }
    }
}

} // namespace

extern "C" void kernel_launch(void* const* d_in, const int* in_sizes, int n_in,
                              void* d_out, int out_size, void* d_ws, size_t ws_size,
                              hipStream_t stream) {
    (void)in_sizes; (void)n_in; (void)out_size; (void)ws_size;

    const float* x_cond = (const float*)d_in[0];
    const float* x_pred = (const float*)d_in[1];
    const float* cw_c   = (const float*)d_in[2];
    const float* cb_c   = (const float*)d_in[3];
    const float* sw_c   = (const float*)d_in[4];
    const float* sb_c   = (const float*)d_in[5];
    const float* cw_p   = (const float*)d_in[6];
    const float* cb_p   = (const float*)d_in[7];
    const float* sw_p   = (const float*)d_in[8];
    const float* sb_p   = (const float*)d_in[9];
    const float* Wq     = (const float*)d_in[10];
    const float* bq     = (const float*)d_in[11];
    const float* Wk     = (const float*)d_in[12];
    const float* bk     = (const float*)d_in[13];
    const float* Wv     = (const float*)d_in[14];
    const float* bv     = (const float*)d_in[15];
    const float* Wo     = (const float*)d_in[16];
    const float* bo     = (const float*)d_in[17];
    const float* ln1g   = (const float*)d_in[18];
    const float* ln1b   = (const float*)d_in[19];
    const float* fw1    = (const float*)d_in[20];
    const float* fb1    = (const float*)d_in[21];
    const float* fw2    = (const float*)d_in[22];
    const float* fb2    = (const float*)d_in[23];
    const float* ln2g   = (const float*)d_in[24];
    const float* ln2b   = (const float*)d_in[25];
    const float* pw     = (const float*)d_in[26];
    const float* pb     = (const float*)d_in[27];

    float* outp = (float*)d_out;
    float* ws   = (float*)d_ws;
    float*     xA   = ws + WS_XA;
    float*     xB   = ws + WS_XB;
    _Float16*  q16  = (_Float16*)(ws + WS_Q16);
    _Float16*  k16  = (_Float16*)(ws + WS_K16);
    float*     vcb  = ws + WS_VC;
    float*     wvc  = ws + WS_WVC;
    float*     bvc  = ws + WS_BVC;
    unsigned*  fh1  = (unsigned*)(ws + WS_FH1);
    unsigned*  fh2  = (unsigned*)(ws + WS_FH2);

    // Wv head-mean + MFMA B-fragment packing (must precede pre/ffn)
    prep_kernel<<<128, 256, 0, stream>>>(Wv, bv, wvc, bvc,
                                         fw1, fw2, fh1, fh2);

    // selectors + layer-0 QKV, one launch (R19: 4 tokens per block)
    pre_kernel<<<(NB_ * TC_ + NB_ * TP_) / 4, 256, 0, stream>>>(
        x_cond, cw_c, cb_c, sw_c, sb_c,
        x_pred, cw_p, cb_p, sw_p, sb_p,
        outp + OFF_VC, outp + OFF_VP, xA,
        Wq, bq, Wk, bk, wvc, bvc, q16, k16, vcb);

    for (int l = 0; l < L_; ++l) {
        attn_kernel<<<NB_ * TT_, 256, 0, stream>>>(
            q16, k16, vcb, xA, xB,
            Wo + (long)l * DK_ * D_, bo + l * D_,
            ln1g + l * D_, ln1b + l * D_,
            outp + OFF_LOGS + (long)l * NB_ * TT_ * TT_);
        const int nl = l + 1;
        ffn_kernel<<<NB_ * TT_ / 4, 256, 0, stream>>>(
            xB, xA, fh1 + (long)l * FHL_, fb1 + l * DFF_,
            fh2 + (long)l * FHL_, fb2 + l * D_,
            ln2g + l * D_, ln2b + l * D_,
            (l < L_ - 1) ? 1 : 0,
            Wq + (long)nl * D_ * D_ * (l < L_ - 1),
            bq + nl * D_ * (l < L_ - 1),
            Wk + (long)nl * D_ * D_ * (l < L_ - 1),
            bk + nl * D_ * (l < L_ - 1),
            wvc + nl * D_ * DK_ * (l < L_ - 1),
            bvc + nl * DK_ * (l < L_ - 1),
            q16, k16, vcb,
            (l == L_ - 1) ? 1 : 0, pw, pb, outp);
    }
}

// Round 10
// 282.280 us; speedup vs baseline: 1.1890x; 1.0099x over previous
//
#include <hip/hip_runtime.h>

namespace {

constexpr int NB_  = 2;
constexpr int TC_  = 1024;
constexpr int TP_  = 512;
constexpr int TT_  = 1536;   // TC + TP
constexpr int D_   = 128;
constexpr int H_   = 8;
constexpr int DK_  = 16;
constexpr int DFF_ = 512;
constexpr int L_   = 2;
constexpr int HOR_ = 96;
constexpr int NQ_  = 3;

constexpr int SCP_ = TT_ + 8;   // ushort stride per head row (even → dword-tiled)

typedef _Float16 h2 __attribute__((ext_vector_type(2)));
typedef _Float16 h8 __attribute__((ext_vector_type(8)));
typedef float    f32x4 __attribute__((ext_vector_type(4)));

// ---- output float offsets (return order: out, v_cond, v_pred, logs) ----
constexpr int OFF_OUT  = 0;
constexpr int OFF_VC   = NB_ * NQ_ * HOR_;            // 576
constexpr int OFF_VP   = OFF_VC + NB_ * TC_ * 8;      // 16960
constexpr int OFF_LOGS = OFF_VP + NB_ * TP_ * 4;      // 21056

// ---- workspace float offsets ----
constexpr int WS_XA  = 0;
constexpr int WS_XB  = WS_XA  + NB_ * TT_ * D_;       // 393216
constexpr int WS_Q16 = WS_XB  + NB_ * TT_ * D_;       // f16, half-sized
constexpr int WS_K16 = WS_Q16 + NB_ * TT_ * D_ / 2;
constexpr int WS_VC  = WS_K16 + NB_ * TT_ * D_ / 2;
constexpr int WS_WVC = WS_VC  + NB_ * TT_ * DK_;      // 2 layers x 2048
constexpr int WS_BVC = WS_WVC + L_ * D_ * DK_;        // 2 layers x 16
// R23: MFMA B-fragments for ffn GEMM1/GEMM2 (f16 pairs, 1 dword each).
// Per tile: 64 lanes x 4 dwords (16B lane fragment), frag layout
// col = lane&15, k = 8*(lane>>4) + j  (j = 0..7 contiguous in k).
constexpr int FHL_   = 32768;                         // dwords per layer
constexpr int WS_FH1 = WS_BVC + L_ * DK_;
constexpr int WS_FH2 = WS_FH1 + L_ * FHL_;
// R24: MFMA B-fragments for QKV (Wq/Wk [128][128]: 4 kt x 8 nt tiles).
constexpr int WHQL_  = 8192;                          // dwords per layer
constexpr int WS_WHQ = WS_FH2 + L_ * FHL_;
constexpr int WS_WHK = WS_WHQ + L_ * WHQL_;

__device__ inline float dot2f(h2 a, h2 b, float c) {
#if __has_builtin(__builtin_amdgcn_fdot2)
    return __builtin_amdgcn_fdot2(a, b, c, false);
#else
    return c + (float)a[0] * (float)b[0] + (float)a[1] * (float)b[1];
#endif
}

__device__ inline unsigned pack2h(float a, float b) {   // 1 inst: v_cvt_pkrtz
#if __has_builtin(__builtin_amdgcn_cvt_pkrtz)
    return __builtin_bit_cast(unsigned, __builtin_amdgcn_cvt_pkrtz(a, b));
#else
    h2 p; p[0] = (_Float16)a; p[1] = (_Float16)b;
    return __builtin_bit_cast(unsigned, p);
#endif
}

__device__ inline float fast_rcp(float x) {             // v_rcp_f32, 1 inst
#if __has_builtin(__builtin_amdgcn_rcpf)
    return __builtin_amdgcn_rcpf(x);
#else
    return 1.0f / x;
#endif
}

// =======================================================================
// DPP wave reductions — VALU pipe (R16: attn 79->64 µs).
// MEASURED-DEAD-END ledger (do not retry):
//  - R17/R20: packed-f16 fdot2 rewrites of f32 VALU loops (attn Newton
//    64->82 µs; ffn/pre +35 µs).
//  - R21/R6: ffn GEMM1 float2 weight loads (300.2 -> 310.8 µs).
//  - R22/R7: yb-fusion in ffn LN: neutral (noise band ±3-5 µs).
// MEASURED-WIN ledger:
//  - R23/R8: ffn GEMMs on MFMA (v_mfma_f32_16x16x32_f16, M=16 pad):
//    302.9 -> 285.1. Fragment layouts verified end-to-end.
// R9 bench was an INFRA failure (container failed twice) — this is an
// unchanged resubmit of the R24 kernel (QKV on MFMA).
// =======================================================================
template <int CTRL>
__device__ inline float dpp_add(float x) {
    const int y = __builtin_amdgcn_update_dpp(
        0, __builtin_bit_cast(int, x), CTRL, 0xF, 0xF, true);
    return x + __builtin_bit_cast(float, y);
}
template <int CTRL>
__device__ inline float dpp_maxf(float x) {
    const int y = __builtin_amdgcn_update_dpp(
        __builtin_bit_cast(int, x), __builtin_bit_cast(int, x),
        CTRL, 0xF, 0xF, false);
    return fmaxf(x, __builtin_bit_cast(float, y));
}
__device__ inline float bcast63(float x) {
    return __builtin_bit_cast(float,
        __builtin_amdgcn_readlane(__builtin_bit_cast(int, x), 63));
}
__device__ inline float wave_sum_l63(float x) {
    x = dpp_add<0x111>(x); x = dpp_add<0x112>(x); x = dpp_add<0x114>(x);
    x = dpp_add<0x118>(x); x = dpp_add<0x142>(x); x = dpp_add<0x143>(x);
    return x;
}
__device__ inline float wave_sum(float x) { return bcast63(wave_sum_l63(x)); }
__device__ inline float wave_max(float x) {
    x = dpp_maxf<0x111>(x); x = dpp_maxf<0x112>(x); x = dpp_maxf<0x114>(x);
    x = dpp_maxf<0x118>(x); x = dpp_maxf<0x142>(x); x = dpp_maxf<0x143>(x);
    return bcast63(x);
}

// =======================================================================
// Prep: Wv head-mean + MFMA B-fragment packing (R23 ffn, R24 QKV).
// =======================================================================
__global__ __launch_bounds__(256) void prep_kernel(
    const float* __restrict__ Wv, const float* __restrict__ bv,
    float* __restrict__ wvc, float* __restrict__ bvc,
    const float* __restrict__ fw1, const float* __restrict__ fw2,
    const float* __restrict__ Wq, const float* __restrict__ Wk,
    unsigned* __restrict__ fh1, unsigned* __restrict__ fh2,
    unsigned* __restrict__ whq, unsigned* __restrict__ whk)
{
    const int gid = blockIdx.x * 256 + threadIdx.x;
    const int stride = gridDim.x * 256;

    for (int e = gid; e < L_ * D_ * DK_; e += stride) {
        const int l = e / (D_ * DK_), rem = e - l * D_ * DK_;
        const int i = rem >> 4, dk = rem & 15;
        const float* W = Wv + (long)l * D_ * D_;
        float s = 0.f;
        #pragma unroll
        for (int hh = 0; hh < H_; ++hh) s += W[i * D_ + hh * DK_ + dk];
        wvc[e] = s * 0.125f;
    }
    for (int e = gid; e < L_ * DK_; e += stride) {
        const int l = e / DK_, dk = e - l * DK_;
        const float* bb = bv + l * D_;
        float s = 0.f;
        #pragma unroll
        for (int hh = 0; hh < H_; ++hh) s += bb[hh * DK_ + dk];
        bvc[e] = s * 0.125f;
    }
    // fh1: GEMM1 B = fw1 [k=128][n=512]; tiles kt 0..3, nt 0..31
    for (int e = gid; e < L_ * FHL_; e += stride) {
        const int l = e >> 15, rem = e & 32767;
        const int tile = rem >> 8, within = rem & 255;
        const int lane = within >> 2, p = within & 3;
        const int kt = tile >> 5, nt = tile & 31;
        const int k = kt * 32 + 8 * (lane >> 4) + 2 * p;
        const int n = nt * 16 + (lane & 15);
        const float* W = fw1 + (long)l * D_ * DFF_;
        fh1[e] = pack2h(W[k * DFF_ + n], W[(k + 1) * DFF_ + n]);
    }
    // fh2: GEMM2 B = fw2 [k=512][n=128]; tiles kt 0..15, nt 0..7
    for (int e = gid; e < L_ * FHL_; e += stride) {
        const int l = e >> 15, rem = e & 32767;
        const int tile = rem >> 8, within = rem & 255;
        const int lane = within >> 2, p = within & 3;
        const int kt = tile >> 3, nt = tile & 7;
        const int k = kt * 32 + 8 * (lane >> 4) + 2 * p;
        const int n = nt * 16 + (lane & 15);
        const float* W = fw2 + (long)l * DFF_ * D_;
        fh2[e] = pack2h(W[k * D_ + n], W[(k + 1) * D_ + n]);
    }
    // whq/whk: QKV B = Wq/Wk [k=128][n=128]; tiles kt 0..3, nt 0..7
    for (int e = gid; e < L_ * WHQL_; e += stride) {
        const int l = e >> 13, rem = e & 8191;
        const int tile = rem >> 8, within = rem & 255;
        const int lane = within >> 2, p = within & 3;
        const int kt = tile >> 3, nt = tile & 7;
        const int k = kt * 32 + 8 * (lane >> 4) + 2 * p;
        const int n = nt * 16 + (lane & 15);
        const float* Q = Wq + (long)l * D_ * D_;
        const float* K = Wk + (long)l * D_ * D_;
        whq[e] = pack2h(Q[k * D_ + n], Q[(k + 1) * D_ + n]);
        whk[e] = pack2h(K[k * D_ + n], K[(k + 1) * D_ + n]);
    }
}

// =======================================================================
// Selector + fused layer-0 QKV — R19: 4 tokens/block (768 blocks), one
// wave per token for the selector. R24: QKV on the MFMA pipe (same
// fragment scheme as R23 ffn): waves 0-1 -> Q n-tiles, waves 2-3 -> K.
// =======================================================================
template <int NV>
__device__ inline void selector_qkv_body(
    const float* __restrict__ x, const float* __restrict__ cw,
    const float* __restrict__ cb, const float* __restrict__ sw,
    const float* __restrict__ sb, float* __restrict__ vout,
    float* __restrict__ xout, int Tsel, int row_off, int blk,
    const unsigned* __restrict__ whq0, const float* __restrict__ bq,
    const unsigned* __restrict__ whk0, const float* __restrict__ bk,
    const float* __restrict__ wvc, const float* __restrict__ bvc,
    _Float16* __restrict__ q16, _Float16* __restrict__ k16,
    float* __restrict__ vc)
{
    const int tpb = Tsel / 4;            // token-groups per batch
    const int b   = blk / tpb;
    const int t0  = (blk - b * tpb) * 4;
    const int tid = threadIdx.x;
    const int lane = tid & 63, wave = tid >> 6;
    const int t = t0 + wave;             // this wave's token

    __shared__ float    xrT[D_][4];      // staged selector outputs [d][r]
    __shared__ _Float16 xh16[16][136];   // A rows (4 real + 12 zero)

    // zero-pad A rows 4-15 (before barrier; disjoint from row 0-3 writes)
    for (int idx = tid; idx < 12 * 64; idx += 256)
        *(unsigned*)&xh16[4 + (idx >> 6)][2 * (idx & 63)] = 0u;

    // ---- selector: lane covers dims d0 = lane, d1 = lane + 64 ----
    const int d0 = lane, d1 = lane + 64;
    float xw[3 * NV];
    #pragma unroll
    for (int kk = 0; kk < 3; ++kk) {
        const int ts = t + kk - 2;
        #pragma unroll
        for (int v = 0; v < NV; ++v)
            xw[kk * NV + v] = (ts >= 0) ? x[((long)b * Tsel + ts) * NV + v] : 0.0f;
    }
    float ls0[NV], ls1[NV];
    #pragma unroll
    for (int v = 0; v < NV; ++v) {
        const float* c0 = cw + ((long)(v * D_ + d0)) * 3;
        const float* c1 = cw + ((long)(v * D_ + d1)) * 3;
        float a0 = cb[v * D_ + d0], a1 = cb[v * D_ + d1];
        a0 = fmaf(xw[0*NV+v], c0[0], a0); a1 = fmaf(xw[0*NV+v], c1[0], a1);
        a0 = fmaf(xw[1*NV+v], c0[1], a0); a1 = fmaf(xw[1*NV+v], c1[1], a1);
        a0 = fmaf(xw[2*NV+v], c0[2], a0); a1 = fmaf(xw[2*NV+v], c1[2], a1);
        ls0[v] = a0; ls1[v] = a1;
    }
    float u[NV];
    {
        const float s0 = sw[d0], s1 = sw[d1];
        #pragma unroll
        for (int v = 0; v < NV; ++v)
            u[v] = wave_sum(fmaf(ls1[v], s1, ls0[v] * s0));
    }
    // tiny entmax Newton, run redundantly by all 64 lanes (no divergence)
    float wls[NV];
    {
        float m = -1e30f;
        #pragma unroll
        for (int v = 0; v < NV; ++v) {
            float s = u[v] + sb[0];
            s = fminf(fmaxf(s, -10.0f), 10.0f);
            u[v] = 0.5f * s;
            m = fmaxf(m, u[v]);
        }
        float tau = m - 1.0f;
        for (int it = 0; it < 12; ++it) {
            float S1 = 0.f, S2 = 0.f;
            #pragma unroll
            for (int v = 0; v < NV; ++v) {
                float dd = fmaxf(u[v] - tau, 0.f);
                S1 += dd; S2 = fmaf(dd, dd, S2);
            }
            tau += (S2 - 1.0f) * 0.5f * fast_rcp(S1);   // self-correcting
        }
        float S1 = 0.f, S2 = 0.f, K = 0.f;
        #pragma unroll
        for (int v = 0; v < NV; ++v) {
            if (u[v] > tau) { S1 += u[v]; S2 = fmaf(u[v], u[v], S2); K += 1.f; }
        }
        const float mean = S1 / K;
        const float arg  = fmaxf(fmaf(mean, mean, -(S2 - 1.0f) / K), 0.f);
        tau = mean - sqrtf(arg);
        #pragma unroll
        for (int v = 0; v < NV; ++v) {
            const float dd = fmaxf(u[v] - tau, 0.f);
            wls[v] = dd * dd;
        }
    }
    float acc0 = 0.f, acc1 = 0.f;
    #pragma unroll
    for (int v = 0; v < NV; ++v) {
        acc0 = fmaf(ls0[v], wls[v], acc0);
        acc1 = fmaf(ls1[v], wls[v], acc1);
    }
    const long rowb = (long)b * TT_ + row_off + t0;   // block's first row
    const long row  = rowb + wave;
    xout[row * D_ + d0] = acc0;
    xout[row * D_ + d1] = acc1;
    xrT[d0][wave] = acc0;
    xrT[d1][wave] = acc1;
    xh16[wave][d0] = (_Float16)acc0;
    xh16[wave][d1] = (_Float16)acc1;
    if (lane == 0) {
        #pragma unroll
        for (int v = 0; v < NV; ++v)
            vout[((long)b * Tsel + t) * NV + v] = wls[v];
    }
    __syncthreads();

    // ---- fused layer-0 QKV via MFMA (R24): wave -> {Q|K} x 4 n-tiles ----
    {
        const int which = wave >> 1;            // 0: Q (waves 0,1), 1: K
        const unsigned* __restrict__ Wp = which ? whk0 : whq0;
        const float* __restrict__ bias = which ? bk : bq;
        _Float16* __restrict__ dst = which ? k16 : q16;
        const int ntb = (wave & 1) * 4;
        const int arow = lane & 15, ak = 8 * (lane >> 4);
        h8 af[4];
        #pragma unroll
        for (int kt = 0; kt < 4; ++kt)
            af[kt] = *(const h8*)&xh16[arow][kt * 32 + ak];
        #pragma unroll
        for (int nt4 = 0; nt4 < 4; ++nt4) {
            const int nt = ntb + nt4;
            f32x4 acc = {0.f, 0.f, 0.f, 0.f};
            #pragma unroll
            for (int kt = 0; kt < 4; ++kt) {
                const h8 bf = *(const h8*)(Wp + (((kt * 8 + nt) * 64 + lane) << 2));
                acc = __builtin_amdgcn_mfma_f32_16x16x32_f16(af[kt], bf, acc, 0, 0, 0);
            }
            if (lane < 16) {
                const int col = nt * 16 + lane;
                const float bb = bias[col];
                #pragma unroll
                for (int j = 0; j < 4; ++j)
                    dst[(rowb + j) * D_ + col] = (_Float16)(acc[j] + bb);
            }
        }
    }
    if (tid < 64) {
        const int r = tid >> 4, c16 = tid & 15;
        float av = bvc[c16];
        for (int i = 0; i < D_; ++i)
            av = fmaf(xrT[i][r], wvc[i * DK_ + c16], av);
        vc[(rowb + r) * DK_ + c16] = av;
    }
}

__global__ __launch_bounds__(256) void pre_kernel(
    const float* __restrict__ x_cond, const float* __restrict__ cw_c,
    const float* __restrict__ cb_c, const float* __restrict__ sw_c,
    const float* __restrict__ sb_c,
    const float* __restrict__ x_pred, const float* __restrict__ cw_p,
    const float* __restrict__ cb_p, const float* __restrict__ sw_p,
    const float* __restrict__ sb_p,
    float* __restrict__ vc_out, float* __restrict__ vp_out,
    float* __restrict__ xout,
    const unsigned* __restrict__ whq0, const float* __restrict__ bq,
    const unsigned* __restrict__ whk0, const float* __restrict__ bk,
    const float* __restrict__ wvc, const float* __restrict__ bvc,
    _Float16* __restrict__ q16, _Float16* __restrict__ k16,
    float* __restrict__ vc)
{
    const int blk = blockIdx.x;
    if (blk < NB_ * TC_ / 4) {
        selector_qkv_body<8>(x_cond, cw_c, cb_c, sw_c, sb_c, vc_out, xout,
                             TC_, 0, blk, whq0, bq, whk0, bk, wvc, bvc,
                             q16, k16, vc);
    } else {
        selector_qkv_body<4>(x_pred, cw_p, cb_p, sw_p, sb_p, vp_out, xout,
                             TP_, TC_, blk - NB_ * TC_ / 4,
                             whq0, bq, whk0, bk, wvc, bvc, q16, k16, vc);
    }
}

// =======================================================================
// entmax15 Newton, TWO head rows per wave INTERLEAVED (R18, 62.4 µs).
// R17 packed-f16 Newton regressed — scalar f32 retained.
// =======================================================================
template <int NJ>
__device__ inline void entmax_head2(unsigned short* __restrict__ sa,
                                    unsigned short* __restrict__ sb,
                                    int lane, int t)
{
    const unsigned* __restrict__ rpa = (const unsigned*)sa;
    const unsigned* __restrict__ rpb = (const unsigned*)sb;
    float va[2 * NJ], vb[2 * NJ];
    #pragma unroll
    for (int j = 0; j < NJ; ++j) {
        const unsigned dwa = rpa[64 * j + lane];
        const unsigned dwb = rpb[64 * j + lane];
        const h2 ha = __builtin_bit_cast(h2, dwa);
        const h2 hb = __builtin_bit_cast(h2, dwb);
        const int s0 = 128 * j + 2 * lane;
        const bool in0 = (s0 <= t), in1 = (s0 + 1 <= t);
        va[2*j]   = in0 ? (float)ha[0] : -1e30f;
        va[2*j+1] = in1 ? (float)ha[1] : -1e30f;
        vb[2*j]   = in0 ? (float)hb[0] : -1e30f;
        vb[2*j+1] = in1 ? (float)hb[1] : -1e30f;
    }

    float ma0 = va[0], ma1 = va[1], mb0 = vb[0], mb1 = vb[1];
    #pragma unroll
    for (int j = 2; j < 2 * NJ; j += 2) {
        ma0 = fmaxf(ma0, va[j]); ma1 = fmaxf(ma1, va[j+1]);
        mb0 = fmaxf(mb0, vb[j]); mb1 = fmaxf(mb1, vb[j+1]);
    }
    const float ma = wave_max(fmaxf(ma0, ma1));
    const float mb = wave_max(fmaxf(mb0, mb1));

    float ta = ma - 1.0f, tb = mb - 1.0f;   // f(tau0) >= 0
    #pragma unroll
    for (int it = 0; it < 7; ++it) {
        float a10 = 0.f, a11 = 0.f, a20 = 0.f, a21 = 0.f;
        float b10 = 0.f, b11 = 0.f, b20 = 0.f, b21 = 0.f;
        #pragma unroll
        for (int j = 0; j < 2 * NJ; j += 2) {
            const float da0 = fmaxf(va[j]   - ta, 0.f);
            const float da1 = fmaxf(va[j+1] - ta, 0.f);
            const float db0 = fmaxf(vb[j]   - tb, 0.f);
            const float db1 = fmaxf(vb[j+1] - tb, 0.f);
            a10 += da0; a11 += da1;
            a20 = fmaf(da0, da0, a20); a21 = fmaf(da1, da1, a21);
            b10 += db0; b11 += db1;
            b20 = fmaf(db0, db0, b20); b21 = fmaf(db1, db1, b21);
        }
        const float S1a = wave_sum(a10 + a11);
        const float S2a = wave_sum(a20 + a21);
        const float S1b = wave_sum(b10 + b11);
        const float S2b = wave_sum(b20 + b21);
        ta += (S2a - 1.0f) * 0.5f * fast_rcp(S1a);
        tb += (S2b - 1.0f) * 0.5f * fast_rcp(S1b);
    }
    {
        float a1 = 0.f, a2 = 0.f, ka = 0.f;
        float b1 = 0.f, b2 = 0.f, kb = 0.f;
        #pragma unroll
        for (int j = 0; j < 2 * NJ; ++j) {
            if (va[j] > ta) { a1 += va[j]; a2 = fmaf(va[j], va[j], a2); ka += 1.f; }
            if (vb[j] > tb) { b1 += vb[j]; b2 = fmaf(vb[j], vb[j], b2); kb += 1.f; }
        }
        a1 = wave_sum(a1); a2 = wave_sum(a2); ka = wave_sum(ka);
        b1 = wave_sum(b1); b2 = wave_sum(b2); kb = wave_sum(kb);
        const float meana = a1 / ka;
        const float arga  = fmaxf(fmaf(meana, meana, -(a2 - 1.0f) / ka), 0.f);
        ta = meana - sqrtf(arga);
        const float meanb = b1 / kb;
        const float argb  = fmaxf(fmaf(meanb, meanb, -(b2 - 1.0f) / kb), 0.f);
        tb = meanb - sqrtf(argb);
    }
    unsigned* __restrict__ wpa = (unsigned*)sa;
    unsigned* __restrict__ wpb = (unsigned*)sb;
    #pragma unroll
    for (int j = 0; j < NJ; ++j) {
        const float da0 = fmaxf(va[2*j]   - ta, 0.f);
        const float da1 = fmaxf(va[2*j+1] - ta, 0.f);
        const float db0 = fmaxf(vb[2*j]   - tb, 0.f);
        const float db1 = fmaxf(vb[2*j+1] - tb, 0.f);
        wpa[64 * j + lane] = pack2h(da0 * da0, da1 * da1);
        wpb[64 * j + lane] = pack2h(db0 * db0, db1 * db1);
    }
}

template <int NJ>
__device__ inline void entmax_pair(unsigned short* __restrict__ scb,
                                   int wave, int lane, int t)
{
    entmax_head2<NJ>(scb + (wave * 2 + 0) * SCP_,
                     scb + (wave * 2 + 1) * SCP_, lane, t);
}

// =======================================================================
// Attention: one block (256 threads, 4 waves) per (b, t).  [R14 config]
// UNCHANGED since R18 (62 µs, VALUBusy ~64%). See R15-R18 notes.
// =======================================================================
__global__ __launch_bounds__(256) void attn_kernel(
    const _Float16* __restrict__ q16, const _Float16* __restrict__ k16,
    const float* __restrict__ vcomb, const float* __restrict__ xin,
    float* __restrict__ xout,
    const float* __restrict__ Wo, const float* __restrict__ bo,
    const float* __restrict__ lng, const float* __restrict__ lnb,
    float* __restrict__ logs)
{
    __shared__ unsigned short scb[H_ * SCP_];   // 24.7 KB f16 scores/weights
    __shared__ _Float16 qrow16[D_];
    __shared__ float red[64];
    __shared__ float o16[DK_];
    __shared__ float yrow[D_];
    __shared__ float stat[2];

    const int blk = blockIdx.x;
    const int t = TT_ - 1 - (blk >> 1);   // descending-work dispatch order
    const int b = blk & 1;
    const int tid = threadIdx.x;
    const int lane = tid & 63, wave = tid >> 6;
    const long rowq  = (long)b * TT_ + t;
    const long bbase = (long)b * TT_;

    if (tid < 64)
        ((unsigned*)qrow16)[tid] = ((const unsigned*)(q16 + rowq * D_))[tid];
    __syncthreads();

    // ---- scores: u = (q.k / 4) / 2 = dot * 0.125, f16 dot2, stored f16 ----
    {
        const int h  = tid & 7;
        const int sl = tid >> 3;   // 0..31
        unsigned short* __restrict__ srow = scb + h * SCP_;
        h2 qv[8];
        __builtin_memcpy(qv, (const _Float16*)qrow16 + h * DK_, 32);
        for (int s = sl; s <= t; s += 32) {
            float4 kk0, kk1;
            {
                const float4* kp4 = (const float4*)(k16 + (bbase + s) * D_ + h * DK_);
                kk0 = kp4[0]; kk1 = kp4[1];
            }
            h2 kh[8];
            __builtin_memcpy(kh,     &kk0, 16);
            __builtin_memcpy(kh + 4, &kk1, 16);
            float dot = 0.f;
            #pragma unroll
            for (int i2 = 0; i2 < 8; ++i2) dot = dot2f(qv[i2], kh[i2], dot);
            const _Float16 sh = (_Float16)(dot * 0.125f);
            srow[s] = __builtin_bit_cast(unsigned short, sh);
        }
    }
    __syncthreads();

    // ---- entmax15: wave w = heads 2w, 2w+1 interleaved; even-NJ templates ----
    {
        const int njn = (t >> 7) + 1;          // needed dwords: 1..12
        switch ((njn + 1) & ~1) {              // round up to even
        case 2:  entmax_pair<2 >(scb, wave, lane, t); break;
        case 4:  entmax_pair<4 >(scb, wave, lane, t); break;
        case 6:  entmax_pair<6 >(scb, wave, lane, t); break;
        case 8:  entmax_pair<8 >(scb, wave, lane, t); break;
        case 10: entmax_pair<10>(scb, wave, lane, t); break;
        default: entmax_pair<12>(scb, wave, lane, t); break;
        }
    }
    __syncthreads();

    // ---- w_avg via v_pk_add_f16 -> logs; acc16 += w_avg * v_comb ----
    float4 A0 = make_float4(0,0,0,0), A1 = A0, A2 = A0, A3 = A0;
    float* lrow = logs + rowq * TT_;
    const unsigned* __restrict__ rp0 = (const unsigned*)scb;
    #pragma unroll
    for (int it = 0; it < 3; ++it) {
        const int dwi = tid + 256 * it;       // 0..767
        const int s0 = 2 * dwi;
        if (s0 <= t) {
            h2 hs = __builtin_bit_cast(h2, rp0[dwi]);
            #pragma unroll
            for (int h = 1; h < H_; ++h)
                hs = hs + __builtin_bit_cast(h2, rp0[h * (SCP_ / 2) + dwi]);
            const float wa0 = (float)hs[0] * 0.125f;
            const float wa1 = (float)hs[1] * 0.125f;  // 0 beyond t
            {
                const float4* vp = (const float4*)(vcomb + (bbase + s0) * DK_);
                const float4 v0 = vp[0], v1 = vp[1], v2 = vp[2], v3 = vp[3];
                A0.x = fmaf(wa0, v0.x, A0.x); A0.y = fmaf(wa0, v0.y, A0.y);
                A0.z = fmaf(wa0, v0.z, A0.z); A0.w = fmaf(wa0, v0.w, A0.w);
                A1.x = fmaf(wa0, v1.x, A1.x); A1.y = fmaf(wa0, v1.y, A1.y);
                A1.z = fmaf(wa0, v1.z, A1.z); A1.w = fmaf(wa0, v1.w, A1.w);
                A2.x = fmaf(wa0, v2.x, A2.x); A2.y = fmaf(wa0, v2.y, A2.y);
                A2.z = fmaf(wa0, v2.z, A2.z); A2.w = fmaf(wa0, v2.w, A2.w);
                A3.x = fmaf(wa0, v3.x, A3.x); A3.y = fmaf(wa0, v3.y, A3.y);
                A3.z = fmaf(wa0, v3.z, A3.z); A3.w = fmaf(wa0, v3.w, A3.w);
            }
            if (s0 + 1 <= t) {
                const float4* vp = (const float4*)(vcomb + (bbase + s0 + 1) * DK_);
                const float4 v0 = vp[0], v1 = vp[1], v2 = vp[2], v3 = vp[3];
                A0.x = fmaf(wa1, v0.x, A0.x); A0.y = fmaf(wa1, v0.y, A0.y);
                A0.z = fmaf(wa1, v0.z, A0.z); A0.w = fmaf(wa1, v0.w, A0.w);
                A1.x = fmaf(wa1, v1.x, A1.x); A1.y = fmaf(wa1, v1.y, A1.y);
                A1.z = fmaf(wa1, v1.z, A1.z); A1.w = fmaf(wa1, v1.w, A1.w);
                A2.x = fmaf(wa1, v2.x, A2.x); A2.y = fmaf(wa1, v2.y, A2.y);
                A2.z = fmaf(wa1, v2.z, A2.z); A2.w = fmaf(wa1, v2.w, A2.w);
                A3.x = fmaf(wa1, v3.x, A3.x); A3.y = fmaf(wa1, v3.y, A3.y);
                A3.z = fmaf(wa1, v3.z, A3.z); A3.w = fmaf(wa1, v3.w, A3.w);
            }
            *(float2*)(lrow + s0) = make_float2(wa0, wa1);
        } else {
            *(float2*)(lrow + s0) = make_float2(0.f, 0.f);
        }
    }
    A0.x = wave_sum_l63(A0.x); A0.y = wave_sum_l63(A0.y);
    A0.z = wave_sum_l63(A0.z); A0.w = wave_sum_l63(A0.w);
    A1.x = wave_sum_l63(A1.x); A1.y = wave_sum_l63(A1.y);
    A1.z = wave_sum_l63(A1.z); A1.w = wave_sum_l63(A1.w);
    A2.x = wave_sum_l63(A2.x); A2.y = wave_sum_l63(A2.y);
    A2.z = wave_sum_l63(A2.z); A2.w = wave_sum_l63(A2.w);
    A3.x = wave_sum_l63(A3.x); A3.y = wave_sum_l63(A3.y);
    A3.z = wave_sum_l63(A3.z); A3.w = wave_sum_l63(A3.w);
    if (lane == 63) {
        float* r = red + wave * 16;
        r[0]=A0.x; r[1]=A0.y; r[2]=A0.z; r[3]=A0.w;
        r[4]=A1.x; r[5]=A1.y; r[6]=A1.z; r[7]=A1.w;
        r[8]=A2.x; r[9]=A2.y; r[10]=A2.z; r[11]=A2.w;
        r[12]=A3.x; r[13]=A3.y; r[14]=A3.z; r[15]=A3.w;
    }
    __syncthreads();
    if (tid < DK_) o16[tid] = red[tid] + red[16 + tid] + red[32 + tid] + red[48 + tid];
    __syncthreads();

    // ---- @Wo + bo, residual, LN1 (single-pass mean/var) ----
    float y = 0.f;
    if (tid < D_) {
        float a = bo[tid];
        #pragma unroll
        for (int j = 0; j < DK_; ++j) a = fmaf(o16[j], Wo[j * D_ + tid], a);
        y = xin[rowq * D_ + tid] + a;
        yrow[tid] = y;
    }
    __syncthreads();
    if (tid < 64) {
        const float y0 = yrow[tid], y1 = yrow[tid + 64];
        float sm = wave_sum_l63(y0 + y1);
        float sq = wave_sum_l63(fmaf(y0, y0, y1 * y1));
        if (tid == 63) {
            const float mean = sm * (1.0f / D_);
            stat[0] = mean;
            stat[1] = fmaxf(sq * (1.0f / D_) - mean * mean, 0.f);
        }
    }
    __syncthreads();
    if (tid < D_) {
        const float r = rsqrtf(stat[1] + 1e-5f);
        xout[rowq * D_ + tid] = (y - stat[0]) * r * lng[tid] + lnb[tid];
    }
}

// =======================================================================
// FFN + LN2 (+ fused next-layer QKV, or final projection).  R23: GEMMs
// on the matrix pipe (302.9 -> 285.1). R24: do_qkv also via MFMA —
// xh16 is dead after GEMM1, so the normalized rows are repacked into it
// and the QKV uses the same fragment scheme (waves 0-1 Q, 2-3 K).
// =======================================================================
__global__ __launch_bounds__(256) void ffn_kernel(
    const float* __restrict__ xin, float* __restrict__ xout,
    const unsigned* __restrict__ fh1l, const float* __restrict__ fb1,
    const unsigned* __restrict__ fh2l, const float* __restrict__ fb2,
    const float* __restrict__ g, const float* __restrict__ bta,
    int do_qkv,
    const unsigned* __restrict__ whq_nl, const float* __restrict__ bq,
    const unsigned* __restrict__ whk_nl, const float* __restrict__ bk,
    const float* __restrict__ wvc, const float* __restrict__ bvc,
    _Float16* __restrict__ q16, _Float16* __restrict__ k16,
    float* __restrict__ vc,
    int do_proj, const float* __restrict__ pw,
    const float* __restrict__ pb, float* __restrict__ outp)
{
    __shared__ float    xrT[D_][4];        // [i][r] f32, residual + QKV  2 KB
    __shared__ _Float16 xh16[16][136];     // A of GEMM1 / QKV            4.25 KB
    __shared__ _Float16 h16[16][520];      // A of GEMM2 (rows 4-15 zero) 16.25 KB
    __shared__ float    predf[4][D_];      // GEMM2 output rows           2 KB
    __shared__ float    xn[D_];            // last-row normalized (proj)  0.5 KB

    const long row0 = (long)blockIdx.x * 4;
    const int tid = threadIdx.x;
    const int w = tid >> 6, l = tid & 63;

    // stage x: f32 (residual/QKV) + f16 rows 0-3; zero pad rows 4-15
    for (int idx = tid; idx < 4 * D_; idx += 256) {
        const int r = idx >> 7, i = idx & 127;
        const float v = xin[row0 * D_ + idx];
        xrT[i][r] = v;
        xh16[r][i] = (_Float16)v;
    }
    for (int idx = tid; idx < 12 * 64; idx += 256)
        *(unsigned*)&xh16[4 + (idx >> 6)][2 * (idx & 63)] = 0u;
    for (int idx = tid; idx < 12 * 256; idx += 256)
        *(unsigned*)&h16[4 + (idx >> 8)][2 * (idx & 255)] = 0u;
    __syncthreads();

    // ---- GEMM1 (MFMA): [16x128] @ [128x512]; wave w owns nt = 8w..8w+7 ----
    {
        const int arow = l & 15, ak = 8 * (l >> 4);
        h8 af[4];
        #pragma unroll
        for (int kt = 0; kt < 4; ++kt)
            af[kt] = *(const h8*)&xh16[arow][kt * 32 + ak];
        #pragma unroll
        for (int nt8 = 0; nt8 < 8; ++nt8) {
            const int nt = w * 8 + nt8;
            f32x4 acc = {0.f, 0.f, 0.f, 0.f};
            #pragma unroll
            for (int kt = 0; kt < 4; ++kt) {
                const h8 bf = *(const h8*)(fh1l + (((kt * 32 + nt) * 64 + l) << 2));
                acc = __builtin_amdgcn_mfma_f32_16x16x32_f16(af[kt], bf, acc, 0, 0, 0);
            }
            if (l < 16) {
                const int col = nt * 16 + l;
                const float bias = fb1[col];
                #pragma unroll
                for (int j = 0; j < 4; ++j)
                    h16[j][col] = (_Float16)fmaxf(acc[j] + bias, 0.f);
            }
        }
    }
    __syncthreads();

    // ---- GEMM2 (MFMA): [16x512] @ [512x128]; wave w owns nt = 2w, 2w+1 ----
    {
        const int arow = l & 15, ak = 8 * (l >> 4);
        f32x4 acc0 = {0.f, 0.f, 0.f, 0.f}, acc1 = acc0;
        for (int kt = 0; kt < 16; ++kt) {
            const h8 af = *(const h8*)&h16[arow][kt * 32 + ak];
            const h8 b0 = *(const h8*)(fh2l + (((kt * 8 + 2 * w + 0) * 64 + l) << 2));
            const h8 b1 = *(const h8*)(fh2l + (((kt * 8 + 2 * w + 1) * 64 + l) << 2));
            acc0 = __builtin_amdgcn_mfma_f32_16x16x32_f16(af, b0, acc0, 0, 0, 0);
            acc1 = __builtin_amdgcn_mfma_f32_16x16x32_f16(af, b1, acc1, 0, 0, 0);
        }
        if (l < 16) {
            #pragma unroll
            for (int j = 0; j < 4; ++j) {
                predf[j][(2 * w + 0) * 16 + l] = acc0[j];
                predf[j][(2 * w + 1) * 16 + l] = acc1[j];
            }
        }
    }
    __syncthreads();

    // LN per row, fused bias+residual (R22): wave w handles row w
    const int lane = l;
    const bool pblk = do_proj && (((row0 + 4) % TT_) == 0);
    {
        const float y0 = predf[w][lane]      + fb2[lane]      + xrT[lane][w];
        const float y1 = predf[w][lane + 64] + fb2[lane + 64] + xrT[lane + 64][w];
        const float sm = wave_sum(y0 + y1);
        const float sq = wave_sum(fmaf(y0, y0, y1 * y1));
        const float mean = sm * (1.0f / D_);
        const float var  = fmaxf(sq * (1.0f / D_) - mean * mean, 0.f);
        const float rcp = rsqrtf(var + 1e-5f);
        const float o0 = (y0 - mean) * rcp * g[lane]      + bta[lane];
        const float o1 = (y1 - mean) * rcp * g[lane + 64] + bta[lane + 64];
        xout[(row0 + w) * D_ + lane]      = o0;
        xout[(row0 + w) * D_ + lane + 64] = o1;
        xrT[lane][w]      = o0;           // re-stash for fused qkv
        xrT[lane + 64][w] = o1;
        if (pblk && w == 3) { xn[lane] = o0; xn[lane + 64] = o1; }
    }

    if (do_qkv) {
        __syncthreads();   // xrT holds normalized rows; xh16 rows 4-15 still 0
        for (int idx = tid; idx < 4 * D_; idx += 256) {
            const int r = idx >> 7, i = idx & 127;
            xh16[r][i] = (_Float16)xrT[i][r];
        }
        __syncthreads();
        // QKV via MFMA (R24): wave -> {Q|K} x 4 n-tiles
        {
            const int which = w >> 1;
            const unsigned* __restrict__ Wp = which ? whk_nl : whq_nl;
            const float* __restrict__ bias = which ? bk : bq;
            _Float16* __restrict__ dst = which ? k16 : q16;
            const int ntb = (w & 1) * 4;
            const int arow = l & 15, ak = 8 * (l >> 4);
            h8 af[4];
            #pragma unroll
            for (int kt = 0; kt < 4; ++kt)
                af[kt] = *(const h8*)&xh16[arow][kt * 32 + ak];
            #pragma unroll
            for (int nt4 = 0; nt4 < 4; ++nt4) {
                const int nt = ntb + nt4;
                f32x4 acc = {0.f, 0.f, 0.f, 0.f};
                #pragma unroll
                for (int kt = 0; kt < 4; ++kt) {
                    const h8 bf = *(const h8*)(Wp + (((kt * 8 + nt) * 64 + l) << 2));
                    acc = __builtin_amdgcn_mfma_f32_16x16x32_f16(af[kt], bf, acc, 0, 0, 0);
                }
                if (l < 16) {
                    const int col = nt * 16 + l;
                    const float bb = bias[col];
                    #pragma unroll
                    for (int j = 0; j < 4; ++j)
                        dst[(row0 + j) * D_ + col] = (_Float16)(acc[j] + bb);
                }
            }
        }
        if (tid < 64) {
            const int r = tid >> 4, c16 = tid & 15;
            float av = bvc[c16];
            for (int i = 0; i < D_; ++i)
                av = fmaf(xrT[i][r], wvc[i * DK_ + c16], av);
            vc[(row0 + r) * DK_ + c16] = av;
        }
    }

    if (pblk) {
        __syncthreads();   // block-uniform condition — safe
        const int b = (int)((row0 + 3) / TT_);
        for (int idx = tid; idx < NQ_ * HOR_; idx += 256) {
            const int qq = idx / HOR_, hh = idx - qq * HOR_;
            float s = pb[idx];
            for (int d = 0; d < D_; ++d)
                s = fmaf(xn[d], pw[((long)qq * D_ + d) * HOR_ + hh], s);
            outp[b * NQ_ * HOR_ + idx] = s;
        }
    }
}

} // namespace

extern "C" void kernel_launch(void* const* d_in, const int* in_sizes, int n_in,
                              void* d_out, int out_size, void* d_ws, size_t ws_size,
                              hipStream_t stream) {
    (void)in_sizes; (void)n_in; (void)out_size; (void)ws_size;

    const float* x_cond = (const float*)d_in[0];
    const float* x_pred = (const float*)d_in[1];
    const float* cw_c   = (const float*)d_in[2];
    const float* cb_c   = (const float*)d_in[3];
    const float* sw_c   = (const float*)d_in[4];
    const float* sb_c   = (const float*)d_in[5];
    const float* cw_p   = (const float*)d_in[6];
    const float* cb_p   = (const float*)d_in[7];
    const float* sw_p   = (const float*)d_in[8];
    const float* sb_p   = (const float*)d_in[9];
    const float* Wq     = (const float*)d_in[10];
    const float* bq     = (const float*)d_in[11];
    const float* Wk     = (const float*)d_in[12];
    const float* bk     = (const float*)d_in[13];
    const float* Wv     = (const float*)d_in[14];
    const float* bv     = (const float*)d_in[15];
    const float* Wo     = (const float*)d_in[16];
    const float* bo     = (const float*)d_in[17];
    const float* ln1g   = (const float*)d_in[18];
    const float* ln1b   = (const float*)d_in[19];
    const float* fw1    = (const float*)d_in[20];
    const float* fb1    = (const float*)d_in[21];
    const float* fw2    = (const float*)d_in[22];
    const float* fb2    = (const float*)d_in[23];
    const float* ln2g   = (const float*)d_in[24];
    const float* ln2b   = (const float*)d_in[25];
    const float* pw     = (const float*)d_in[26];
    const float* pb     = (const float*)d_in[27];

    float* outp = (float*)d_out;
    float* ws   = (float*)d_ws;
    float*     xA   = ws + WS_XA;
    float*     xB   = ws + WS_XB;
    _Float16*  q16  = (_Float16*)(ws + WS_Q16);
    _Float16*  k16  = (_Float16*)(ws + WS_K16);
    float*     vcb  = ws + WS_VC;
    float*     wvc  = ws + WS_WVC;
    float*     bvc  = ws + WS_BVC;
    unsigned*  fh1  = (unsigned*)(ws + WS_FH1);
    unsigned*  fh2  = (unsigned*)(ws + WS_FH2);
    unsigned*  whq  = (unsigned*)(ws + WS_WHQ);
    unsigned*  whk  = (unsigned*)(ws + WS_WHK);

    // Wv head-mean + MFMA B-fragment packing (must precede pre/ffn)
    prep_kernel<<<128, 256, 0, stream>>>(Wv, bv, wvc, bvc,
                                         fw1, fw2, Wq, Wk,
                                         fh1, fh2, whq, whk);

    // selectors + layer-0 QKV, one launch (R19: 4 tokens per block)
    pre_kernel<<<(NB_ * TC_ + NB_ * TP_) / 4, 256, 0, stream>>>(
        x_cond, cw_c, cb_c, sw_c, sb_c,
        x_pred, cw_p, cb_p, sw_p, sb_p,
        outp + OFF_VC, outp + OFF_VP, xA,
        whq, bq, whk, bk, wvc, bvc, q16, k16, vcb);

    for (int l = 0; l < L_; ++l) {
        attn_kernel<<<NB_ * TT_, 256, 0, stream>>>(
            q16, k16, vcb, xA, xB,
            Wo + (long)l * DK_ * D_, bo + l * D_,
            ln1g + l * D_, ln1b + l * D_,
            outp + OFF_LOGS + (long)l * NB_ * TT_ * TT_);
        const int nl = l + 1;
        const int more = (l < L_ - 1);
        ffn_kernel<<<NB_ * TT_ / 4, 256, 0, stream>>>(
            xB, xA, fh1 + (long)l * FHL_, fb1 + l * DFF_,
            fh2 + (long)l * FHL_, fb2 + l * D_,
            ln2g + l * D_, ln2b + l * D_,
            more,
            whq + (long)nl * WHQL_ * more, bq + nl * D_ * more,
            whk + (long)nl * WHQL_ * more, bk + nl * D_ * more,
            wvc + nl * D_ * DK_ * more, bvc + nl * DK_ * more,
            q16, k16, vcb,
            (l == L_ - 1) ? 1 : 0, pw, pb, outp);
    }
}